// Round 1
// baseline (1934.794 us; speedup 1.0000x reference)
//
#include <hip/hip_runtime.h>
#include <cmath>

#define B_  2
#define L_  1024
#define DM  1024
#define DI  2048
#define DS  16
#define DR  64

// ---------------------------------------------------------------------------
// Generic bounds-checked fp32 GEMM: C[M,N] = A[M,K] @ B[K,N] (row-major, with
// explicit leading dims). BM=BN=64, BK=16, 256 threads, 4x4 per thread.
// ---------------------------------------------------------------------------
__global__ __launch_bounds__(256) void gemm_f32(
    const float* __restrict__ A, const float* __restrict__ Bm,
    float* __restrict__ C, int M, int N, int K, int lda, int ldb, int ldc)
{
    __shared__ float As[16][65];
    __shared__ float Bs[16][65];
    const int tid = threadIdx.x;
    const int bm = blockIdx.y * 64, bn = blockIdx.x * 64;
    const int tr = tid >> 4;   // 0..15
    const int tc = tid & 15;   // 0..15
    float acc[4][4] = {};

    for (int k0 = 0; k0 < K; k0 += 16) {
        // A tile: 64 rows x 16 cols
        for (int i = tid; i < 64 * 16; i += 256) {
            int r = i >> 4, c = i & 15;
            float v = 0.f;
            if (bm + r < M && k0 + c < K) v = A[(size_t)(bm + r) * lda + k0 + c];
            As[c][r] = v;
        }
        // B tile: 16 rows x 64 cols
        for (int i = tid; i < 16 * 64; i += 256) {
            int r = i >> 6, c = i & 63;
            float v = 0.f;
            if (k0 + r < K && bn + c < N) v = Bm[(size_t)(k0 + r) * ldb + bn + c];
            Bs[r][c] = v;
        }
        __syncthreads();
        #pragma unroll
        for (int kk = 0; kk < 16; ++kk) {
            float a0[4], b0[4];
            #pragma unroll
            for (int i = 0; i < 4; ++i) a0[i] = As[kk][tr * 4 + i];
            #pragma unroll
            for (int j = 0; j < 4; ++j) b0[j] = Bs[kk][tc * 4 + j];
            #pragma unroll
            for (int i = 0; i < 4; ++i)
                #pragma unroll
                for (int j = 0; j < 4; ++j)
                    acc[i][j] = fmaf(a0[i], b0[j], acc[i][j]);
        }
        __syncthreads();
    }
    #pragma unroll
    for (int i = 0; i < 4; ++i) {
        int r = bm + tr * 4 + i;
        if (r >= M) continue;
        #pragma unroll
        for (int j = 0; j < 4; ++j) {
            int c = bn + tc * 4 + j;
            if (c < N) C[(size_t)r * ldc + c] = acc[i][j];
        }
    }
}

// ---------------------------------------------------------------------------
// Depthwise causal conv (k=4) over time + bias + SiLU.
// x_in(b,t,d) = xz[(b*L+t)*4096 + d];  u = silu(conv)
// ---------------------------------------------------------------------------
__global__ __launch_bounds__(256) void conv_silu(
    const float* __restrict__ xz, const float* __restrict__ w,
    const float* __restrict__ bias, float* __restrict__ u)
{
    int idx = blockIdx.x * 256 + threadIdx.x;       // over B*L*DI
    if (idx >= B_ * L_ * DI) return;
    int d  = idx & (DI - 1);
    int bl = idx >> 11;          // b*L + l
    int l  = bl & (L_ - 1);

    const float w0 = w[d * 4 + 0], w1 = w[d * 4 + 1];
    const float w2 = w[d * 4 + 2], w3 = w[d * 4 + 3];
    float s = bias[d];
    size_t base = (size_t)bl * 4096 + d;            // t = l
    if (l >= 3) s = fmaf(w0, xz[base - 3 * 4096], s);
    if (l >= 2) s = fmaf(w1, xz[base - 2 * 4096], s);
    if (l >= 1) s = fmaf(w2, xz[base - 1 * 4096], s);
    s = fmaf(w3, xz[base], s);
    float sig = 1.f / (1.f + __expf(-s));
    u[idx] = s * sig;
}

// ---------------------------------------------------------------------------
// delta = softplus(delta_raw + b_dt[d])
// ---------------------------------------------------------------------------
__global__ __launch_bounds__(256) void softplus_bias(
    float* __restrict__ delta, const float* __restrict__ b_dt)
{
    int idx = blockIdx.x * 256 + threadIdx.x;
    if (idx >= B_ * L_ * DI) return;
    int d = idx & (DI - 1);
    float v = delta[idx] + b_dt[d];
    delta[idx] = (v > 20.f) ? v : log1pf(__expf(v));
}

// ---------------------------------------------------------------------------
// Selective scan. 16 lanes per channel (one per state n), 16 channels/block.
// Grid: B*DI/16 = 256 blocks of 256 threads.
// Fuses: dA=exp(delta*A), h=dA*h+delta*u*B, y=h.C, +D_skip*u, *silu(z).
// ---------------------------------------------------------------------------
__global__ __launch_bounds__(256) void scan_kernel(
    const float* __restrict__ delta, const float* __restrict__ u,
    const float* __restrict__ xdbl,  const float* __restrict__ xz,
    const float* __restrict__ A_log, const float* __restrict__ D_skip,
    float* __restrict__ y)
{
    const int tid = threadIdx.x;
    const int n      = tid & 15;
    const int dlocal = tid >> 4;                    // 0..15
    const int cg = blockIdx.x * 16 + dlocal;        // 0..4095
    const int b = cg >> 11;
    const int d = cg & (DI - 1);

    const float Adn = -__expf(A_log[d * DS + n]);
    const float Dd  = D_skip[d];
    float h = 0.f;

    size_t pd = (size_t)b * L_ * DI + d;
    size_t px = (size_t)b * L_ * 96;
    size_t pz = (size_t)b * L_ * 4096 + 2048 + d;

    for (int t = 0; t < L_; ++t) {
        float dv = delta[pd];
        float uv = u[pd];
        float Bn = xdbl[px + DR + n];
        float Cn = xdbl[px + DR + DS + n];
        float dA = __expf(dv * Adn);
        h = fmaf(dA, h, dv * uv * Bn);
        float part = h * Cn;
        part += __shfl_xor(part, 1);
        part += __shfl_xor(part, 2);
        part += __shfl_xor(part, 4);
        part += __shfl_xor(part, 8);
        if (n == 0) {
            float zv = xz[pz];
            float yv = part + Dd * uv;
            yv *= zv * (1.f / (1.f + __expf(-zv)));
            y[pd] = yv;
        }
        pd += DI; px += 96; pz += 4096;
    }
}

// ---------------------------------------------------------------------------
extern "C" void kernel_launch(void* const* d_in, const int* in_sizes, int n_in,
                              void* d_out, int out_size, void* d_ws, size_t ws_size,
                              hipStream_t stream)
{
    const float* x      = (const float*)d_in[0];
    const float* W_in   = (const float*)d_in[1];
    const float* conv_w = (const float*)d_in[2];
    const float* conv_b = (const float*)d_in[3];
    const float* W_xprj = (const float*)d_in[4];
    const float* W_dt   = (const float*)d_in[5];
    const float* b_dt   = (const float*)d_in[6];
    const float* A_log  = (const float*)d_in[7];
    const float* D_skip = (const float*)d_in[8];
    const float* W_out  = (const float*)d_in[9];
    float* out = (float*)d_out;

    char* ws = (char*)d_ws;
    float* xz    = (float*)(ws);                     // 2048 x 4096  (32 MB)
    float* u     = (float*)(ws + 33554432);          // 2048 x 2048  (16 MB)
    float* xdbl  = (float*)(ws + 50331648);          // 2048 x 96    (0.75 MB)
    float* delta = (float*)(ws + 51118080);          // 2048 x 2048  (16 MB)
    float* y     = (float*)(ws + 67895296);          // 2048 x 2048  (16 MB)

    dim3 blk(256);
    const int M = B_ * L_;   // 2048

    // xz = x @ W_in            (2048 x 1024) @ (1024 x 4096)
    gemm_f32<<<dim3(4096 / 64, M / 64), blk, 0, stream>>>(
        x, W_in, xz, M, 2 * DI, DM, DM, 2 * DI, 2 * DI);

    // u = silu(depthwise_conv(x_in) + b)
    conv_silu<<<dim3((B_ * L_ * DI) / 256), blk, 0, stream>>>(xz, conv_w, conv_b, u);

    // x_dbl = u @ W_xproj      (2048 x 2048) @ (2048 x 96)
    gemm_f32<<<dim3(2, M / 64), blk, 0, stream>>>(
        u, W_xprj, xdbl, M, DR + 2 * DS, DI, DI, DR + 2 * DS, DR + 2 * DS);

    // delta_raw = dt_lr @ W_dt (2048 x 64) @ (64 x 2048)   (lda = 96!)
    gemm_f32<<<dim3(DI / 64, M / 64), blk, 0, stream>>>(
        xdbl, W_dt, delta, M, DI, DR, DR + 2 * DS, DI, DI);

    // delta = softplus(delta_raw + b_dt)
    softplus_bias<<<dim3((B_ * L_ * DI) / 256), blk, 0, stream>>>(delta, b_dt);

    // selective scan + skip + gate
    scan_kernel<<<dim3((B_ * DI) / 16), blk, 0, stream>>>(
        delta, u, xdbl, xz, A_log, D_skip, y);

    // out = y @ W_out          (2048 x 2048) @ (2048 x 1024)
    gemm_f32<<<dim3(DM / 64, M / 64), blk, 0, stream>>>(
        y, W_out, out, M, DM, DI, DI, DM, DM);
}

// Round 2
// 570.228 us; speedup vs baseline: 3.3930x; 3.3930x over previous
//
#include <hip/hip_runtime.h>
#include <cmath>

#define B_  2
#define L_  1024
#define DM  1024
#define DI  2048
#define DS  16
#define DR  64
#define NC  8          // scan time-chunks
#define CL  (L_/NC)    // 128 steps per chunk

typedef __attribute__((ext_vector_type(8))) short short8;
typedef __attribute__((ext_vector_type(4))) float f32x4;

static __device__ __forceinline__ ushort f2bf(float f) {
    union { float f; unsigned u; } c; c.f = f;
    unsigned u = c.u;
    return (ushort)((u + 0x7fffu + ((u >> 16) & 1u)) >> 16);   // RNE
}
static __device__ __forceinline__ float bf2f(ushort h) {
    union { unsigned u; float f; } c; c.u = ((unsigned)h) << 16;
    return c.f;
}

// pack 8 floats -> hi/lo bf16 uint4s
static __device__ __forceinline__ void cvt8(const float* v, uint4& hi, uint4& lo) {
    unsigned h[4], l[4];
    #pragma unroll
    for (int j = 0; j < 4; ++j) {
        ushort h0 = f2bf(v[2*j]),   h1 = f2bf(v[2*j+1]);
        ushort l0 = f2bf(v[2*j]   - bf2f(h0));
        ushort l1 = f2bf(v[2*j+1] - bf2f(h1));
        h[j] = (unsigned)h0 | ((unsigned)h1 << 16);
        l[j] = (unsigned)l0 | ((unsigned)l1 << 16);
    }
    hi = make_uint4(h[0], h[1], h[2], h[3]);
    lo = make_uint4(l[0], l[1], l[2], l[3]);
}

static __device__ __forceinline__ int swz(int r, int ch) {   // k-chunk swizzle
    return (ch ^ (r & 3) ^ ((r >> 2) & 3)) * 8;
}

// ---------------------------------------------------------------------------
// C[M,N] = A[M,K] @ B[K,N], fp32 in/out, bf16x3 split MFMA (fp32-accurate).
// 128x128 tile, BK=32, 256 threads (4 waves, each 64x64 via 4x4 16x16 frags).
// Requires M%128==0, K%32==0; N bounds-checked.
// ---------------------------------------------------------------------------
__global__ __launch_bounds__(256) void gemm_bf16x3(
    const float* __restrict__ A, const float* __restrict__ Bm,
    float* __restrict__ C, int M, int N, int K, int lda, int ldb, int ldc)
{
    __shared__ ushort Ah[128][32], Al[128][32], Bh[128][32], Bl[128][32];
    const int tid = threadIdx.x;
    const int bm = blockIdx.y * 128, bn = blockIdx.x * 128;
    const int wid = tid >> 6, lane = tid & 63;
    const int wr = (wid >> 1) * 64, wc = (wid & 1) * 64;
    const int fr = lane & 15, fq = lane >> 4;

    f32x4 acc[4][4] = {};

    for (int k0 = 0; k0 < K; k0 += 32) {
        __syncthreads();
        // ---- stage A tile: 128 rows x 32 k (hi+lo) ----
        #pragma unroll
        for (int it = 0; it < 2; ++it) {
            int p = it * 256 + tid;
            int row = p >> 2, ch = p & 3;
            const float* ga = &A[(size_t)(bm + row) * lda + k0 + ch * 8];
            float4 v0 = *(const float4*)ga;
            float4 v1 = *(const float4*)(ga + 4);
            float vv[8] = {v0.x, v0.y, v0.z, v0.w, v1.x, v1.y, v1.z, v1.w};
            uint4 hi, lo; cvt8(vv, hi, lo);
            int sc = swz(row, ch);
            *(uint4*)&Ah[row][sc] = hi;
            *(uint4*)&Al[row][sc] = lo;
        }
        // ---- stage B tile transposed: [n][k], coalesced global reads ----
        #pragma unroll
        for (int it = 0; it < 2; ++it) {
            int p = it * 256 + tid;
            int n = p & 127, ch = p >> 7;
            bool ok = (bn + n) < N;
            float vv[8];
            #pragma unroll
            for (int j = 0; j < 8; ++j)
                vv[j] = ok ? Bm[(size_t)(k0 + ch * 8 + j) * ldb + bn + n] : 0.f;
            uint4 hi, lo; cvt8(vv, hi, lo);
            int sc = swz(n, ch);
            *(uint4*)&Bh[n][sc] = hi;
            *(uint4*)&Bl[n][sc] = lo;
        }
        __syncthreads();
        // ---- fragments + MFMA ----
        short8 ah[4], al[4], bh[4], bl[4];
        #pragma unroll
        for (int m = 0; m < 4; ++m) {
            int r = wr + m * 16 + fr;
            int sc = swz(r, fq);
            ah[m] = *(const short8*)&Ah[r][sc];
            al[m] = *(const short8*)&Al[r][sc];
        }
        #pragma unroll
        for (int n = 0; n < 4; ++n) {
            int c = wc + n * 16 + fr;
            int sc = swz(c, fq);
            bh[n] = *(const short8*)&Bh[c][sc];
            bl[n] = *(const short8*)&Bl[c][sc];
        }
        #pragma unroll
        for (int m = 0; m < 4; ++m)
            #pragma unroll
            for (int n = 0; n < 4; ++n) {
                acc[m][n] = __builtin_amdgcn_mfma_f32_16x16x32_bf16(ah[m], bh[n], acc[m][n], 0, 0, 0);
                acc[m][n] = __builtin_amdgcn_mfma_f32_16x16x32_bf16(ah[m], bl[n], acc[m][n], 0, 0, 0);
                acc[m][n] = __builtin_amdgcn_mfma_f32_16x16x32_bf16(al[m], bh[n], acc[m][n], 0, 0, 0);
            }
    }
    // ---- C write: row=(lane>>4)*4+reg, col=lane&15 ----
    #pragma unroll
    for (int m = 0; m < 4; ++m) {
        int rbase = bm + wr + m * 16 + fq * 4;
        #pragma unroll
        for (int n = 0; n < 4; ++n) {
            int col = bn + wc + n * 16 + fr;
            if (col >= N) continue;
            #pragma unroll
            for (int j = 0; j < 4; ++j)
                C[(size_t)(rbase + j) * ldc + col] = acc[m][n][j];
        }
    }
}

// ---------------------------------------------------------------------------
// Depthwise causal conv (k=4) + bias + SiLU.
// ---------------------------------------------------------------------------
__global__ __launch_bounds__(256) void conv_silu(
    const float* __restrict__ xz, const float* __restrict__ w,
    const float* __restrict__ bias, float* __restrict__ u)
{
    int idx = blockIdx.x * 256 + threadIdx.x;
    if (idx >= B_ * L_ * DI) return;
    int d  = idx & (DI - 1);
    int bl = idx >> 11;
    int l  = bl & (L_ - 1);

    const float w0 = w[d * 4 + 0], w1 = w[d * 4 + 1];
    const float w2 = w[d * 4 + 2], w3 = w[d * 4 + 3];
    float s = bias[d];
    size_t base = (size_t)bl * 4096 + d;
    if (l >= 3) s = fmaf(w0, xz[base - 3 * 4096], s);
    if (l >= 2) s = fmaf(w1, xz[base - 2 * 4096], s);
    if (l >= 1) s = fmaf(w2, xz[base - 1 * 4096], s);
    s = fmaf(w3, xz[base], s);
    u[idx] = s / (1.f + __expf(-s));
}

// ---------------------------------------------------------------------------
__global__ __launch_bounds__(256) void softplus_bias(
    float* __restrict__ delta, const float* __restrict__ b_dt)
{
    int idx = blockIdx.x * 256 + threadIdx.x;
    if (idx >= B_ * L_ * DI) return;
    int d = idx & (DI - 1);
    float v = delta[idx] + b_dt[d];
    delta[idx] = (v > 20.f) ? v : log1pf(__expf(v));
}

// ---------------------------------------------------------------------------
// Scan phase A: per-(b,d,n,chunk) partials (aP = prod dA, hP from h0=0).
// idx bits: n:4 | d:11 | c:3 | b:1
// ---------------------------------------------------------------------------
__global__ __launch_bounds__(256) void scan_partial(
    const float* __restrict__ delta, const float* __restrict__ u,
    const float* __restrict__ xdbl,  const float* __restrict__ A_log,
    float* __restrict__ sA, float* __restrict__ sH)
{
    int idx = blockIdx.x * 256 + threadIdx.x;
    int n = idx & 15;
    int d = (idx >> 4) & (DI - 1);
    int c = (idx >> 15) & (NC - 1);
    int b = idx >> 18;

    const float Adn = -__expf(A_log[d * DS + n]);
    float aP = 1.f, h = 0.f;
    size_t pd = ((size_t)b * L_ + c * CL) * DI + d;
    size_t px = ((size_t)b * L_ + c * CL) * 96;
    for (int t = 0; t < CL; ++t) {
        float dv = delta[pd], uv = u[pd];
        float Bn = xdbl[px + DR + n];
        float dA = __expf(dv * Adn);
        aP *= dA;
        h = fmaf(dA, h, dv * uv * Bn);
        pd += DI; px += 96;
    }
    int o = ((c * B_ + b) * DI + d) * DS + n;
    sA[o] = aP; sH[o] = h;
}

// ---------------------------------------------------------------------------
// Scan phase B: serial combine over chunks -> h_init per chunk.
// ---------------------------------------------------------------------------
__global__ __launch_bounds__(256) void scan_combine(
    const float* __restrict__ sA, const float* __restrict__ sH,
    float* __restrict__ hinit)
{
    int idx = blockIdx.x * 256 + threadIdx.x;   // (b,d,n), 65536
    int n = idx & 15;
    int d = (idx >> 4) & (DI - 1);
    int b = idx >> 15;
    float h = 0.f;
    #pragma unroll
    for (int c = 0; c < NC; ++c) {
        int o = ((c * B_ + b) * DI + d) * DS + n;
        hinit[o] = h;
        h = fmaf(sA[o], h, sH[o]);
    }
}

// ---------------------------------------------------------------------------
// Scan phase C: recompute chunk from h_init, reduce over n, skip+gate.
// 16 lanes per (b,c,d); y may alias delta (read-before-write per index).
// ---------------------------------------------------------------------------
__global__ __launch_bounds__(256) void scan_final(
    const float* __restrict__ delta, const float* __restrict__ u,
    const float* __restrict__ xdbl,  const float* __restrict__ xz,
    const float* __restrict__ A_log, const float* __restrict__ D_skip,
    const float* __restrict__ hinit, float* __restrict__ y)
{
    int tid = threadIdx.x;
    int n = tid & 15;
    int gi = blockIdx.x * 16 + (tid >> 4);   // (b,c,d), d fastest
    int d = gi & (DI - 1);
    int c = (gi >> 11) & (NC - 1);
    int b = gi >> 14;

    const float Adn = -__expf(A_log[d * DS + n]);
    const float Dd  = D_skip[d];
    float h = hinit[((c * B_ + b) * DI + d) * DS + n];

    size_t pd = ((size_t)b * L_ + c * CL) * DI + d;
    size_t px = ((size_t)b * L_ + c * CL) * 96;
    size_t pz = ((size_t)b * L_ + c * CL) * 4096 + 2048 + d;
    for (int t = 0; t < CL; ++t) {
        float dv = delta[pd], uv = u[pd];
        float Bn = xdbl[px + DR + n];
        float Cn = xdbl[px + DR + DS + n];
        float dA = __expf(dv * Adn);
        h = fmaf(dA, h, dv * uv * Bn);
        float part = h * Cn;
        part += __shfl_xor(part, 1);
        part += __shfl_xor(part, 2);
        part += __shfl_xor(part, 4);
        part += __shfl_xor(part, 8);
        if (n == 0) {
            float zv = xz[pz];
            float yv = part + Dd * uv;
            yv *= zv / (1.f + __expf(-zv));
            y[pd] = yv;
        }
        pd += DI; px += 96; pz += 4096;
    }
}

// ---------------------------------------------------------------------------
extern "C" void kernel_launch(void* const* d_in, const int* in_sizes, int n_in,
                              void* d_out, int out_size, void* d_ws, size_t ws_size,
                              hipStream_t stream)
{
    const float* x      = (const float*)d_in[0];
    const float* W_in   = (const float*)d_in[1];
    const float* conv_w = (const float*)d_in[2];
    const float* conv_b = (const float*)d_in[3];
    const float* W_xprj = (const float*)d_in[4];
    const float* W_dt   = (const float*)d_in[5];
    const float* b_dt   = (const float*)d_in[6];
    const float* A_log  = (const float*)d_in[7];
    const float* D_skip = (const float*)d_in[8];
    const float* W_out  = (const float*)d_in[9];
    float* out = (float*)d_out;

    char* ws = (char*)d_ws;
    float* xz    = (float*)(ws);                 // 2048 x 4096 (32 MB)
    float* u     = (float*)(ws + 33554432);      // 2048 x 2048 (16 MB)
    float* xdbl  = (float*)(ws + 50331648);      // 2048 x 96   (768 KB)
    float* delta = (float*)(ws + 51118080);      // 2048 x 2048 (16 MB), y aliases
    float* sA    = (float*)(ws + 67895296);      // 2 MB
    float* sH    = (float*)(ws + 69992448);      // 2 MB
    float* hin   = (float*)(ws + 72089600);      // 2 MB  (end 74186752)
    float* y     = delta;

    dim3 blk(256);
    const int M = B_ * L_;   // 2048

    // xz = x @ W_in            (2048x1024)@(1024x4096)
    gemm_bf16x3<<<dim3(4096 / 128, M / 128), blk, 0, stream>>>(
        x, W_in, xz, M, 2 * DI, DM, DM, 2 * DI, 2 * DI);

    // u = silu(conv(x_in) + b)
    conv_silu<<<dim3((B_ * L_ * DI) / 256), blk, 0, stream>>>(xz, conv_w, conv_b, u);

    // x_dbl = u @ W_xproj      (2048x2048)@(2048x96)
    gemm_bf16x3<<<dim3(1, M / 128), blk, 0, stream>>>(
        u, W_xprj, xdbl, M, DR + 2 * DS, DI, DI, DR + 2 * DS, DR + 2 * DS);

    // delta_raw = dt_lr @ W_dt (2048x64)@(64x2048), lda=96
    gemm_bf16x3<<<dim3(DI / 128, M / 128), blk, 0, stream>>>(
        xdbl, W_dt, delta, M, DI, DR, DR + 2 * DS, DI, DI);

    // delta = softplus(delta_raw + b_dt)
    softplus_bias<<<dim3((B_ * L_ * DI) / 256), blk, 0, stream>>>(delta, b_dt);

    // chunked selective scan
    scan_partial<<<dim3((B_ * DI * DS * NC) / 256), blk, 0, stream>>>(
        delta, u, xdbl, A_log, sA, sH);
    scan_combine<<<dim3((B_ * DI * DS) / 256), blk, 0, stream>>>(sA, sH, hin);
    scan_final<<<dim3((B_ * DI * NC) / 16), blk, 0, stream>>>(
        delta, u, xdbl, xz, A_log, D_skip, hin, y);

    // out = y @ W_out          (2048x2048)@(2048x1024)
    gemm_bf16x3<<<dim3(DM / 128, M / 128), blk, 0, stream>>>(
        y, W_out, out, M, DM, DI, DI, DM, DM);
}

// Round 3
// 377.461 us; speedup vs baseline: 5.1258x; 1.5107x over previous
//
#include <hip/hip_runtime.h>
#include <cmath>

#define B_  2
#define L_  1024
#define DM  1024
#define DI  2048
#define DS  16
#define DR  64
#define NC  8          // scan time-chunks
#define CL  (L_/NC)    // 128 steps per chunk

typedef __attribute__((ext_vector_type(8))) short short8;
typedef __attribute__((ext_vector_type(4))) float f32x4;

static __device__ __forceinline__ ushort f2bf(float f) {
    union { float f; unsigned u; } c; c.f = f;
    unsigned u = c.u;
    return (ushort)((u + 0x7fffu + ((u >> 16) & 1u)) >> 16);   // RNE
}
static __device__ __forceinline__ float bf2f(ushort h) {
    union { unsigned u; float f; } c; c.u = ((unsigned)h) << 16;
    return c.f;
}

// pack 8 floats -> hi/lo bf16 uint4s
static __device__ __forceinline__ void cvt8(const float* v, uint4& hi, uint4& lo) {
    unsigned h[4], l[4];
    #pragma unroll
    for (int j = 0; j < 4; ++j) {
        ushort h0 = f2bf(v[2*j]),   h1 = f2bf(v[2*j+1]);
        ushort l0 = f2bf(v[2*j]   - bf2f(h0));
        ushort l1 = f2bf(v[2*j+1] - bf2f(h1));
        h[j] = (unsigned)h0 | ((unsigned)h1 << 16);
        l[j] = (unsigned)l0 | ((unsigned)l1 << 16);
    }
    hi = make_uint4(h[0], h[1], h[2], h[3]);
    lo = make_uint4(l[0], l[1], l[2], l[3]);
}

// ---------------------------------------------------------------------------
// convA: fp32 [R][C] (leading dim ld) -> bf16 hi/lo [R][C] row-major.
// One thread = 8 elements. C = 1<<c8sh elements... c8 count = C/8.
// ---------------------------------------------------------------------------
__global__ __launch_bounds__(256) void convA(
    const float* __restrict__ in, int ld, ushort* __restrict__ oh,
    ushort* __restrict__ ol, int c8sh, int total)
{
    int v = blockIdx.x * 256 + threadIdx.x;
    if (v >= total) return;
    int r  = v >> c8sh;
    int c8 = v & ((1 << c8sh) - 1);
    const float* p = in + (size_t)r * ld + c8 * 8;
    float4 v0 = *(const float4*)p;
    float4 v1 = *(const float4*)(p + 4);
    float vv[8] = {v0.x, v0.y, v0.z, v0.w, v1.x, v1.y, v1.z, v1.w};
    uint4 hi, lo; cvt8(vv, hi, lo);
    size_t o = ((size_t)r << c8sh << 3) + c8 * 8;
    *(uint4*)&oh[o] = hi;
    *(uint4*)&ol[o] = lo;
}

// ---------------------------------------------------------------------------
// convBT: fp32 [K][N] -> bf16 hi/lo [Npad][K] (transposed). 32x32 LDS tiles.
// Rows n >= N are zero-padded.
// ---------------------------------------------------------------------------
__global__ __launch_bounds__(256) void convBT(
    const float* __restrict__ in, ushort* __restrict__ oh,
    ushort* __restrict__ ol, int K, int N, int Npad)
{
    __shared__ float t[32][33];
    int tx = threadIdx.x, ty = threadIdx.y;
    int n0 = blockIdx.x * 32, k0 = blockIdx.y * 32;
    #pragma unroll
    for (int i = 0; i < 4; ++i) {
        int k = k0 + ty * 4 + i, n = n0 + tx;
        t[ty * 4 + i][tx] = (n < N) ? in[(size_t)k * N + n] : 0.f;
    }
    __syncthreads();
    #pragma unroll
    for (int i = 0; i < 4; ++i) {
        int r = n0 + ty * 4 + i;   // output row (= n)
        int c = k0 + tx;           // output col (= k)
        if (r < Npad) {
            float v = t[tx][ty * 4 + i];
            ushort h = f2bf(v);
            oh[(size_t)r * K + c] = h;
            ol[(size_t)r * K + c] = f2bf(v - bf2f(h));
        }
    }
}

// ---------------------------------------------------------------------------
// GEMM: C[M][N] = A[M][K] @ B[N][K]^T, bf16x3 split (fp32-accurate).
// 128x128 tile, BK=32, 4 waves. global_load_lds(16B) staging, linear LDS +
// XOR-swizzled source/read:  perm(a) = a ^ (((a>>7)&7)<<4)  (involution).
// blockIdx.z = K-split chunk (kspl elements each); C gets z*M row offset.
// ---------------------------------------------------------------------------
static __device__ __forceinline__ void stage_tile(
    ushort* lds, const ushort* __restrict__ g, int ld, int row0, int k0,
    int wid, int lane)
{
    #pragma unroll
    for (int it = 0; it < 2; ++it) {
        int o  = wid * 2048 + it * 1024;          // wave-uniform LDS byte base
        int ob = o + lane * 16;                   // this lane's dest byte
        int a  = ob ^ (((ob >> 7) & 7) << 4);     // logical byte address
        int row = a >> 6;
        int lc  = (a >> 4) & 3;
        const ushort* gp = g + (size_t)(row0 + row) * ld + k0 + lc * 8;
        __builtin_amdgcn_global_load_lds(
            (const __attribute__((address_space(1))) void*)gp,
            (__attribute__((address_space(3))) void*)((char*)lds + o),
            16, 0, 0);
    }
}

static __device__ __forceinline__ short8 frag(const ushort* lds, int row, int fq) {
    int a = row * 64 + fq * 16;
    int b = a ^ (((a >> 7) & 7) << 4);
    return *(const short8*)((const char*)lds + b);
}

__global__ __launch_bounds__(256) void gemm_bt(
    const ushort* __restrict__ Ah, const ushort* __restrict__ Al,
    const ushort* __restrict__ Bh, const ushort* __restrict__ Bl,
    float* __restrict__ C, int M, int N, int lda, int ldb, int ldc, int kspl)
{
    __shared__ ushort sm[16384];                  // 32 KB: Ah|Al|Bh|Bl tiles
    ushort* sAh = sm;         ushort* sAl = sm + 4096;
    ushort* sBh = sm + 8192;  ushort* sBl = sm + 12288;

    const int tid = threadIdx.x, wid = tid >> 6, lane = tid & 63;
    const int bm = blockIdx.y * 128, bn = blockIdx.x * 128;
    const int kb = blockIdx.z * kspl;
    const int wr = (wid >> 1) * 64, wc = (wid & 1) * 64;
    const int fr = lane & 15, fq = lane >> 4;

    f32x4 acc[4][4] = {};

    for (int k0 = 0; k0 < kspl; k0 += 32) {
        stage_tile(sAh, Ah, lda, bm, kb + k0, wid, lane);
        stage_tile(sAl, Al, lda, bm, kb + k0, wid, lane);
        stage_tile(sBh, Bh, ldb, bn, kb + k0, wid, lane);
        stage_tile(sBl, Bl, ldb, bn, kb + k0, wid, lane);
        __syncthreads();                          // drains vmcnt before barrier

        short8 a_h[4], a_l[4], b_h[4], b_l[4];
        #pragma unroll
        for (int m = 0; m < 4; ++m) {
            a_h[m] = frag(sAh, wr + m * 16 + fr, fq);
            a_l[m] = frag(sAl, wr + m * 16 + fr, fq);
        }
        #pragma unroll
        for (int n = 0; n < 4; ++n) {
            b_h[n] = frag(sBh, wc + n * 16 + fr, fq);
            b_l[n] = frag(sBl, wc + n * 16 + fr, fq);
        }
        #pragma unroll
        for (int m = 0; m < 4; ++m)
            #pragma unroll
            for (int n = 0; n < 4; ++n) {
                acc[m][n] = __builtin_amdgcn_mfma_f32_16x16x32_bf16(a_h[m], b_h[n], acc[m][n], 0, 0, 0);
                acc[m][n] = __builtin_amdgcn_mfma_f32_16x16x32_bf16(a_h[m], b_l[n], acc[m][n], 0, 0, 0);
                acc[m][n] = __builtin_amdgcn_mfma_f32_16x16x32_bf16(a_l[m], b_h[n], acc[m][n], 0, 0, 0);
            }
        __syncthreads();                          // protect LDS re-stage
    }

    #pragma unroll
    for (int m = 0; m < 4; ++m) {
        int rbase = bm + wr + m * 16 + fq * 4;
        #pragma unroll
        for (int n = 0; n < 4; ++n) {
            int col = bn + wc + n * 16 + fr;
            if (col >= N) continue;
            #pragma unroll
            for (int j = 0; j < 4; ++j)
                C[((size_t)blockIdx.z * M + rbase + j) * ldc + col] = acc[m][n][j];
        }
    }
}

// ---------------------------------------------------------------------------
__global__ __launch_bounds__(256) void reduce4(
    const float* __restrict__ p, float* __restrict__ o, int n)
{
    int i = blockIdx.x * 256 + threadIdx.x;
    if (i >= n) return;
    o[i] = ((p[i] + p[i + n]) + (p[i + 2 * n] + p[i + 3 * n]));
}

// ---------------------------------------------------------------------------
// Depthwise causal conv (k=4) + bias + SiLU -> u as bf16 hi/lo.
// ---------------------------------------------------------------------------
__global__ __launch_bounds__(256) void conv_silu(
    const float* __restrict__ xz, const float* __restrict__ w,
    const float* __restrict__ bias, ushort* __restrict__ uh,
    ushort* __restrict__ ul)
{
    int idx = blockIdx.x * 256 + threadIdx.x;
    if (idx >= B_ * L_ * DI) return;
    int d  = idx & (DI - 1);
    int bl = idx >> 11;
    int l  = bl & (L_ - 1);

    const float w0 = w[d * 4 + 0], w1 = w[d * 4 + 1];
    const float w2 = w[d * 4 + 2], w3 = w[d * 4 + 3];
    float s = bias[d];
    size_t base = (size_t)bl * 4096 + d;
    if (l >= 3) s = fmaf(w0, xz[base - 3 * 4096], s);
    if (l >= 2) s = fmaf(w1, xz[base - 2 * 4096], s);
    if (l >= 1) s = fmaf(w2, xz[base - 1 * 4096], s);
    s = fmaf(w3, xz[base], s);
    float v = s / (1.f + __expf(-s));
    ushort h = f2bf(v);
    uh[idx] = h;
    ul[idx] = f2bf(v - bf2f(h));
}

// ---------------------------------------------------------------------------
__global__ __launch_bounds__(256) void softplus_bias(
    float* __restrict__ delta, const float* __restrict__ b_dt)
{
    int idx = blockIdx.x * 256 + threadIdx.x;
    if (idx >= B_ * L_ * DI) return;
    int d = idx & (DI - 1);
    float v = delta[idx] + b_dt[d];
    delta[idx] = (v > 20.f) ? v : log1pf(__expf(v));
}

// ---------------------------------------------------------------------------
// Scan phase A: per-(b,d,n,chunk) partials. idx bits: n:4 | d:11 | c:3 | b:1
// ---------------------------------------------------------------------------
__global__ __launch_bounds__(256) void scan_partial(
    const float* __restrict__ delta, const ushort* __restrict__ uh,
    const ushort* __restrict__ ul, const float* __restrict__ xdbl,
    const float* __restrict__ A_log, float* __restrict__ sA,
    float* __restrict__ sH)
{
    int idx = blockIdx.x * 256 + threadIdx.x;
    int n = idx & 15;
    int d = (idx >> 4) & (DI - 1);
    int c = (idx >> 15) & (NC - 1);
    int b = idx >> 18;

    const float Adn = -__expf(A_log[d * DS + n]);
    float aP = 1.f, h = 0.f;
    size_t pd = ((size_t)b * L_ + c * CL) * DI + d;
    size_t px = ((size_t)b * L_ + c * CL) * 96;
    for (int t = 0; t < CL; ++t) {
        float dv = delta[pd];
        float uv = bf2f(uh[pd]) + bf2f(ul[pd]);
        float Bn = xdbl[px + DR + n];
        float dA = __expf(dv * Adn);
        aP *= dA;
        h = fmaf(dA, h, dv * uv * Bn);
        pd += DI; px += 96;
    }
    int o = ((c * B_ + b) * DI + d) * DS + n;
    sA[o] = aP; sH[o] = h;
}

// ---------------------------------------------------------------------------
__global__ __launch_bounds__(256) void scan_combine(
    const float* __restrict__ sA, const float* __restrict__ sH,
    float* __restrict__ hinit)
{
    int idx = blockIdx.x * 256 + threadIdx.x;   // (b,d,n)
    int n = idx & 15;
    int d = (idx >> 4) & (DI - 1);
    int b = idx >> 15;
    float h = 0.f;
    #pragma unroll
    for (int c = 0; c < NC; ++c) {
        int o = ((c * B_ + b) * DI + d) * DS + n;
        hinit[o] = h;
        h = fmaf(sA[o], h, sH[o]);
    }
}

// ---------------------------------------------------------------------------
// Scan phase C: recompute chunk from h_init, reduce over n, skip+gate.
// y may alias delta (read-before-write per index).
// ---------------------------------------------------------------------------
__global__ __launch_bounds__(256) void scan_final(
    const float* __restrict__ delta, const ushort* __restrict__ uh,
    const ushort* __restrict__ ul, const float* __restrict__ xdbl,
    const float* __restrict__ xz, const float* __restrict__ A_log,
    const float* __restrict__ D_skip, const float* __restrict__ hinit,
    float* __restrict__ y)
{
    int tid = threadIdx.x;
    int n = tid & 15;
    int gi = blockIdx.x * 16 + (tid >> 4);   // (b,c,d), d fastest
    int d = gi & (DI - 1);
    int c = (gi >> 11) & (NC - 1);
    int b = gi >> 14;

    const float Adn = -__expf(A_log[d * DS + n]);
    const float Dd  = D_skip[d];
    float h = hinit[((c * B_ + b) * DI + d) * DS + n];

    size_t pd = ((size_t)b * L_ + c * CL) * DI + d;
    size_t px = ((size_t)b * L_ + c * CL) * 96;
    size_t pz = ((size_t)b * L_ + c * CL) * 4096 + 2048 + d;
    for (int t = 0; t < CL; ++t) {
        float dv = delta[pd];
        float uv = bf2f(uh[pd]) + bf2f(ul[pd]);
        float Bn = xdbl[px + DR + n];
        float Cn = xdbl[px + DR + DS + n];
        float dA = __expf(dv * Adn);
        h = fmaf(dA, h, dv * uv * Bn);
        float part = h * Cn;
        part += __shfl_xor(part, 1);
        part += __shfl_xor(part, 2);
        part += __shfl_xor(part, 4);
        part += __shfl_xor(part, 8);
        if (n == 0) {
            float zv = xz[pz];
            float yv = part + Dd * uv;
            yv *= zv / (1.f + __expf(-zv));
            y[pd] = yv;
        }
        pd += DI; px += 96; pz += 4096;
    }
}

// ---------------------------------------------------------------------------
extern "C" void kernel_launch(void* const* d_in, const int* in_sizes, int n_in,
                              void* d_out, int out_size, void* d_ws, size_t ws_size,
                              hipStream_t stream)
{
    const float* x      = (const float*)d_in[0];
    const float* W_in   = (const float*)d_in[1];
    const float* conv_w = (const float*)d_in[2];
    const float* conv_b = (const float*)d_in[3];
    const float* W_xprj = (const float*)d_in[4];
    const float* W_dt   = (const float*)d_in[5];
    const float* b_dt   = (const float*)d_in[6];
    const float* A_log  = (const float*)d_in[7];
    const float* D_skip = (const float*)d_in[8];
    const float* W_out  = (const float*)d_in[9];
    float* out = (float*)d_out;

    char* ws = (char*)d_ws;
    float*  xz    = (float*)(ws + 0);            // 32M
    float*  delta = (float*)(ws + 33554432);     // 16M (later aliased as y)
    float*  xdbl  = (float*)(ws + 50331648);     // 768K
    float*  sA    = (float*)(ws + 51118080);     // 2M
    float*  sH    = (float*)(ws + 53215232);     // 2M
    float*  hin   = (float*)(ws + 55312384);     // 2M
    ushort* Xh    = (ushort*)(ws + 57409536);    // 4M  } x bf16
    ushort* Xl    = (ushort*)(ws + 61603840);    // 4M  }
    float*  parts = (float*)(ws + 57409536);     // 3M   alias (after GEMM1)
    ushort* Woh   = (ushort*)(ws + 57409536);    // 4M   alias (after reduce)
    ushort* Wol   = (ushort*)(ws + 61603840);    // 4M
    ushort* WIh   = (ushort*)(ws + 65798144);    // 8M  } W_in^T bf16
    ushort* WIl   = (ushort*)(ws + 74186752);    // 8M  }
    ushort* Yh    = (ushort*)(ws + 65798144);    //      alias (after GEMM1)
    ushort* Yl    = (ushort*)(ws + 74186752);
    ushort* Uh    = (ushort*)(ws + 82575360);    // 8M  } u bf16
    ushort* Ul    = (ushort*)(ws + 90963968);    // 8M  }
    ushort* WXh   = (ushort*)(ws + 99352576);    // 512K
    ushort* WXl   = (ushort*)(ws + 99876864);    // 512K
    ushort* DTh   = (ushort*)(ws + 100401152);   // 256K
    ushort* DTl   = (ushort*)(ws + 100657664);   // 256K
    ushort* WDh   = (ushort*)(ws + 100914176);   // 256K
    ushort* WDl   = (ushort*)(ws + 101170688);   // 256K (end ~96.7 MB)
    float*  y     = delta;

    dim3 blk(256);
    dim3 blkT(32, 8);
    const int M = B_ * L_;   // 2048

    // ---- convert x and W_in ----
    convA<<<dim3(262144 / 256), blk, 0, stream>>>(x, DM, Xh, Xl, 7, 262144);
    convBT<<<dim3(4096 / 32, DM / 32), blkT, 0, stream>>>(W_in, WIh, WIl, DM, 4096, 4096);

    // ---- xz = x @ W_in : (2048x1024)@(1024x4096) ----
    gemm_bt<<<dim3(32, 16, 1), blk, 0, stream>>>(
        Xh, Xl, WIh, WIl, xz, M, 4096, DM, DM, 4096, DM);

    // ---- u = silu(conv(x_in)+b) -> bf16 hi/lo ----
    conv_silu<<<dim3((B_ * L_ * DI) / 256), blk, 0, stream>>>(xz, conv_w, conv_b, Uh, Ul);

    // ---- x_dbl = u @ W_xproj : split-K x4 ----
    convBT<<<dim3(128 / 32, DI / 32), blkT, 0, stream>>>(W_xprj, WXh, WXl, DI, 96, 128);
    gemm_bt<<<dim3(1, 16, 4), blk, 0, stream>>>(
        Uh, Ul, WXh, WXl, parts, M, 96, DI, DI, 96, 512);
    reduce4<<<dim3(196608 / 256), blk, 0, stream>>>(parts, xdbl, M * 96);

    // ---- delta_raw = dt_lr @ W_dt : (2048x64)@(64x2048) ----
    convA<<<dim3(16384 / 256), blk, 0, stream>>>(xdbl, 96, DTh, DTl, 3, 16384);
    convBT<<<dim3(DI / 32, DR / 32), blkT, 0, stream>>>(W_dt, WDh, WDl, DR, DI, DI);
    gemm_bt<<<dim3(16, 16, 1), blk, 0, stream>>>(
        DTh, DTl, WDh, WDl, delta, M, DI, DR, DR, DI, DR);

    // ---- delta = softplus(delta_raw + b_dt) ----
    softplus_bias<<<dim3((B_ * L_ * DI) / 256), blk, 0, stream>>>(delta, b_dt);

    // ---- chunked selective scan ----
    scan_partial<<<dim3((B_ * DI * DS * NC) / 256), blk, 0, stream>>>(
        delta, Uh, Ul, xdbl, A_log, sA, sH);
    scan_combine<<<dim3((B_ * DI * DS) / 256), blk, 0, stream>>>(sA, sH, hin);
    scan_final<<<dim3((B_ * DI * NC) / 16), blk, 0, stream>>>(
        delta, Uh, Ul, xdbl, xz, A_log, D_skip, hin, y);

    // ---- out = y @ W_out : (2048x2048)@(2048x1024) ----
    convA<<<dim3(524288 / 256), blk, 0, stream>>>(y, DI, Yh, Yl, 8, 524288);
    convBT<<<dim3(DM / 32, DI / 32), blkT, 0, stream>>>(W_out, Woh, Wol, DI, DM, DM);
    gemm_bt<<<dim3(8, 16, 1), blk, 0, stream>>>(
        Yh, Yl, Woh, Wol, out, M, DM, DI, DI, DM, DI);
}

// Round 4
// 311.486 us; speedup vs baseline: 6.2115x; 1.2118x over previous
//
#include <hip/hip_runtime.h>
#include <cmath>

#define B_  2
#define L_  1024
#define DM  1024
#define DI  2048
#define DS  16
#define DR  64
#define NC  32         // scan time-chunks
#define CL  (L_/NC)    // 32 steps per chunk

typedef __attribute__((ext_vector_type(8))) short short8;
typedef __attribute__((ext_vector_type(4))) float f32x4;

static __device__ __forceinline__ ushort f2bf(float f) {
    union { float f; unsigned u; } c; c.f = f;
    unsigned u = c.u;
    return (ushort)((u + 0x7fffu + ((u >> 16) & 1u)) >> 16);   // RNE
}
static __device__ __forceinline__ float bf2f(ushort h) {
    union { unsigned u; float f; } c; c.u = ((unsigned)h) << 16;
    return c.f;
}

// pack 8 floats -> hi/lo bf16 uint4s
static __device__ __forceinline__ void cvt8(const float* v, uint4& hi, uint4& lo) {
    unsigned h[4], l[4];
    #pragma unroll
    for (int j = 0; j < 4; ++j) {
        ushort h0 = f2bf(v[2*j]),   h1 = f2bf(v[2*j+1]);
        ushort l0 = f2bf(v[2*j]   - bf2f(h0));
        ushort l1 = f2bf(v[2*j+1] - bf2f(h1));
        h[j] = (unsigned)h0 | ((unsigned)h1 << 16);
        l[j] = (unsigned)l0 | ((unsigned)l1 << 16);
    }
    hi = make_uint4(h[0], h[1], h[2], h[3]);
    lo = make_uint4(l[0], l[1], l[2], l[3]);
}

static __device__ __forceinline__ float softplus_f(float v) {
    return (v > 20.f) ? v : log1pf(__expf(v));
}

// ---------------------------------------------------------------------------
// convA: fp32 [R][C] (leading dim ld) -> bf16 hi/lo [R][C] row-major.
// ---------------------------------------------------------------------------
__global__ __launch_bounds__(256) void convA(
    const float* __restrict__ in, int ld, ushort* __restrict__ oh,
    ushort* __restrict__ ol, int c8sh, int total)
{
    int v = blockIdx.x * 256 + threadIdx.x;
    if (v >= total) return;
    int r  = v >> c8sh;
    int c8 = v & ((1 << c8sh) - 1);
    const float* p = in + (size_t)r * ld + c8 * 8;
    float4 v0 = *(const float4*)p;
    float4 v1 = *(const float4*)(p + 4);
    float vv[8] = {v0.x, v0.y, v0.z, v0.w, v1.x, v1.y, v1.z, v1.w};
    uint4 hi, lo; cvt8(vv, hi, lo);
    size_t o = ((size_t)r << c8sh << 3) + c8 * 8;
    *(uint4*)&oh[o] = hi;
    *(uint4*)&ol[o] = lo;
}

// ---------------------------------------------------------------------------
// convBT: fp32 [K][N] -> bf16 hi/lo [Npad][K] (transposed). 32x32 LDS tiles.
// ---------------------------------------------------------------------------
__global__ __launch_bounds__(256) void convBT(
    const float* __restrict__ in, ushort* __restrict__ oh,
    ushort* __restrict__ ol, int K, int N, int Npad)
{
    __shared__ float t[32][33];
    int tx = threadIdx.x, ty = threadIdx.y;
    int n0 = blockIdx.x * 32, k0 = blockIdx.y * 32;
    #pragma unroll
    for (int i = 0; i < 4; ++i) {
        int k = k0 + ty * 4 + i, n = n0 + tx;
        t[ty * 4 + i][tx] = (n < N) ? in[(size_t)k * N + n] : 0.f;
    }
    __syncthreads();
    #pragma unroll
    for (int i = 0; i < 4; ++i) {
        int r = n0 + ty * 4 + i;
        int c = k0 + tx;
        if (r < Npad) {
            float v = t[tx][ty * 4 + i];
            ushort h = f2bf(v);
            oh[(size_t)r * K + c] = h;
            ol[(size_t)r * K + c] = f2bf(v - bf2f(h));
        }
    }
}

// ---------------------------------------------------------------------------
// GEMM: C[M][N] = A[M][K] @ B[N][K]^T, bf16x3 split (fp32-accurate).
// ---------------------------------------------------------------------------
static __device__ __forceinline__ void stage_tile(
    ushort* lds, const ushort* __restrict__ g, int ld, int row0, int k0,
    int wid, int lane)
{
    #pragma unroll
    for (int it = 0; it < 2; ++it) {
        int o  = wid * 2048 + it * 1024;
        int ob = o + lane * 16;
        int a  = ob ^ (((ob >> 7) & 7) << 4);
        int row = a >> 6;
        int lc  = (a >> 4) & 3;
        const ushort* gp = g + (size_t)(row0 + row) * ld + k0 + lc * 8;
        __builtin_amdgcn_global_load_lds(
            (const __attribute__((address_space(1))) void*)gp,
            (__attribute__((address_space(3))) void*)((char*)lds + o),
            16, 0, 0);
    }
}

static __device__ __forceinline__ short8 frag(const ushort* lds, int row, int fq) {
    int a = row * 64 + fq * 16;
    int b = a ^ (((a >> 7) & 7) << 4);
    return *(const short8*)((const char*)lds + b);
}

__global__ __launch_bounds__(256) void gemm_bt(
    const ushort* __restrict__ Ah, const ushort* __restrict__ Al,
    const ushort* __restrict__ Bh, const ushort* __restrict__ Bl,
    float* __restrict__ C, int M, int N, int lda, int ldb, int ldc, int kspl)
{
    __shared__ ushort sm[16384];
    ushort* sAh = sm;         ushort* sAl = sm + 4096;
    ushort* sBh = sm + 8192;  ushort* sBl = sm + 12288;

    const int tid = threadIdx.x, wid = tid >> 6, lane = tid & 63;
    const int bm = blockIdx.y * 128, bn = blockIdx.x * 128;
    const int kb = blockIdx.z * kspl;
    const int wr = (wid >> 1) * 64, wc = (wid & 1) * 64;
    const int fr = lane & 15, fq = lane >> 4;

    f32x4 acc[4][4] = {};

    for (int k0 = 0; k0 < kspl; k0 += 32) {
        stage_tile(sAh, Ah, lda, bm, kb + k0, wid, lane);
        stage_tile(sAl, Al, lda, bm, kb + k0, wid, lane);
        stage_tile(sBh, Bh, ldb, bn, kb + k0, wid, lane);
        stage_tile(sBl, Bl, ldb, bn, kb + k0, wid, lane);
        __syncthreads();

        short8 a_h[4], a_l[4], b_h[4], b_l[4];
        #pragma unroll
        for (int m = 0; m < 4; ++m) {
            a_h[m] = frag(sAh, wr + m * 16 + fr, fq);
            a_l[m] = frag(sAl, wr + m * 16 + fr, fq);
        }
        #pragma unroll
        for (int n = 0; n < 4; ++n) {
            b_h[n] = frag(sBh, wc + n * 16 + fr, fq);
            b_l[n] = frag(sBl, wc + n * 16 + fr, fq);
        }
        #pragma unroll
        for (int m = 0; m < 4; ++m)
            #pragma unroll
            for (int n = 0; n < 4; ++n) {
                acc[m][n] = __builtin_amdgcn_mfma_f32_16x16x32_bf16(a_h[m], b_h[n], acc[m][n], 0, 0, 0);
                acc[m][n] = __builtin_amdgcn_mfma_f32_16x16x32_bf16(a_h[m], b_l[n], acc[m][n], 0, 0, 0);
                acc[m][n] = __builtin_amdgcn_mfma_f32_16x16x32_bf16(a_l[m], b_h[n], acc[m][n], 0, 0, 0);
            }
        __syncthreads();
    }

    #pragma unroll
    for (int m = 0; m < 4; ++m) {
        int rbase = bm + wr + m * 16 + fq * 4;
        #pragma unroll
        for (int n = 0; n < 4; ++n) {
            int col = bn + wc + n * 16 + fr;
            if (col >= N) continue;
            #pragma unroll
            for (int j = 0; j < 4; ++j)
                C[((size_t)blockIdx.z * M + rbase + j) * ldc + col] = acc[m][n][j];
        }
    }
}

// ---------------------------------------------------------------------------
__global__ __launch_bounds__(256) void reduce4(
    const float* __restrict__ p, float* __restrict__ o, int n)
{
    int i = blockIdx.x * 256 + threadIdx.x;
    if (i >= n) return;
    o[i] = ((p[i] + p[i + n]) + (p[i + 2 * n] + p[i + 3 * n]));
}

// ---------------------------------------------------------------------------
// Depthwise causal conv (k=4) + bias + SiLU -> u as bf16 hi/lo.
// ---------------------------------------------------------------------------
__global__ __launch_bounds__(256) void conv_silu(
    const float* __restrict__ xz, const float* __restrict__ w,
    const float* __restrict__ bias, ushort* __restrict__ uh,
    ushort* __restrict__ ul)
{
    int idx = blockIdx.x * 256 + threadIdx.x;
    if (idx >= B_ * L_ * DI) return;
    int d  = idx & (DI - 1);
    int bl = idx >> 11;
    int l  = bl & (L_ - 1);

    const float w0 = w[d * 4 + 0], w1 = w[d * 4 + 1];
    const float w2 = w[d * 4 + 2], w3 = w[d * 4 + 3];
    float s = bias[d];
    size_t base = (size_t)bl * 4096 + d;
    if (l >= 3) s = fmaf(w0, xz[base - 3 * 4096], s);
    if (l >= 2) s = fmaf(w1, xz[base - 2 * 4096], s);
    if (l >= 1) s = fmaf(w2, xz[base - 1 * 4096], s);
    s = fmaf(w3, xz[base], s);
    float v = s / (1.f + __expf(-s));
    ushort h = f2bf(v);
    uh[idx] = h;
    ul[idx] = f2bf(v - bf2f(h));
}

// ---------------------------------------------------------------------------
// Scan phase A: lane owns channel d for chunk c. h[16], Adn[16] in regs.
// delta is RAW (softplus fused here). aP via exp(Adn * sum_t dv) (exact).
// grid: 512 blocks = b(1b) | c(5b) | dblk(3b); 256 threads = d within slice.
// ---------------------------------------------------------------------------
__global__ __launch_bounds__(256) void scan_partial(
    const float* __restrict__ delta, const ushort* __restrict__ uh,
    const ushort* __restrict__ ul, const float* __restrict__ xdbl,
    const float* __restrict__ A_log, const float* __restrict__ b_dt,
    float* __restrict__ sA, float* __restrict__ sH)
{
    __shared__ float Bs[CL][16];
    const int tid  = threadIdx.x;
    const int dblk = blockIdx.x & 7;
    const int c    = (blockIdx.x >> 3) & (NC - 1);
    const int b    = blockIdx.x >> 8;
    const int d    = dblk * 256 + tid;
    const int bl0  = b * L_ + c * CL;

    for (int i = tid; i < CL * 16; i += 256) {
        int t = i >> 4, n = i & 15;
        Bs[t][n] = xdbl[(size_t)(bl0 + t) * 96 + DR + n];
    }
    __syncthreads();

    float Adn[16];
    #pragma unroll
    for (int q = 0; q < 4; ++q) {
        float4 al = *(const float4*)&A_log[d * DS + q * 4];
        Adn[q * 4 + 0] = -__expf(al.x);
        Adn[q * 4 + 1] = -__expf(al.y);
        Adn[q * 4 + 2] = -__expf(al.z);
        Adn[q * 4 + 3] = -__expf(al.w);
    }
    const float bd = b_dt[d];
    float h[16];
    #pragma unroll
    for (int n = 0; n < 16; ++n) h[n] = 0.f;
    float S = 0.f;

    size_t pd = (size_t)bl0 * DI + d;
    for (int t = 0; t < CL; ++t) {
        float dv = softplus_f(delta[pd] + bd);
        float uv = bf2f(uh[pd]) + bf2f(ul[pd]);
        float du = dv * uv;
        S += dv;
        float Bv[16];
        *(float4*)&Bv[0]  = *(const float4*)&Bs[t][0];
        *(float4*)&Bv[4]  = *(const float4*)&Bs[t][4];
        *(float4*)&Bv[8]  = *(const float4*)&Bs[t][8];
        *(float4*)&Bv[12] = *(const float4*)&Bs[t][12];
        #pragma unroll
        for (int n = 0; n < 16; ++n) {
            float dA = __expf(dv * Adn[n]);
            h[n] = fmaf(dA, h[n], du * Bv[n]);
        }
        pd += DI;
    }

    size_t o = (((size_t)c * B_ + b) * DI + d) * DS;
    float aP[16], hh[16];
    #pragma unroll
    for (int n = 0; n < 16; ++n) { aP[n] = __expf(S * Adn[n]); hh[n] = h[n]; }
    #pragma unroll
    for (int q = 0; q < 4; ++q) {
        *(float4*)&sA[o + q * 4] = *(float4*)&aP[q * 4];
        *(float4*)&sH[o + q * 4] = *(float4*)&hh[q * 4];
    }
}

// ---------------------------------------------------------------------------
// Scan phase B: serial combine over chunks -> h_init per chunk.
// ---------------------------------------------------------------------------
__global__ __launch_bounds__(256) void scan_combine(
    const float* __restrict__ sA, const float* __restrict__ sH,
    float* __restrict__ hinit)
{
    int idx = blockIdx.x * 256 + threadIdx.x;   // (b,d,n)
    int n = idx & 15;
    int d = (idx >> 4) & (DI - 1);
    int b = idx >> 15;
    float h = 0.f;
    #pragma unroll
    for (int c = 0; c < NC; ++c) {
        size_t o = (((size_t)c * B_ + b) * DI + d) * DS + n;
        hinit[o] = h;
        h = fmaf(sA[o], h, sH[o]);
    }
}

// ---------------------------------------------------------------------------
// Scan phase C: lane owns channel; rescan chunk from h_init; y-dot in regs;
// skip + z-gate fused. y aliases delta (same-index read-then-write).
// ---------------------------------------------------------------------------
__global__ __launch_bounds__(256) void scan_final(
    const float* __restrict__ delta, const ushort* __restrict__ uh,
    const ushort* __restrict__ ul, const float* __restrict__ xdbl,
    const float* __restrict__ xz, const float* __restrict__ A_log,
    const float* __restrict__ b_dt, const float* __restrict__ D_skip,
    const float* __restrict__ hinit, float* __restrict__ y)
{
    __shared__ float Bs[CL][16];
    __shared__ float Cs[CL][16];
    const int tid  = threadIdx.x;
    const int dblk = blockIdx.x & 7;
    const int c    = (blockIdx.x >> 3) & (NC - 1);
    const int b    = blockIdx.x >> 8;
    const int d    = dblk * 256 + tid;
    const int bl0  = b * L_ + c * CL;

    for (int i = tid; i < CL * 16; i += 256) {
        int t = i >> 4, n = i & 15;
        size_t px = (size_t)(bl0 + t) * 96 + DR + n;
        Bs[t][n] = xdbl[px];
        Cs[t][n] = xdbl[px + DS];
    }
    __syncthreads();

    float Adn[16];
    #pragma unroll
    for (int q = 0; q < 4; ++q) {
        float4 al = *(const float4*)&A_log[d * DS + q * 4];
        Adn[q * 4 + 0] = -__expf(al.x);
        Adn[q * 4 + 1] = -__expf(al.y);
        Adn[q * 4 + 2] = -__expf(al.z);
        Adn[q * 4 + 3] = -__expf(al.w);
    }
    const float bd = b_dt[d];
    const float Dd = D_skip[d];

    float h[16];
    size_t o = (((size_t)c * B_ + b) * DI + d) * DS;
    #pragma unroll
    for (int q = 0; q < 4; ++q)
        *(float4*)&h[q * 4] = *(const float4*)&hinit[o + q * 4];

    size_t pd = (size_t)bl0 * DI + d;
    size_t pz = (size_t)bl0 * 4096 + 2048 + d;
    for (int t = 0; t < CL; ++t) {
        float dv = softplus_f(delta[pd] + bd);
        float uv = bf2f(uh[pd]) + bf2f(ul[pd]);
        float du = dv * uv;
        float Bv[16], Cv[16];
        *(float4*)&Bv[0]  = *(const float4*)&Bs[t][0];
        *(float4*)&Bv[4]  = *(const float4*)&Bs[t][4];
        *(float4*)&Bv[8]  = *(const float4*)&Bs[t][8];
        *(float4*)&Bv[12] = *(const float4*)&Bs[t][12];
        *(float4*)&Cv[0]  = *(const float4*)&Cs[t][0];
        *(float4*)&Cv[4]  = *(const float4*)&Cs[t][4];
        *(float4*)&Cv[8]  = *(const float4*)&Cs[t][8];
        *(float4*)&Cv[12] = *(const float4*)&Cs[t][12];
        float acc = 0.f;
        #pragma unroll
        for (int n = 0; n < 16; ++n) {
            float dA = __expf(dv * Adn[n]);
            h[n] = fmaf(dA, h[n], du * Bv[n]);
            acc = fmaf(h[n], Cv[n], acc);
        }
        float zv = xz[pz];
        float yv = acc + Dd * uv;
        yv *= zv / (1.f + __expf(-zv));
        y[pd] = yv;
        pd += DI; pz += 4096;
    }
}

// ---------------------------------------------------------------------------
extern "C" void kernel_launch(void* const* d_in, const int* in_sizes, int n_in,
                              void* d_out, int out_size, void* d_ws, size_t ws_size,
                              hipStream_t stream)
{
    const float* x      = (const float*)d_in[0];
    const float* W_in   = (const float*)d_in[1];
    const float* conv_w = (const float*)d_in[2];
    const float* conv_b = (const float*)d_in[3];
    const float* W_xprj = (const float*)d_in[4];
    const float* W_dt   = (const float*)d_in[5];
    const float* b_dt   = (const float*)d_in[6];
    const float* A_log  = (const float*)d_in[7];
    const float* D_skip = (const float*)d_in[8];
    const float* W_out  = (const float*)d_in[9];
    float* out = (float*)d_out;

    char* ws = (char*)d_ws;
    float*  xz    = (float*)(ws + 0);            // 32M
    float*  delta = (float*)(ws + 33554432);     // 16M raw delta; y aliases
    float*  xdbl  = (float*)(ws + 50331648);     // 768K
    // scan scratch (8M each) aliases Xh/Xl/WIh/WIl/parts (dead by scan time)
    float*  sA    = (float*)(ws + 57409536);
    float*  sH    = (float*)(ws + 65798144);
    float*  hin   = (float*)(ws + 74186752);     // end 82575360
    ushort* Xh    = (ushort*)(ws + 57409536);    // 4M
    ushort* Xl    = (ushort*)(ws + 61603840);    // 4M
    float*  parts = (float*)(ws + 57409536);     // 3M (xproj split-K)
    ushort* WIh   = (ushort*)(ws + 65798144);    // 8M
    ushort* WIl   = (ushort*)(ws + 74186752);    // 8M
    ushort* Uh    = (ushort*)(ws + 82575360);    // 8M
    ushort* Ul    = (ushort*)(ws + 90963968);    // 8M
    ushort* WXh   = (ushort*)(ws + 99352576);    // 512K
    ushort* WXl   = (ushort*)(ws + 99876864);    // 512K
    ushort* DTh   = (ushort*)(ws + 100401152);   // 256K
    ushort* DTl   = (ushort*)(ws + 100657664);   // 256K
    ushort* WDh   = (ushort*)(ws + 100914176);   // 256K
    ushort* WDl   = (ushort*)(ws + 101170688);   // 256K (end 101427200)
    // post-scan aliases (scan scratch dead):
    ushort* Yh    = (ushort*)(ws + 57409536);    // 8M
    ushort* Yl    = (ushort*)(ws + 65798144);    // 8M
    ushort* Woh   = (ushort*)(ws + 74186752);    // 4M
    ushort* Wol   = (ushort*)(ws + 78381056);    // 4M
    float*  y     = delta;

    dim3 blk(256);
    dim3 blkT(32, 8);
    const int M = B_ * L_;   // 2048

    // ---- convert x and W_in ----
    convA<<<dim3(262144 / 256), blk, 0, stream>>>(x, DM, Xh, Xl, 7, 262144);
    convBT<<<dim3(4096 / 32, DM / 32), blkT, 0, stream>>>(W_in, WIh, WIl, DM, 4096, 4096);

    // ---- xz = x @ W_in ----
    gemm_bt<<<dim3(32, 16, 1), blk, 0, stream>>>(
        Xh, Xl, WIh, WIl, xz, M, 4096, DM, DM, 4096, DM);

    // ---- u = silu(conv(x_in)+b) -> bf16 hi/lo ----
    conv_silu<<<dim3((B_ * L_ * DI) / 256), blk, 0, stream>>>(xz, conv_w, conv_b, Uh, Ul);

    // ---- x_dbl = u @ W_xproj : split-K x4 ----
    convBT<<<dim3(128 / 32, DI / 32), blkT, 0, stream>>>(W_xprj, WXh, WXl, DI, 96, 128);
    gemm_bt<<<dim3(1, 16, 4), blk, 0, stream>>>(
        Uh, Ul, WXh, WXl, parts, M, 96, DI, DI, 96, 512);
    reduce4<<<dim3(196608 / 256), blk, 0, stream>>>(parts, xdbl, M * 96);

    // ---- delta_raw = dt_lr @ W_dt ----
    convA<<<dim3(16384 / 256), blk, 0, stream>>>(xdbl, 96, DTh, DTl, 3, 16384);
    convBT<<<dim3(DI / 32, DR / 32), blkT, 0, stream>>>(W_dt, WDh, WDl, DR, DI, DI);
    gemm_bt<<<dim3(16, 16, 1), blk, 0, stream>>>(
        DTh, DTl, WDh, WDl, delta, M, DI, DR, DR, DI, DR);

    // ---- chunked selective scan (softplus fused) ----
    scan_partial<<<dim3(B_ * NC * 8), blk, 0, stream>>>(
        delta, Uh, Ul, xdbl, A_log, b_dt, sA, sH);
    scan_combine<<<dim3((B_ * DI * DS) / 256), blk, 0, stream>>>(sA, sH, hin);
    scan_final<<<dim3(B_ * NC * 8), blk, 0, stream>>>(
        delta, Uh, Ul, xdbl, xz, A_log, b_dt, D_skip, hin, y);

    // ---- out = y @ W_out ----
    convA<<<dim3(524288 / 256), blk, 0, stream>>>(y, DI, Yh, Yl, 8, 524288);
    convBT<<<dim3(DM / 32, DI / 32), blkT, 0, stream>>>(W_out, Woh, Wol, DI, DM, DM);
    gemm_bt<<<dim3(8, 16, 1), blk, 0, stream>>>(
        Yh, Yl, Woh, Wol, out, M, DM, DI, DI, DM, DI);
}

// Round 5
// 264.409 us; speedup vs baseline: 7.3174x; 1.1780x over previous
//
#include <hip/hip_runtime.h>
#include <cmath>

#define B_  2
#define L_  1024
#define DM  1024
#define DI  2048
#define DS  16
#define DR  64
#define NC  32         // scan time-chunks
#define CL  (L_/NC)    // 32 steps per chunk

typedef __attribute__((ext_vector_type(8))) short short8;
typedef __attribute__((ext_vector_type(4))) float f32x4;

static __device__ __forceinline__ ushort f2bf(float f) {
    union { float f; unsigned u; } c; c.f = f;
    unsigned u = c.u;
    return (ushort)((u + 0x7fffu + ((u >> 16) & 1u)) >> 16);   // RNE
}
static __device__ __forceinline__ float bf2f(ushort h) {
    union { unsigned u; float f; } c; c.u = ((unsigned)h) << 16;
    return c.f;
}

// pack 8 floats -> hi/lo bf16 uint4s
static __device__ __forceinline__ void cvt8(const float* v, uint4& hi, uint4& lo) {
    unsigned h[4], l[4];
    #pragma unroll
    for (int j = 0; j < 4; ++j) {
        ushort h0 = f2bf(v[2*j]),   h1 = f2bf(v[2*j+1]);
        ushort l0 = f2bf(v[2*j]   - bf2f(h0));
        ushort l1 = f2bf(v[2*j+1] - bf2f(h1));
        h[j] = (unsigned)h0 | ((unsigned)h1 << 16);
        l[j] = (unsigned)l0 | ((unsigned)l1 << 16);
    }
    hi = make_uint4(h[0], h[1], h[2], h[3]);
    lo = make_uint4(l[0], l[1], l[2], l[3]);
}

static __device__ __forceinline__ float softplus_f(float v) {
    return (v > 20.f) ? v : log1pf(__expf(v));
}

// ---------------------------------------------------------------------------
// convA: fp32 [R][C] (leading dim ld) -> bf16 hi/lo [R][C] row-major.
// ---------------------------------------------------------------------------
__global__ __launch_bounds__(256) void convA(
    const float* __restrict__ in, int ld, ushort* __restrict__ oh,
    ushort* __restrict__ ol, int c8sh, int total)
{
    int v = blockIdx.x * 256 + threadIdx.x;
    if (v >= total) return;
    int r  = v >> c8sh;
    int c8 = v & ((1 << c8sh) - 1);
    const float* p = in + (size_t)r * ld + c8 * 8;
    float4 v0 = *(const float4*)p;
    float4 v1 = *(const float4*)(p + 4);
    float vv[8] = {v0.x, v0.y, v0.z, v0.w, v1.x, v1.y, v1.z, v1.w};
    uint4 hi, lo; cvt8(vv, hi, lo);
    size_t o = ((size_t)r << c8sh << 3) + c8 * 8;
    *(uint4*)&oh[o] = hi;
    *(uint4*)&ol[o] = lo;
}

// ---------------------------------------------------------------------------
// convBT: fp32 [K][N] -> bf16 hi/lo [Npad][K] (transposed). 32x32 LDS tiles.
// ---------------------------------------------------------------------------
__global__ __launch_bounds__(256) void convBT(
    const float* __restrict__ in, ushort* __restrict__ oh,
    ushort* __restrict__ ol, int K, int N, int Npad)
{
    __shared__ float t[32][33];
    int tx = threadIdx.x, ty = threadIdx.y;
    int n0 = blockIdx.x * 32, k0 = blockIdx.y * 32;
    #pragma unroll
    for (int i = 0; i < 4; ++i) {
        int k = k0 + ty * 4 + i, n = n0 + tx;
        t[ty * 4 + i][tx] = (n < N) ? in[(size_t)k * N + n] : 0.f;
    }
    __syncthreads();
    #pragma unroll
    for (int i = 0; i < 4; ++i) {
        int r = n0 + ty * 4 + i;
        int c = k0 + tx;
        if (r < Npad) {
            float v = t[tx][ty * 4 + i];
            ushort h = f2bf(v);
            oh[(size_t)r * K + c] = h;
            ol[(size_t)r * K + c] = f2bf(v - bf2f(h));
        }
    }
}

// ---------------------------------------------------------------------------
// GEMM: C[M][N] = A[M][K] @ B[N][K]^T, bf16x3 split (fp32-accurate).
// 128x128 tile, BK=32, 4 waves, double-buffered LDS (2-phase pipeline):
// issue next-tile global_load_lds BEFORE computing current tile; single
// barrier (with implicit vmcnt drain) per K-step. XOR-swizzle involution
// perm(a) = a ^ (((a>>7)&7)<<4) applied to source addr and frag read.
// ---------------------------------------------------------------------------
static __device__ __forceinline__ void stage_tile(
    ushort* lds, const ushort* __restrict__ g, int ld, int row0, int k0,
    int wid, int lane)
{
    #pragma unroll
    for (int it = 0; it < 2; ++it) {
        int o  = wid * 2048 + it * 1024;          // tile-local byte base
        int ob = o + lane * 16;
        int a  = ob ^ (((ob >> 7) & 7) << 4);     // logical byte address
        int row = a >> 6;
        int lc  = (a >> 4) & 3;
        const ushort* gp = g + (size_t)(row0 + row) * ld + k0 + lc * 8;
        __builtin_amdgcn_global_load_lds(
            (const __attribute__((address_space(1))) void*)gp,
            (__attribute__((address_space(3))) void*)((char*)lds + o),
            16, 0, 0);
    }
}

static __device__ __forceinline__ void stage_all(
    ushort* buf, const ushort* Ah, const ushort* Al, const ushort* Bh,
    const ushort* Bl, int lda, int ldb, int bm, int bn, int k,
    int wid, int lane)
{
    stage_tile(buf,         Ah, lda, bm, k, wid, lane);
    stage_tile(buf + 4096,  Al, lda, bm, k, wid, lane);
    stage_tile(buf + 8192,  Bh, ldb, bn, k, wid, lane);
    stage_tile(buf + 12288, Bl, ldb, bn, k, wid, lane);
}

static __device__ __forceinline__ short8 frag(const ushort* lds, int row, int fq) {
    int a = row * 64 + fq * 16;
    int b = a ^ (((a >> 7) & 7) << 4);
    return *(const short8*)((const char*)lds + b);
}

static __device__ __forceinline__ void compute_tile(
    const ushort* buf, int wr, int wc, int fr, int fq, f32x4 acc[4][4])
{
    const ushort* sAh = buf;        const ushort* sAl = buf + 4096;
    const ushort* sBh = buf + 8192; const ushort* sBl = buf + 12288;
    short8 a_h[4], a_l[4], b_h[4], b_l[4];
    #pragma unroll
    for (int m = 0; m < 4; ++m) {
        a_h[m] = frag(sAh, wr + m * 16 + fr, fq);
        a_l[m] = frag(sAl, wr + m * 16 + fr, fq);
    }
    #pragma unroll
    for (int n = 0; n < 4; ++n) {
        b_h[n] = frag(sBh, wc + n * 16 + fr, fq);
        b_l[n] = frag(sBl, wc + n * 16 + fr, fq);
    }
    #pragma unroll
    for (int m = 0; m < 4; ++m)
        #pragma unroll
        for (int n = 0; n < 4; ++n) {
            acc[m][n] = __builtin_amdgcn_mfma_f32_16x16x32_bf16(a_h[m], b_h[n], acc[m][n], 0, 0, 0);
            acc[m][n] = __builtin_amdgcn_mfma_f32_16x16x32_bf16(a_h[m], b_l[n], acc[m][n], 0, 0, 0);
            acc[m][n] = __builtin_amdgcn_mfma_f32_16x16x32_bf16(a_l[m], b_h[n], acc[m][n], 0, 0, 0);
        }
}

__global__ __launch_bounds__(256) void gemm_bt(
    const ushort* __restrict__ Ah, const ushort* __restrict__ Al,
    const ushort* __restrict__ Bh, const ushort* __restrict__ Bl,
    float* __restrict__ C, int M, int N, int lda, int ldb, int ldc, int kspl)
{
    __shared__ ushort sm[32768];                  // 64 KB: two 32 KB buffers

    const int tid = threadIdx.x, wid = tid >> 6, lane = tid & 63;
    const int bm = blockIdx.y * 128, bn = blockIdx.x * 128;
    const int kb = blockIdx.z * kspl;
    const int wr = (wid >> 1) * 64, wc = (wid & 1) * 64;
    const int fr = lane & 15, fq = lane >> 4;

    f32x4 acc[4][4] = {};

    stage_all(sm, Ah, Al, Bh, Bl, lda, ldb, bm, bn, kb, wid, lane);
    __syncthreads();                              // implicit vmcnt(0) drain
    int cur = 0;
    for (int k0 = 32; k0 < kspl; k0 += 32) {
        ushort* nbuf = (cur ? sm : sm + 16384);   // buffer being staged
        ushort* cbuf = (cur ? sm + 16384 : sm);   // buffer being computed
        stage_all(nbuf, Ah, Al, Bh, Bl, lda, ldb, bm, bn, kb + k0, wid, lane);
        compute_tile(cbuf, wr, wc, fr, fq, acc);
        __syncthreads();                          // drains stage loads too
        cur ^= 1;
    }
    compute_tile(cur ? sm + 16384 : sm, wr, wc, fr, fq, acc);

    #pragma unroll
    for (int m = 0; m < 4; ++m) {
        int rbase = bm + wr + m * 16 + fq * 4;
        #pragma unroll
        for (int n = 0; n < 4; ++n) {
            int col = bn + wc + n * 16 + fr;
            if (col >= N) continue;
            #pragma unroll
            for (int j = 0; j < 4; ++j)
                C[((size_t)blockIdx.z * M + rbase + j) * ldc + col] = acc[m][n][j];
        }
    }
}

// ---------------------------------------------------------------------------
__global__ __launch_bounds__(256) void reduceN(
    const float* __restrict__ p, float* __restrict__ o, int n, int nch)
{
    int i = blockIdx.x * 256 + threadIdx.x;
    if (i >= n) return;
    float s = 0.f;
    for (int c = 0; c < nch; ++c) s += p[i + (size_t)c * n];
    o[i] = s;
}

// ---------------------------------------------------------------------------
// Depthwise causal conv (k=4) + bias + SiLU -> u as bf16 hi/lo.
// ---------------------------------------------------------------------------
__global__ __launch_bounds__(256) void conv_silu(
    const float* __restrict__ xz, const float* __restrict__ w,
    const float* __restrict__ bias, ushort* __restrict__ uh,
    ushort* __restrict__ ul)
{
    int idx = blockIdx.x * 256 + threadIdx.x;
    if (idx >= B_ * L_ * DI) return;
    int d  = idx & (DI - 1);
    int bl = idx >> 11;
    int l  = bl & (L_ - 1);

    const float w0 = w[d * 4 + 0], w1 = w[d * 4 + 1];
    const float w2 = w[d * 4 + 2], w3 = w[d * 4 + 3];
    float s = bias[d];
    size_t base = (size_t)bl * 4096 + d;
    if (l >= 3) s = fmaf(w0, xz[base - 3 * 4096], s);
    if (l >= 2) s = fmaf(w1, xz[base - 2 * 4096], s);
    if (l >= 1) s = fmaf(w2, xz[base - 1 * 4096], s);
    s = fmaf(w3, xz[base], s);
    float v = s / (1.f + __expf(-s));
    ushort h = f2bf(v);
    uh[idx] = h;
    ul[idx] = f2bf(v - bf2f(h));
}

// ---------------------------------------------------------------------------
// Scan phase A: lane owns channel d for chunk c. h[16], Adn[16] in regs.
// softplus fused; chunk dA-product via exp(Adn * sum_t dv) (exact).
// ---------------------------------------------------------------------------
__global__ __launch_bounds__(256) void scan_partial(
    const float* __restrict__ delta, const ushort* __restrict__ uh,
    const ushort* __restrict__ ul, const float* __restrict__ xdbl,
    const float* __restrict__ A_log, const float* __restrict__ b_dt,
    float* __restrict__ sA, float* __restrict__ sH)
{
    __shared__ float Bs[CL][16];
    const int tid  = threadIdx.x;
    const int dblk = blockIdx.x & 7;
    const int c    = (blockIdx.x >> 3) & (NC - 1);
    const int b    = blockIdx.x >> 8;
    const int d    = dblk * 256 + tid;
    const int bl0  = b * L_ + c * CL;

    for (int i = tid; i < CL * 16; i += 256) {
        int t = i >> 4, n = i & 15;
        Bs[t][n] = xdbl[(size_t)(bl0 + t) * 96 + DR + n];
    }
    __syncthreads();

    float Adn[16];
    #pragma unroll
    for (int q = 0; q < 4; ++q) {
        float4 al = *(const float4*)&A_log[d * DS + q * 4];
        Adn[q * 4 + 0] = -__expf(al.x);
        Adn[q * 4 + 1] = -__expf(al.y);
        Adn[q * 4 + 2] = -__expf(al.z);
        Adn[q * 4 + 3] = -__expf(al.w);
    }
    const float bd = b_dt[d];
    float h[16];
    #pragma unroll
    for (int n = 0; n < 16; ++n) h[n] = 0.f;
    float S = 0.f;

    size_t pd = (size_t)bl0 * DI + d;
    for (int t = 0; t < CL; ++t) {
        float dv = softplus_f(delta[pd] + bd);
        float uv = bf2f(uh[pd]) + bf2f(ul[pd]);
        float du = dv * uv;
        S += dv;
        float Bv[16];
        *(float4*)&Bv[0]  = *(const float4*)&Bs[t][0];
        *(float4*)&Bv[4]  = *(const float4*)&Bs[t][4];
        *(float4*)&Bv[8]  = *(const float4*)&Bs[t][8];
        *(float4*)&Bv[12] = *(const float4*)&Bs[t][12];
        #pragma unroll
        for (int n = 0; n < 16; ++n) {
            float dA = __expf(dv * Adn[n]);
            h[n] = fmaf(dA, h[n], du * Bv[n]);
        }
        pd += DI;
    }

    size_t o = (((size_t)c * B_ + b) * DI + d) * DS;
    float aP[16], hh[16];
    #pragma unroll
    for (int n = 0; n < 16; ++n) { aP[n] = __expf(S * Adn[n]); hh[n] = h[n]; }
    #pragma unroll
    for (int q = 0; q < 4; ++q) {
        *(float4*)&sA[o + q * 4] = *(float4*)&aP[q * 4];
        *(float4*)&sH[o + q * 4] = *(float4*)&hh[q * 4];
    }
}

// ---------------------------------------------------------------------------
__global__ __launch_bounds__(256) void scan_combine(
    const float* __restrict__ sA, const float* __restrict__ sH,
    float* __restrict__ hinit)
{
    int idx = blockIdx.x * 256 + threadIdx.x;   // (b,d,n)
    int n = idx & 15;
    int d = (idx >> 4) & (DI - 1);
    int b = idx >> 15;
    float h = 0.f;
    #pragma unroll
    for (int c = 0; c < NC; ++c) {
        size_t o = (((size_t)c * B_ + b) * DI + d) * DS + n;
        hinit[o] = h;
        h = fmaf(sA[o], h, sH[o]);
    }
}

// ---------------------------------------------------------------------------
// Scan phase C: lane owns channel; rescan chunk from h_init; y-dot in regs;
// skip + z-gate fused; writes y directly as bf16 hi/lo (GEMM_out A-operand).
// ---------------------------------------------------------------------------
__global__ __launch_bounds__(256) void scan_final(
    const float* __restrict__ delta, const ushort* __restrict__ uh,
    const ushort* __restrict__ ul, const float* __restrict__ xdbl,
    const float* __restrict__ xz, const float* __restrict__ A_log,
    const float* __restrict__ b_dt, const float* __restrict__ D_skip,
    const float* __restrict__ hinit, ushort* __restrict__ yh,
    ushort* __restrict__ yl)
{
    __shared__ float Bs[CL][16];
    __shared__ float Cs[CL][16];
    const int tid  = threadIdx.x;
    const int dblk = blockIdx.x & 7;
    const int c    = (blockIdx.x >> 3) & (NC - 1);
    const int b    = blockIdx.x >> 8;
    const int d    = dblk * 256 + tid;
    const int bl0  = b * L_ + c * CL;

    for (int i = tid; i < CL * 16; i += 256) {
        int t = i >> 4, n = i & 15;
        size_t px = (size_t)(bl0 + t) * 96 + DR + n;
        Bs[t][n] = xdbl[px];
        Cs[t][n] = xdbl[px + DS];
    }
    __syncthreads();

    float Adn[16];
    #pragma unroll
    for (int q = 0; q < 4; ++q) {
        float4 al = *(const float4*)&A_log[d * DS + q * 4];
        Adn[q * 4 + 0] = -__expf(al.x);
        Adn[q * 4 + 1] = -__expf(al.y);
        Adn[q * 4 + 2] = -__expf(al.z);
        Adn[q * 4 + 3] = -__expf(al.w);
    }
    const float bd = b_dt[d];
    const float Dd = D_skip[d];

    float h[16];
    size_t o = (((size_t)c * B_ + b) * DI + d) * DS;
    #pragma unroll
    for (int q = 0; q < 4; ++q)
        *(float4*)&h[q * 4] = *(const float4*)&hinit[o + q * 4];

    size_t pd = (size_t)bl0 * DI + d;
    size_t pz = (size_t)bl0 * 4096 + 2048 + d;
    for (int t = 0; t < CL; ++t) {
        float dv = softplus_f(delta[pd] + bd);
        float uv = bf2f(uh[pd]) + bf2f(ul[pd]);
        float du = dv * uv;
        float Bv[16], Cv[16];
        *(float4*)&Bv[0]  = *(const float4*)&Bs[t][0];
        *(float4*)&Bv[4]  = *(const float4*)&Bs[t][4];
        *(float4*)&Bv[8]  = *(const float4*)&Bs[t][8];
        *(float4*)&Bv[12] = *(const float4*)&Bs[t][12];
        *(float4*)&Cv[0]  = *(const float4*)&Cs[t][0];
        *(float4*)&Cv[4]  = *(const float4*)&Cs[t][4];
        *(float4*)&Cv[8]  = *(const float4*)&Cs[t][8];
        *(float4*)&Cv[12] = *(const float4*)&Cs[t][12];
        float acc = 0.f;
        #pragma unroll
        for (int n = 0; n < 16; ++n) {
            float dA = __expf(dv * Adn[n]);
            h[n] = fmaf(dA, h[n], du * Bv[n]);
            acc = fmaf(h[n], Cv[n], acc);
        }
        float zv = xz[pz];
        float yv = acc + Dd * uv;
        yv *= zv / (1.f + __expf(-zv));
        ushort hh = f2bf(yv);
        yh[pd] = hh;
        yl[pd] = f2bf(yv - bf2f(hh));
        pd += DI; pz += 4096;
    }
}

// ---------------------------------------------------------------------------
extern "C" void kernel_launch(void* const* d_in, const int* in_sizes, int n_in,
                              void* d_out, int out_size, void* d_ws, size_t ws_size,
                              hipStream_t stream)
{
    const float* x      = (const float*)d_in[0];
    const float* W_in   = (const float*)d_in[1];
    const float* conv_w = (const float*)d_in[2];
    const float* conv_b = (const float*)d_in[3];
    const float* W_xprj = (const float*)d_in[4];
    const float* W_dt   = (const float*)d_in[5];
    const float* b_dt   = (const float*)d_in[6];
    const float* A_log  = (const float*)d_in[7];
    const float* D_skip = (const float*)d_in[8];
    const float* W_out  = (const float*)d_in[9];
    float* out = (float*)d_out;

    char* ws = (char*)d_ws;
    float*  xz    = (float*)(ws + 0);            // 32M
    float*  delta = (float*)(ws + 33554432);     // 16M raw delta
    float*  xdbl  = (float*)(ws + 50331648);     // 768K
    // pre-scan aliases of the 57.4M..82.6M region:
    ushort* Xh    = (ushort*)(ws + 57409536);    // 4M
    ushort* Xl    = (ushort*)(ws + 61603840);    // 4M
    float*  parts = (float*)(ws + 57409536);     // 6M (xproj split-K x8)
    ushort* WIh   = (ushort*)(ws + 65798144);    // 8M
    ushort* WIl   = (ushort*)(ws + 74186752);    // 8M
    // scan scratch (same region, pre-scan users dead):
    float*  sA    = (float*)(ws + 57409536);     // 8M
    float*  sH    = (float*)(ws + 65798144);     // 8M
    float*  hin   = (float*)(ws + 74186752);     // 8M (end 82575360)
    ushort* Uh    = (ushort*)(ws + 82575360);    // 8M
    ushort* Ul    = (ushort*)(ws + 90963968);    // 8M
    ushort* WXh   = (ushort*)(ws + 99352576);    // 512K
    ushort* WXl   = (ushort*)(ws + 99876864);    // 512K
    ushort* DTh   = (ushort*)(ws + 100401152);   // 256K
    ushort* DTl   = (ushort*)(ws + 100657664);   // 256K
    ushort* WDh   = (ushort*)(ws + 100914176);   // 256K
    ushort* WDl   = (ushort*)(ws + 101170688);   // 256K (end 101427200)
    // post-scan aliases:
    ushort* Yh    = (ushort*)(ws + 57409536);    // 8M (over sA; sA dead in phase C)
    ushort* Yl    = (ushort*)(ws + 65798144);    // 8M (over sH)
    ushort* Woh   = (ushort*)(ws + 74186752);    // 4M (over hin, after scan_final)
    ushort* Wol   = (ushort*)(ws + 78381056);    // 4M
    float*  parts2= (float*)(ws + 82575360);     // 16M (over Uh/Ul, after scan_final)

    dim3 blk(256);
    dim3 blkT(32, 8);
    const int M = B_ * L_;   // 2048

    // ---- convert x and W_in ----
    convA<<<dim3(262144 / 256), blk, 0, stream>>>(x, DM, Xh, Xl, 7, 262144);
    convBT<<<dim3(4096 / 32, DM / 32), blkT, 0, stream>>>(W_in, WIh, WIl, DM, 4096, 4096);

    // ---- xz = x @ W_in : (2048x1024)@(1024x4096) ----
    gemm_bt<<<dim3(32, 16, 1), blk, 0, stream>>>(
        Xh, Xl, WIh, WIl, xz, M, 4096, DM, DM, 4096, DM);

    // ---- u = silu(conv(x_in)+b) -> bf16 hi/lo ----
    conv_silu<<<dim3((B_ * L_ * DI) / 256), blk, 0, stream>>>(xz, conv_w, conv_b, Uh, Ul);

    // ---- x_dbl = u @ W_xproj : split-K x8 ----
    convBT<<<dim3(128 / 32, DI / 32), blkT, 0, stream>>>(W_xprj, WXh, WXl, DI, 96, 128);
    gemm_bt<<<dim3(1, 16, 8), blk, 0, stream>>>(
        Uh, Ul, WXh, WXl, parts, M, 96, DI, DI, 96, 256);
    reduceN<<<dim3(196608 / 256), blk, 0, stream>>>(parts, xdbl, M * 96, 8);

    // ---- delta_raw = dt_lr @ W_dt : (2048x64)@(64x2048) ----
    convA<<<dim3(16384 / 256), blk, 0, stream>>>(xdbl, 96, DTh, DTl, 3, 16384);
    convBT<<<dim3(DI / 32, DR / 32), blkT, 0, stream>>>(W_dt, WDh, WDl, DR, DI, DI);
    gemm_bt<<<dim3(16, 16, 1), blk, 0, stream>>>(
        DTh, DTl, WDh, WDl, delta, M, DI, DR, DR, DI, DR);

    // ---- chunked selective scan (softplus + y->bf16 fused) ----
    scan_partial<<<dim3(B_ * NC * 8), blk, 0, stream>>>(
        delta, Uh, Ul, xdbl, A_log, b_dt, sA, sH);
    scan_combine<<<dim3((B_ * DI * DS) / 256), blk, 0, stream>>>(sA, sH, hin);
    scan_final<<<dim3(B_ * NC * 8), blk, 0, stream>>>(
        delta, Uh, Ul, xdbl, xz, A_log, b_dt, D_skip, hin, Yh, Yl);

    // ---- out = y @ W_out : split-K x2 ----
    convBT<<<dim3(DM / 32, DI / 32), blkT, 0, stream>>>(W_out, Woh, Wol, DI, DM, DM);
    gemm_bt<<<dim3(8, 16, 2), blk, 0, stream>>>(
        Yh, Yl, Woh, Wol, parts2, M, DM, DI, DI, DM, 1024);
    reduceN<<<dim3(2097152 / 256), blk, 0, stream>>>(parts2, out, M * DM, 2);
}

// Round 6
// 229.558 us; speedup vs baseline: 8.4284x; 1.1518x over previous
//
#include <hip/hip_runtime.h>
#include <cmath>

#define B_  2
#define L_  1024
#define DM  1024
#define DI  2048
#define DS  16
#define DR  64
#define NC  32         // scan time-chunks
#define CL  (L_/NC)    // 32 steps per chunk

typedef __attribute__((ext_vector_type(8))) short short8;
typedef __attribute__((ext_vector_type(4))) float f32x4;

static __device__ __forceinline__ ushort f2bf(float f) {
    union { float f; unsigned u; } c; c.f = f;
    unsigned u = c.u;
    return (ushort)((u + 0x7fffu + ((u >> 16) & 1u)) >> 16);   // RNE
}
static __device__ __forceinline__ float bf2f(ushort h) {
    union { unsigned u; float f; } c; c.u = ((unsigned)h) << 16;
    return c.f;
}

// pack 8 floats -> hi/lo bf16 uint4s
static __device__ __forceinline__ void cvt8(const float* v, uint4& hi, uint4& lo) {
    unsigned h[4], l[4];
    #pragma unroll
    for (int j = 0; j < 4; ++j) {
        ushort h0 = f2bf(v[2*j]),   h1 = f2bf(v[2*j+1]);
        ushort l0 = f2bf(v[2*j]   - bf2f(h0));
        ushort l1 = f2bf(v[2*j+1] - bf2f(h1));
        h[j] = (unsigned)h0 | ((unsigned)h1 << 16);
        l[j] = (unsigned)l0 | ((unsigned)l1 << 16);
    }
    hi = make_uint4(h[0], h[1], h[2], h[3]);
    lo = make_uint4(l[0], l[1], l[2], l[3]);
}

static __device__ __forceinline__ float softplus_f(float v) {
    return (v > 20.f) ? v : log1pf(__expf(v));
}

// ---------------------------------------------------------------------------
// prep_all: all input conversions in ONE kernel.
//  blk [0,4096)      : W_in^T   (K=1024, N=4096)
//  blk [4096,4352)   : W_xproj^T (K=2048, N=96 -> pad 128)
//  blk [4352,4480)   : W_dt^T   (K=64,   N=2048)
//  blk [4480,5504)   : x -> bf16 hi/lo rows
// ---------------------------------------------------------------------------
static __device__ void bt_body(const float* __restrict__ in,
                               ushort* __restrict__ oh, ushort* __restrict__ ol,
                               int K, int N, int Npad, int bx, int by,
                               float (*t)[33])
{
    const int tid = threadIdx.x;
    const int tx = tid & 31, ty = tid >> 5;
    const int n0 = bx * 32, k0 = by * 32;
    #pragma unroll
    for (int i = 0; i < 4; ++i) {
        int k = k0 + ty * 4 + i, n = n0 + tx;
        t[ty * 4 + i][tx] = (n < N) ? in[(size_t)k * N + n] : 0.f;
    }
    __syncthreads();
    #pragma unroll
    for (int i = 0; i < 4; ++i) {
        int r = n0 + ty * 4 + i;
        int c = k0 + tx;
        if (r < Npad) {
            float v = t[tx][ty * 4 + i];
            ushort h = f2bf(v);
            oh[(size_t)r * K + c] = h;
            ol[(size_t)r * K + c] = f2bf(v - bf2f(h));
        }
    }
}

__global__ __launch_bounds__(256) void prep_all(
    const float* __restrict__ x, const float* __restrict__ W_in,
    const float* __restrict__ W_xprj, const float* __restrict__ W_dt,
    ushort* __restrict__ Xh, ushort* __restrict__ Xl,
    ushort* __restrict__ WIh, ushort* __restrict__ WIl,
    ushort* __restrict__ WXh, ushort* __restrict__ WXl,
    ushort* __restrict__ WDh, ushort* __restrict__ WDl)
{
    __shared__ float t[32][33];
    int blk = blockIdx.x;
    if (blk < 4096) {
        bt_body(W_in, WIh, WIl, 1024, 4096, 4096, blk & 127, blk >> 7, t);
    } else if (blk < 4352) {
        int b2 = blk - 4096;
        bt_body(W_xprj, WXh, WXl, 2048, 96, 128, b2 & 3, b2 >> 2, t);
    } else if (blk < 4480) {
        int b2 = blk - 4352;
        bt_body(W_dt, WDh, WDl, 64, 2048, 2048, b2 & 63, b2 >> 6, t);
    } else {
        int v = (blk - 4480) * 256 + threadIdx.x;    // over 262144
        int r  = v >> 7;
        int c8 = v & 127;
        const float* p = x + (size_t)r * DM + c8 * 8;
        float4 v0 = *(const float4*)p;
        float4 v1 = *(const float4*)(p + 4);
        float vv[8] = {v0.x, v0.y, v0.z, v0.w, v1.x, v1.y, v1.z, v1.w};
        uint4 hi, lo; cvt8(vv, hi, lo);
        size_t o = (size_t)r * 1024 + c8 * 8;
        *(uint4*)&Xh[o] = hi;
        *(uint4*)&Xl[o] = lo;
    }
}

// ---------------------------------------------------------------------------
// convBT (standalone, for W_out after the scan frees its region)
// ---------------------------------------------------------------------------
__global__ __launch_bounds__(256) void convBT(
    const float* __restrict__ in, ushort* __restrict__ oh,
    ushort* __restrict__ ol, int K, int N, int Npad)
{
    __shared__ float t[32][33];
    bt_body(in, oh, ol, K, N, Npad, blockIdx.x, blockIdx.y, t);
}

// ---------------------------------------------------------------------------
// GEMM: C[M][N] = A[M][K] @ B[N][K]^T, bf16x3 split (fp32-accurate).
// 128x128 tile, BK=32, 4 waves, double-buffered LDS with COUNTED vmcnt:
// the barrier before compute waits vmcnt(8) (current buffer done) while the
// 8 prefetch loads stay in flight across the barrier.
// EPI=0: fp32 C (with blockIdx.z row-block offset). EPI=1: softplus(acc +
// bvec[col]) -> bf16 hi/lo pair (delta for the scan).
// ---------------------------------------------------------------------------
static __device__ __forceinline__ void stage_tile(
    ushort* lds, const ushort* __restrict__ g, int ld, int row0, int k0,
    int wid, int lane)
{
    #pragma unroll
    for (int it = 0; it < 2; ++it) {
        int o  = wid * 2048 + it * 1024;          // tile-local byte base
        int ob = o + lane * 16;
        int a  = ob ^ (((ob >> 7) & 7) << 4);     // logical byte address
        int row = a >> 6;
        int lc  = (a >> 4) & 3;
        const ushort* gp = g + (size_t)(row0 + row) * ld + k0 + lc * 8;
        __builtin_amdgcn_global_load_lds(
            (const __attribute__((address_space(1))) void*)gp,
            (__attribute__((address_space(3))) void*)((char*)lds + o),
            16, 0, 0);
    }
}

static __device__ __forceinline__ void stage_all(
    ushort* buf, const ushort* Ah, const ushort* Al, const ushort* Bh,
    const ushort* Bl, int lda, int ldb, int bm, int bn, int k,
    int wid, int lane)
{
    stage_tile(buf,         Ah, lda, bm, k, wid, lane);
    stage_tile(buf + 4096,  Al, lda, bm, k, wid, lane);
    stage_tile(buf + 8192,  Bh, ldb, bn, k, wid, lane);
    stage_tile(buf + 12288, Bl, ldb, bn, k, wid, lane);
}

static __device__ __forceinline__ short8 frag(const ushort* lds, int row, int fq) {
    int a = row * 64 + fq * 16;
    int b = a ^ (((a >> 7) & 7) << 4);
    return *(const short8*)((const char*)lds + b);
}

static __device__ __forceinline__ void compute_tile(
    const ushort* buf, int wr, int wc, int fr, int fq, f32x4 acc[4][4])
{
    const ushort* sAh = buf;        const ushort* sAl = buf + 4096;
    const ushort* sBh = buf + 8192; const ushort* sBl = buf + 12288;
    short8 a_h[4], a_l[4], b_h[4], b_l[4];
    #pragma unroll
    for (int m = 0; m < 4; ++m) {
        a_h[m] = frag(sAh, wr + m * 16 + fr, fq);
        a_l[m] = frag(sAl, wr + m * 16 + fr, fq);
    }
    #pragma unroll
    for (int n = 0; n < 4; ++n) {
        b_h[n] = frag(sBh, wc + n * 16 + fr, fq);
        b_l[n] = frag(sBl, wc + n * 16 + fr, fq);
    }
    #pragma unroll
    for (int m = 0; m < 4; ++m)
        #pragma unroll
        for (int n = 0; n < 4; ++n) {
            acc[m][n] = __builtin_amdgcn_mfma_f32_16x16x32_bf16(a_h[m], b_h[n], acc[m][n], 0, 0, 0);
            acc[m][n] = __builtin_amdgcn_mfma_f32_16x16x32_bf16(a_h[m], b_l[n], acc[m][n], 0, 0, 0);
            acc[m][n] = __builtin_amdgcn_mfma_f32_16x16x32_bf16(a_l[m], b_h[n], acc[m][n], 0, 0, 0);
        }
}

template<int EPI>
__global__ __launch_bounds__(256) void gemm_bt(
    const ushort* __restrict__ Ah, const ushort* __restrict__ Al,
    const ushort* __restrict__ Bh, const ushort* __restrict__ Bl,
    float* __restrict__ C, ushort* __restrict__ oh, ushort* __restrict__ ol,
    const float* __restrict__ bvec,
    int M, int N, int lda, int ldb, int ldc, int kspl)
{
    __shared__ ushort sm[32768];                  // 64 KB: two 32 KB buffers

    const int tid = threadIdx.x, wid = tid >> 6, lane = tid & 63;
    const int bm = blockIdx.y * 128, bn = blockIdx.x * 128;
    const int kb = blockIdx.z * kspl;
    const int wr = (wid >> 1) * 64, wc = (wid & 1) * 64;
    const int fr = lane & 15, fq = lane >> 4;

    f32x4 acc[4][4] = {};

    stage_all(sm, Ah, Al, Bh, Bl, lda, ldb, bm, bn, kb, wid, lane);
    const int nsteps = kspl >> 5;
    for (int step = 0; step + 1 < nsteps; ++step) {
        ushort* nbuf       = (step & 1) ? sm : sm + 16384;
        const ushort* cbuf = (step & 1) ? sm + 16384 : sm;
        stage_all(nbuf, Ah, Al, Bh, Bl, lda, ldb, bm, bn, kb + (step + 1) * 32, wid, lane);
        asm volatile("s_waitcnt vmcnt(8)" ::: "memory");   // cbuf landed; nbuf in flight
        __builtin_amdgcn_s_barrier();
        __builtin_amdgcn_sched_barrier(0);
        compute_tile(cbuf, wr, wc, fr, fq, acc);
        asm volatile("s_waitcnt lgkmcnt(0)" ::: "memory"); // ds_reads drained (WAR)
        __builtin_amdgcn_sched_barrier(0);
        __builtin_amdgcn_s_barrier();
    }
    asm volatile("s_waitcnt vmcnt(0)" ::: "memory");
    __builtin_amdgcn_s_barrier();
    __builtin_amdgcn_sched_barrier(0);
    compute_tile(((nsteps - 1) & 1) ? sm + 16384 : sm, wr, wc, fr, fq, acc);

    #pragma unroll
    for (int m = 0; m < 4; ++m) {
        int rbase = bm + wr + m * 16 + fq * 4;
        #pragma unroll
        for (int n = 0; n < 4; ++n) {
            int col = bn + wc + n * 16 + fr;
            if (col >= N) continue;
            if (EPI == 0) {
                #pragma unroll
                for (int j = 0; j < 4; ++j)
                    C[((size_t)blockIdx.z * M + rbase + j) * ldc + col] = acc[m][n][j];
            } else {
                float bb = bvec[col];
                #pragma unroll
                for (int j = 0; j < 4; ++j) {
                    float v = softplus_f(acc[m][n][j] + bb);
                    ushort hh = f2bf(v);
                    size_t off = (size_t)(rbase + j) * ldc + col;
                    oh[off] = hh;
                    ol[off] = f2bf(v - bf2f(hh));
                }
            }
        }
    }
}

// ---------------------------------------------------------------------------
// reduce_xproj: sum 8 split-K parts -> xdbl; also emit dt_lr as bf16 hi/lo.
// ---------------------------------------------------------------------------
__global__ __launch_bounds__(256) void reduce_xproj(
    const float* __restrict__ p, float* __restrict__ xdbl,
    ushort* __restrict__ DTh, ushort* __restrict__ DTl)
{
    int i = blockIdx.x * 256 + threadIdx.x;
    if (i >= 2048 * 96) return;
    float s = 0.f;
    #pragma unroll
    for (int c = 0; c < 8; ++c) s += p[i + (size_t)c * (2048 * 96)];
    xdbl[i] = s;
    int row = i / 96, col = i - row * 96;
    if (col < 64) {
        ushort h = f2bf(s);
        DTh[row * 64 + col] = h;
        DTl[row * 64 + col] = f2bf(s - bf2f(h));
    }
}

// ---------------------------------------------------------------------------
__global__ __launch_bounds__(256) void reduceN(
    const float* __restrict__ p, float* __restrict__ o, int n, int nch)
{
    int i = blockIdx.x * 256 + threadIdx.x;
    if (i >= n) return;
    float s = 0.f;
    for (int c = 0; c < nch; ++c) s += p[i + (size_t)c * n];
    o[i] = s;
}

// ---------------------------------------------------------------------------
// Depthwise causal conv (k=4) + bias + SiLU -> u as bf16 hi/lo.
// ---------------------------------------------------------------------------
__global__ __launch_bounds__(256) void conv_silu(
    const float* __restrict__ xz, const float* __restrict__ w,
    const float* __restrict__ bias, ushort* __restrict__ uh,
    ushort* __restrict__ ul)
{
    int idx = blockIdx.x * 256 + threadIdx.x;
    if (idx >= B_ * L_ * DI) return;
    int d  = idx & (DI - 1);
    int bl = idx >> 11;
    int l  = bl & (L_ - 1);

    const float w0 = w[d * 4 + 0], w1 = w[d * 4 + 1];
    const float w2 = w[d * 4 + 2], w3 = w[d * 4 + 3];
    float s = bias[d];
    size_t base = (size_t)bl * 4096 + d;
    if (l >= 3) s = fmaf(w0, xz[base - 3 * 4096], s);
    if (l >= 2) s = fmaf(w1, xz[base - 2 * 4096], s);
    if (l >= 1) s = fmaf(w2, xz[base - 1 * 4096], s);
    s = fmaf(w3, xz[base], s);
    float v = s / (1.f + __expf(-s));
    ushort h = f2bf(v);
    uh[idx] = h;
    ul[idx] = f2bf(v - bf2f(h));
}

// ---------------------------------------------------------------------------
// Scan phase A: lane owns channel d for chunk c. h[16], Adn[16] in regs.
// delta arrives pre-softplus'd as bf16 hi/lo. Chunk dA-product via
// exp(Adn * sum_t dv) (exact).
// ---------------------------------------------------------------------------
__global__ __launch_bounds__(256) void scan_partial(
    const ushort* __restrict__ Dh, const ushort* __restrict__ Dl,
    const ushort* __restrict__ uh, const ushort* __restrict__ ul,
    const float* __restrict__ xdbl, const float* __restrict__ A_log,
    float* __restrict__ sA, float* __restrict__ sH)
{
    __shared__ float Bs[CL][16];
    const int tid  = threadIdx.x;
    const int dblk = blockIdx.x & 7;
    const int c    = (blockIdx.x >> 3) & (NC - 1);
    const int b    = blockIdx.x >> 8;
    const int d    = dblk * 256 + tid;
    const int bl0  = b * L_ + c * CL;

    for (int i = tid; i < CL * 16; i += 256) {
        int t = i >> 4, n = i & 15;
        Bs[t][n] = xdbl[(size_t)(bl0 + t) * 96 + DR + n];
    }
    __syncthreads();

    float Adn[16];
    #pragma unroll
    for (int q = 0; q < 4; ++q) {
        float4 al = *(const float4*)&A_log[d * DS + q * 4];
        Adn[q * 4 + 0] = -__expf(al.x);
        Adn[q * 4 + 1] = -__expf(al.y);
        Adn[q * 4 + 2] = -__expf(al.z);
        Adn[q * 4 + 3] = -__expf(al.w);
    }
    float h[16];
    #pragma unroll
    for (int n = 0; n < 16; ++n) h[n] = 0.f;
    float S = 0.f;

    size_t pd = (size_t)bl0 * DI + d;
    for (int t = 0; t < CL; ++t) {
        float dv = bf2f(Dh[pd]) + bf2f(Dl[pd]);
        float uv = bf2f(uh[pd]) + bf2f(ul[pd]);
        float du = dv * uv;
        S += dv;
        float Bv[16];
        *(float4*)&Bv[0]  = *(const float4*)&Bs[t][0];
        *(float4*)&Bv[4]  = *(const float4*)&Bs[t][4];
        *(float4*)&Bv[8]  = *(const float4*)&Bs[t][8];
        *(float4*)&Bv[12] = *(const float4*)&Bs[t][12];
        #pragma unroll
        for (int n = 0; n < 16; ++n) {
            float dA = __expf(dv * Adn[n]);
            h[n] = fmaf(dA, h[n], du * Bv[n]);
        }
        pd += DI;
    }

    size_t o = (((size_t)c * B_ + b) * DI + d) * DS;
    float aP[16], hh[16];
    #pragma unroll
    for (int n = 0; n < 16; ++n) { aP[n] = __expf(S * Adn[n]); hh[n] = h[n]; }
    #pragma unroll
    for (int q = 0; q < 4; ++q) {
        *(float4*)&sA[o + q * 4] = *(float4*)&aP[q * 4];
        *(float4*)&sH[o + q * 4] = *(float4*)&hh[q * 4];
    }
}

// ---------------------------------------------------------------------------
__global__ __launch_bounds__(256) void scan_combine(
    const float* __restrict__ sA, const float* __restrict__ sH,
    float* __restrict__ hinit)
{
    int idx = blockIdx.x * 256 + threadIdx.x;   // (b,d,n)
    int n = idx & 15;
    int d = (idx >> 4) & (DI - 1);
    int b = idx >> 15;
    float h = 0.f;
    #pragma unroll
    for (int c = 0; c < NC; ++c) {
        size_t o = (((size_t)c * B_ + b) * DI + d) * DS + n;
        hinit[o] = h;
        h = fmaf(sA[o], h, sH[o]);
    }
}

// ---------------------------------------------------------------------------
// Scan phase C: lane owns channel; rescan chunk from h_init; y-dot in regs;
// skip + z-gate fused; writes y directly as bf16 hi/lo (GEMM_out A-operand).
// ---------------------------------------------------------------------------
__global__ __launch_bounds__(256) void scan_final(
    const ushort* __restrict__ Dh, const ushort* __restrict__ Dl,
    const ushort* __restrict__ uh, const ushort* __restrict__ ul,
    const float* __restrict__ xdbl, const float* __restrict__ xz,
    const float* __restrict__ A_log, const float* __restrict__ D_skip,
    const float* __restrict__ hinit, ushort* __restrict__ yh,
    ushort* __restrict__ yl)
{
    __shared__ float Bs[CL][16];
    __shared__ float Cs[CL][16];
    const int tid  = threadIdx.x;
    const int dblk = blockIdx.x & 7;
    const int c    = (blockIdx.x >> 3) & (NC - 1);
    const int b    = blockIdx.x >> 8;
    const int d    = dblk * 256 + tid;
    const int bl0  = b * L_ + c * CL;

    for (int i = tid; i < CL * 16; i += 256) {
        int t = i >> 4, n = i & 15;
        size_t px = (size_t)(bl0 + t) * 96 + DR + n;
        Bs[t][n] = xdbl[px];
        Cs[t][n] = xdbl[px + DS];
    }
    __syncthreads();

    float Adn[16];
    #pragma unroll
    for (int q = 0; q < 4; ++q) {
        float4 al = *(const float4*)&A_log[d * DS + q * 4];
        Adn[q * 4 + 0] = -__expf(al.x);
        Adn[q * 4 + 1] = -__expf(al.y);
        Adn[q * 4 + 2] = -__expf(al.z);
        Adn[q * 4 + 3] = -__expf(al.w);
    }
    const float Dd = D_skip[d];

    float h[16];
    size_t o = (((size_t)c * B_ + b) * DI + d) * DS;
    #pragma unroll
    for (int q = 0; q < 4; ++q)
        *(float4*)&h[q * 4] = *(const float4*)&hinit[o + q * 4];

    size_t pd = (size_t)bl0 * DI + d;
    size_t pz = (size_t)bl0 * 4096 + 2048 + d;
    for (int t = 0; t < CL; ++t) {
        float dv = bf2f(Dh[pd]) + bf2f(Dl[pd]);
        float uv = bf2f(uh[pd]) + bf2f(ul[pd]);
        float du = dv * uv;
        float Bv[16], Cv[16];
        *(float4*)&Bv[0]  = *(const float4*)&Bs[t][0];
        *(float4*)&Bv[4]  = *(const float4*)&Bs[t][4];
        *(float4*)&Bv[8]  = *(const float4*)&Bs[t][8];
        *(float4*)&Bv[12] = *(const float4*)&Bs[t][12];
        *(float4*)&Cv[0]  = *(const float4*)&Cs[t][0];
        *(float4*)&Cv[4]  = *(const float4*)&Cs[t][4];
        *(float4*)&Cv[8]  = *(const float4*)&Cs[t][8];
        *(float4*)&Cv[12] = *(const float4*)&Cs[t][12];
        float acc = 0.f;
        #pragma unroll
        for (int n = 0; n < 16; ++n) {
            float dA = __expf(dv * Adn[n]);
            h[n] = fmaf(dA, h[n], du * Bv[n]);
            acc = fmaf(h[n], Cv[n], acc);
        }
        float zv = xz[pz];
        float yv = acc + Dd * uv;
        yv *= zv / (1.f + __expf(-zv));
        ushort hh = f2bf(yv);
        yh[pd] = hh;
        yl[pd] = f2bf(yv - bf2f(hh));
        pd += DI; pz += 4096;
    }
}

// ---------------------------------------------------------------------------
extern "C" void kernel_launch(void* const* d_in, const int* in_sizes, int n_in,
                              void* d_out, int out_size, void* d_ws, size_t ws_size,
                              hipStream_t stream)
{
    const float* x      = (const float*)d_in[0];
    const float* W_in   = (const float*)d_in[1];
    const float* conv_w = (const float*)d_in[2];
    const float* conv_b = (const float*)d_in[3];
    const float* W_xprj = (const float*)d_in[4];
    const float* W_dt   = (const float*)d_in[5];
    const float* b_dt   = (const float*)d_in[6];
    const float* A_log  = (const float*)d_in[7];
    const float* D_skip = (const float*)d_in[8];
    const float* W_out  = (const float*)d_in[9];
    float* out = (float*)d_out;

    char* ws = (char*)d_ws;
    float*  xz    = (float*)(ws + 0);            // 32M
    ushort* Dh    = (ushort*)(ws + 33554432);    // 8M  } softplus'd delta
    ushort* Dl    = (ushort*)(ws + 41943040);    // 8M  }
    float*  xdbl  = (float*)(ws + 50331648);     // 768K
    // rotating region 57.4M..82.6M:
    ushort* Xh    = (ushort*)(ws + 57409536);    // 4M  (prep -> gemm1)
    ushort* Xl    = (ushort*)(ws + 61603840);    // 4M
    float*  parts = (float*)(ws + 57409536);     // 6M  (xproj split-K x8)
    ushort* WIh   = (ushort*)(ws + 65798144);    // 8M  (prep -> gemm1)
    ushort* WIl   = (ushort*)(ws + 74186752);    // 8M
    float*  sA    = (float*)(ws + 57409536);     // 8M  (scan)
    float*  sH    = (float*)(ws + 65798144);     // 8M
    float*  hin   = (float*)(ws + 74186752);     // 8M (end 82575360)
    ushort* Yh    = (ushort*)(ws + 57409536);    // 8M  (scan_final out, over sA)
    ushort* Yl    = (ushort*)(ws + 65798144);    // 8M  (over sH)
    ushort* Woh   = (ushort*)(ws + 74186752);    // 4M  (after scan, over hin)
    ushort* Wol   = (ushort*)(ws + 78381056);    // 4M
    ushort* Uh    = (ushort*)(ws + 82575360);    // 8M
    ushort* Ul    = (ushort*)(ws + 90963968);    // 8M
    float*  parts2= (float*)(ws + 82575360);     // 16M (gemm_out split-K, over U)
    ushort* WXh   = (ushort*)(ws + 99352576);    // 512K
    ushort* WXl   = (ushort*)(ws + 99876864);    // 512K
    ushort* DTh   = (ushort*)(ws + 100401152);   // 256K
    ushort* DTl   = (ushort*)(ws + 100657664);   // 256K
    ushort* WDh   = (ushort*)(ws + 100914176);   // 256K
    ushort* WDl   = (ushort*)(ws + 101170688);   // 256K (end 101427200)

    dim3 blk(256);
    const int M = B_ * L_;   // 2048

    // ---- all input conversions (x, W_in^T, W_xproj^T, W_dt^T) ----
    prep_all<<<dim3(5504), blk, 0, stream>>>(
        x, W_in, W_xprj, W_dt, Xh, Xl, WIh, WIl, WXh, WXl, WDh, WDl);

    // ---- xz = x @ W_in : (2048x1024)@(1024x4096) ----
    gemm_bt<0><<<dim3(32, 16, 1), blk, 0, stream>>>(
        Xh, Xl, WIh, WIl, xz, nullptr, nullptr, nullptr,
        M, 4096, DM, DM, 4096, DM);

    // ---- u = silu(conv(x_in)+b) -> bf16 hi/lo ----
    conv_silu<<<dim3((B_ * L_ * DI) / 256), blk, 0, stream>>>(xz, conv_w, conv_b, Uh, Ul);

    // ---- x_dbl = u @ W_xproj : split-K x8 ----
    gemm_bt<0><<<dim3(1, 16, 8), blk, 0, stream>>>(
        Uh, Ul, WXh, WXl, parts, nullptr, nullptr, nullptr,
        M, 96, DI, DI, 96, 256);
    reduce_xproj<<<dim3(768), blk, 0, stream>>>(parts, xdbl, DTh, DTl);

    // ---- delta = softplus(dt_lr @ W_dt + b_dt) -> bf16 hi/lo (fused epi) ----
    gemm_bt<1><<<dim3(16, 16, 1), blk, 0, stream>>>(
        DTh, DTl, WDh, WDl, nullptr, Dh, Dl, b_dt,
        M, DI, DR, DR, DI, DR);

    // ---- chunked selective scan ----
    scan_partial<<<dim3(B_ * NC * 8), blk, 0, stream>>>(
        Dh, Dl, Uh, Ul, xdbl, A_log, sA, sH);
    scan_combine<<<dim3((B_ * DI * DS) / 256), blk, 0, stream>>>(sA, sH, hin);
    scan_final<<<dim3(B_ * NC * 8), blk, 0, stream>>>(
        Dh, Dl, Uh, Ul, xdbl, xz, A_log, D_skip, hin, Yh, Yl);

    // ---- out = y @ W_out : split-K x2 ----
    convBT<<<dim3(DM / 32, DI / 32), blk, 0, stream>>>(W_out, Woh, Wol, DI, DM, DM);
    gemm_bt<0><<<dim3(8, 16, 2), blk, 0, stream>>>(
        Yh, Yl, Woh, Wol, parts2, nullptr, nullptr, nullptr,
        M, DM, DI, DI, DM, 1024);
    reduceN<<<dim3(2097152 / 256), blk, 0, stream>>>(parts2, out, M * DM, 2);
}

// Round 7
// 211.903 us; speedup vs baseline: 9.1306x; 1.0833x over previous
//
#include <hip/hip_runtime.h>
#include <cmath>

#define B_  2
#define L_  1024
#define DM  1024
#define DI  2048
#define DS  16
#define DR  64
#define NC  32         // scan time-chunks
#define CL  (L_/NC)    // 32 steps per chunk

typedef __attribute__((ext_vector_type(8))) short short8;
typedef __attribute__((ext_vector_type(4))) float f32x4;

static __device__ __forceinline__ ushort f2bf(float f) {
    union { float f; unsigned u; } c; c.f = f;
    unsigned u = c.u;
    return (ushort)((u + 0x7fffu + ((u >> 16) & 1u)) >> 16);   // RNE
}
static __device__ __forceinline__ float bf2f(ushort h) {
    union { unsigned u; float f; } c; c.u = ((unsigned)h) << 16;
    return c.f;
}

// pack 8 floats -> hi/lo bf16 uint4s
static __device__ __forceinline__ void cvt8(const float* v, uint4& hi, uint4& lo) {
    unsigned h[4], l[4];
    #pragma unroll
    for (int j = 0; j < 4; ++j) {
        ushort h0 = f2bf(v[2*j]),   h1 = f2bf(v[2*j+1]);
        ushort l0 = f2bf(v[2*j]   - bf2f(h0));
        ushort l1 = f2bf(v[2*j+1] - bf2f(h1));
        h[j] = (unsigned)h0 | ((unsigned)h1 << 16);
        l[j] = (unsigned)l0 | ((unsigned)l1 << 16);
    }
    hi = make_uint4(h[0], h[1], h[2], h[3]);
    lo = make_uint4(l[0], l[1], l[2], l[3]);
}

static __device__ __forceinline__ float softplus_f(float v) {
    return (v > 20.f) ? v : log1pf(__expf(v));
}

// ---------------------------------------------------------------------------
// prep_all: all input conversions in ONE kernel.
//  blk [0,4096)      : W_in^T    (K=1024, N=4096)  hi/lo
//  blk [4096,4352)   : W_xproj^T (K=2048, N=96->128) hi/lo
//  blk [4352,4480)   : W_dt^T    (K=64,   N=2048)  hi/lo
//  blk [4480,5504)   : x -> bf16 HI ONLY
// ---------------------------------------------------------------------------
static __device__ void bt_body(const float* __restrict__ in,
                               ushort* __restrict__ oh, ushort* __restrict__ ol,
                               int K, int N, int Npad, int bx, int by,
                               float (*t)[33])
{
    const int tid = threadIdx.x;
    const int tx = tid & 31, ty = tid >> 5;
    const int n0 = bx * 32, k0 = by * 32;
    #pragma unroll
    for (int i = 0; i < 4; ++i) {
        int k = k0 + ty * 4 + i, n = n0 + tx;
        t[ty * 4 + i][tx] = (n < N) ? in[(size_t)k * N + n] : 0.f;
    }
    __syncthreads();
    #pragma unroll
    for (int i = 0; i < 4; ++i) {
        int r = n0 + ty * 4 + i;
        int c = k0 + tx;
        if (r < Npad) {
            float v = t[tx][ty * 4 + i];
            ushort h = f2bf(v);
            oh[(size_t)r * K + c] = h;
            ol[(size_t)r * K + c] = f2bf(v - bf2f(h));
        }
    }
}

__global__ __launch_bounds__(256) void prep_all(
    const float* __restrict__ x, const float* __restrict__ W_in,
    const float* __restrict__ W_xprj, const float* __restrict__ W_dt,
    ushort* __restrict__ Xh,
    ushort* __restrict__ WIh, ushort* __restrict__ WIl,
    ushort* __restrict__ WXh, ushort* __restrict__ WXl,
    ushort* __restrict__ WDh, ushort* __restrict__ WDl)
{
    __shared__ float t[32][33];
    int blk = blockIdx.x;
    if (blk < 4096) {
        bt_body(W_in, WIh, WIl, 1024, 4096, 4096, blk & 127, blk >> 7, t);
    } else if (blk < 4352) {
        int b2 = blk - 4096;
        bt_body(W_xprj, WXh, WXl, 2048, 96, 128, b2 & 3, b2 >> 2, t);
    } else if (blk < 4480) {
        int b2 = blk - 4352;
        bt_body(W_dt, WDh, WDl, 64, 2048, 2048, b2 & 63, b2 >> 6, t);
    } else {
        int v = (blk - 4480) * 256 + threadIdx.x;    // over 262144
        int r  = v >> 7;
        int c8 = v & 127;
        const float* p = x + (size_t)r * DM + c8 * 8;
        float4 v0 = *(const float4*)p;
        float4 v1 = *(const float4*)(p + 4);
        float vv[8] = {v0.x, v0.y, v0.z, v0.w, v1.x, v1.y, v1.z, v1.w};
        unsigned h[4];
        #pragma unroll
        for (int j = 0; j < 4; ++j)
            h[j] = (unsigned)f2bf(vv[2*j]) | ((unsigned)f2bf(vv[2*j+1]) << 16);
        size_t o = (size_t)r * 1024 + c8 * 8;
        *(uint4*)&Xh[o] = make_uint4(h[0], h[1], h[2], h[3]);
    }
}

// ---------------------------------------------------------------------------
// convBT (standalone, for W_out after the scan frees its region)
// ---------------------------------------------------------------------------
__global__ __launch_bounds__(256) void convBT(
    const float* __restrict__ in, ushort* __restrict__ oh,
    ushort* __restrict__ ol, int K, int N, int Npad)
{
    __shared__ float t[32][33];
    bt_body(in, oh, ol, K, N, Npad, blockIdx.x, blockIdx.y, t);
}

// ---------------------------------------------------------------------------
// GEMM: C[M][N] = A[M][K] @ B[N][K]^T, 2-term bf16 split:
//   acc += Ah*Bh + Ah*Bl   (A hi-only activations, B hi/lo weights)
// 128x128 tile, BK=32, 4 waves, double-buffered LDS (2-phase, __syncthreads).
// 3 staged tiles/buffer (Ah,Bh,Bl) = 24 KB; two buffers = 48 KB LDS.
// XOR-swizzle involution perm(a)=a^(((a>>7)&7)<<4) on source addr + read.
// EPI=0: fp32 C (blockIdx.z row-block offset). EPI=1: softplus(acc+bvec[col])
// -> bf16 hi/lo pair (delta for the scan).
// ---------------------------------------------------------------------------
static __device__ __forceinline__ void stage_tile(
    ushort* lds, const ushort* __restrict__ g, int ld, int row0, int k0,
    int wid, int lane)
{
    #pragma unroll
    for (int it = 0; it < 2; ++it) {
        int o  = wid * 2048 + it * 1024;          // tile-local byte base
        int ob = o + lane * 16;
        int a  = ob ^ (((ob >> 7) & 7) << 4);     // logical byte address
        int row = a >> 6;
        int lc  = (a >> 4) & 3;
        const ushort* gp = g + (size_t)(row0 + row) * ld + k0 + lc * 8;
        __builtin_amdgcn_global_load_lds(
            (const __attribute__((address_space(1))) void*)gp,
            (__attribute__((address_space(3))) void*)((char*)lds + o),
            16, 0, 0);
    }
}

static __device__ __forceinline__ void stage_all(
    ushort* buf, const ushort* Ah, const ushort* Bh, const ushort* Bl,
    int lda, int ldb, int bm, int bn, int k, int wid, int lane)
{
    stage_tile(buf,        Ah, lda, bm, k, wid, lane);
    stage_tile(buf + 4096, Bh, ldb, bn, k, wid, lane);
    stage_tile(buf + 8192, Bl, ldb, bn, k, wid, lane);
}

static __device__ __forceinline__ short8 frag(const ushort* lds, int row, int fq) {
    int a = row * 64 + fq * 16;
    int b = a ^ (((a >> 7) & 7) << 4);
    return *(const short8*)((const char*)lds + b);
}

static __device__ __forceinline__ void compute_tile(
    const ushort* buf, int wr, int wc, int fr, int fq, f32x4 acc[4][4])
{
    const ushort* sAh = buf;
    const ushort* sBh = buf + 4096;
    const ushort* sBl = buf + 8192;
    short8 a_h[4], b_h[4], b_l[4];
    #pragma unroll
    for (int m = 0; m < 4; ++m)
        a_h[m] = frag(sAh, wr + m * 16 + fr, fq);
    #pragma unroll
    for (int n = 0; n < 4; ++n) {
        b_h[n] = frag(sBh, wc + n * 16 + fr, fq);
        b_l[n] = frag(sBl, wc + n * 16 + fr, fq);
    }
    #pragma unroll
    for (int m = 0; m < 4; ++m)
        #pragma unroll
        for (int n = 0; n < 4; ++n) {
            acc[m][n] = __builtin_amdgcn_mfma_f32_16x16x32_bf16(a_h[m], b_h[n], acc[m][n], 0, 0, 0);
            acc[m][n] = __builtin_amdgcn_mfma_f32_16x16x32_bf16(a_h[m], b_l[n], acc[m][n], 0, 0, 0);
        }
}

template<int EPI>
__global__ __launch_bounds__(256) void gemm_bt(
    const ushort* __restrict__ Ah,
    const ushort* __restrict__ Bh, const ushort* __restrict__ Bl,
    float* __restrict__ C, ushort* __restrict__ oh, ushort* __restrict__ ol,
    const float* __restrict__ bvec,
    int M, int N, int lda, int ldb, int ldc, int kspl)
{
    __shared__ ushort sm[24576];                  // 48 KB: two 24 KB buffers

    const int tid = threadIdx.x, wid = tid >> 6, lane = tid & 63;
    const int bm = blockIdx.y * 128, bn = blockIdx.x * 128;
    const int kb = blockIdx.z * kspl;
    const int wr = (wid >> 1) * 64, wc = (wid & 1) * 64;
    const int fr = lane & 15, fq = lane >> 4;

    f32x4 acc[4][4] = {};

    stage_all(sm, Ah, Bh, Bl, lda, ldb, bm, bn, kb, wid, lane);
    __syncthreads();
    int cur = 0;
    for (int k0 = 32; k0 < kspl; k0 += 32) {
        ushort* nbuf       = cur ? sm : sm + 12288;
        const ushort* cbuf = cur ? sm + 12288 : sm;
        stage_all(nbuf, Ah, Bh, Bl, lda, ldb, bm, bn, kb + k0, wid, lane);
        compute_tile(cbuf, wr, wc, fr, fq, acc);
        __syncthreads();
        cur ^= 1;
    }
    compute_tile(cur ? sm + 12288 : sm, wr, wc, fr, fq, acc);

    #pragma unroll
    for (int m = 0; m < 4; ++m) {
        int rbase = bm + wr + m * 16 + fq * 4;
        #pragma unroll
        for (int n = 0; n < 4; ++n) {
            int col = bn + wc + n * 16 + fr;
            if (col >= N) continue;
            if (EPI == 0) {
                #pragma unroll
                for (int j = 0; j < 4; ++j)
                    C[((size_t)blockIdx.z * M + rbase + j) * ldc + col] = acc[m][n][j];
            } else {
                float bb = bvec[col];
                #pragma unroll
                for (int j = 0; j < 4; ++j) {
                    float v = softplus_f(acc[m][n][j] + bb);
                    ushort hh = f2bf(v);
                    size_t off = (size_t)(rbase + j) * ldc + col;
                    oh[off] = hh;
                    ol[off] = f2bf(v - bf2f(hh));
                }
            }
        }
    }
}

// ---------------------------------------------------------------------------
// reduce_xproj: sum 8 split-K parts -> xdbl; also emit dt_lr as bf16 hi.
// ---------------------------------------------------------------------------
__global__ __launch_bounds__(256) void reduce_xproj(
    const float* __restrict__ p, float* __restrict__ xdbl,
    ushort* __restrict__ DTh)
{
    int i = blockIdx.x * 256 + threadIdx.x;
    if (i >= 2048 * 96) return;
    float s = 0.f;
    #pragma unroll
    for (int c = 0; c < 8; ++c) s += p[i + (size_t)c * (2048 * 96)];
    xdbl[i] = s;
    int row = i / 96, col = i - row * 96;
    if (col < 64) DTh[row * 64 + col] = f2bf(s);
}

// ---------------------------------------------------------------------------
__global__ __launch_bounds__(256) void reduceN(
    const float* __restrict__ p, float* __restrict__ o, int n, int nch)
{
    int i = blockIdx.x * 256 + threadIdx.x;
    if (i >= n) return;
    float s = 0.f;
    for (int c = 0; c < nch; ++c) s += p[i + (size_t)c * n];
    o[i] = s;
}

// ---------------------------------------------------------------------------
// Depthwise causal conv (k=4) + bias + SiLU -> u as bf16 hi/lo
// (scan consumes hi+lo for accuracy; xproj GEMM consumes hi only).
// ---------------------------------------------------------------------------
__global__ __launch_bounds__(256) void conv_silu(
    const float* __restrict__ xz, const float* __restrict__ w,
    const float* __restrict__ bias, ushort* __restrict__ uh,
    ushort* __restrict__ ul)
{
    int idx = blockIdx.x * 256 + threadIdx.x;
    if (idx >= B_ * L_ * DI) return;
    int d  = idx & (DI - 1);
    int bl = idx >> 11;
    int l  = bl & (L_ - 1);

    const float w0 = w[d * 4 + 0], w1 = w[d * 4 + 1];
    const float w2 = w[d * 4 + 2], w3 = w[d * 4 + 3];
    float s = bias[d];
    size_t base = (size_t)bl * 4096 + d;
    if (l >= 3) s = fmaf(w0, xz[base - 3 * 4096], s);
    if (l >= 2) s = fmaf(w1, xz[base - 2 * 4096], s);
    if (l >= 1) s = fmaf(w2, xz[base - 1 * 4096], s);
    s = fmaf(w3, xz[base], s);
    float v = s / (1.f + __expf(-s));
    ushort h = f2bf(v);
    uh[idx] = h;
    ul[idx] = f2bf(v - bf2f(h));
}

// ---------------------------------------------------------------------------
// Scan phase A: lane owns channel d for chunk c. h[16], Adn[16] in regs.
// delta arrives pre-softplus'd as bf16 hi/lo. Chunk dA-product via
// exp(Adn * sum_t dv) (exact).
// ---------------------------------------------------------------------------
__global__ __launch_bounds__(256) void scan_partial(
    const ushort* __restrict__ Dh, const ushort* __restrict__ Dl,
    const ushort* __restrict__ uh, const ushort* __restrict__ ul,
    const float* __restrict__ xdbl, const float* __restrict__ A_log,
    float* __restrict__ sA, float* __restrict__ sH)
{
    __shared__ float Bs[CL][16];
    const int tid  = threadIdx.x;
    const int dblk = blockIdx.x & 7;
    const int c    = (blockIdx.x >> 3) & (NC - 1);
    const int b    = blockIdx.x >> 8;
    const int d    = dblk * 256 + tid;
    const int bl0  = b * L_ + c * CL;

    for (int i = tid; i < CL * 16; i += 256) {
        int t = i >> 4, n = i & 15;
        Bs[t][n] = xdbl[(size_t)(bl0 + t) * 96 + DR + n];
    }
    __syncthreads();

    float Adn[16];
    #pragma unroll
    for (int q = 0; q < 4; ++q) {
        float4 al = *(const float4*)&A_log[d * DS + q * 4];
        Adn[q * 4 + 0] = -__expf(al.x);
        Adn[q * 4 + 1] = -__expf(al.y);
        Adn[q * 4 + 2] = -__expf(al.z);
        Adn[q * 4 + 3] = -__expf(al.w);
    }
    float h[16];
    #pragma unroll
    for (int n = 0; n < 16; ++n) h[n] = 0.f;
    float S = 0.f;

    size_t pd = (size_t)bl0 * DI + d;
    for (int t = 0; t < CL; ++t) {
        float dv = bf2f(Dh[pd]) + bf2f(Dl[pd]);
        float uv = bf2f(uh[pd]) + bf2f(ul[pd]);
        float du = dv * uv;
        S += dv;
        float Bv[16];
        *(float4*)&Bv[0]  = *(const float4*)&Bs[t][0];
        *(float4*)&Bv[4]  = *(const float4*)&Bs[t][4];
        *(float4*)&Bv[8]  = *(const float4*)&Bs[t][8];
        *(float4*)&Bv[12] = *(const float4*)&Bs[t][12];
        #pragma unroll
        for (int n = 0; n < 16; ++n) {
            float dA = __expf(dv * Adn[n]);
            h[n] = fmaf(dA, h[n], du * Bv[n]);
        }
        pd += DI;
    }

    size_t o = (((size_t)c * B_ + b) * DI + d) * DS;
    float aP[16], hh[16];
    #pragma unroll
    for (int n = 0; n < 16; ++n) { aP[n] = __expf(S * Adn[n]); hh[n] = h[n]; }
    #pragma unroll
    for (int q = 0; q < 4; ++q) {
        *(float4*)&sA[o + q * 4] = *(float4*)&aP[q * 4];
        *(float4*)&sH[o + q * 4] = *(float4*)&hh[q * 4];
    }
}

// ---------------------------------------------------------------------------
__global__ __launch_bounds__(256) void scan_combine(
    const float* __restrict__ sA, const float* __restrict__ sH,
    float* __restrict__ hinit)
{
    int idx = blockIdx.x * 256 + threadIdx.x;   // (b,d,n)
    int n = idx & 15;
    int d = (idx >> 4) & (DI - 1);
    int b = idx >> 15;
    float h = 0.f;
    #pragma unroll
    for (int c = 0; c < NC; ++c) {
        size_t o = (((size_t)c * B_ + b) * DI + d) * DS + n;
        hinit[o] = h;
        h = fmaf(sA[o], h, sH[o]);
    }
}

// ---------------------------------------------------------------------------
// Scan phase C: lane owns channel; rescan chunk from h_init; y-dot in regs;
// skip + z-gate fused; writes y as bf16 HI (GEMM_out A-operand).
// ---------------------------------------------------------------------------
__global__ __launch_bounds__(256) void scan_final(
    const ushort* __restrict__ Dh, const ushort* __restrict__ Dl,
    const ushort* __restrict__ uh, const ushort* __restrict__ ul,
    const float* __restrict__ xdbl, const float* __restrict__ xz,
    const float* __restrict__ A_log, const float* __restrict__ D_skip,
    const float* __restrict__ hinit, ushort* __restrict__ yh)
{
    __shared__ float Bs[CL][16];
    __shared__ float Cs[CL][16];
    const int tid  = threadIdx.x;
    const int dblk = blockIdx.x & 7;
    const int c    = (blockIdx.x >> 3) & (NC - 1);
    const int b    = blockIdx.x >> 8;
    const int d    = dblk * 256 + tid;
    const int bl0  = b * L_ + c * CL;

    for (int i = tid; i < CL * 16; i += 256) {
        int t = i >> 4, n = i & 15;
        size_t px = (size_t)(bl0 + t) * 96 + DR + n;
        Bs[t][n] = xdbl[px];
        Cs[t][n] = xdbl[px + DS];
    }
    __syncthreads();

    float Adn[16];
    #pragma unroll
    for (int q = 0; q < 4; ++q) {
        float4 al = *(const float4*)&A_log[d * DS + q * 4];
        Adn[q * 4 + 0] = -__expf(al.x);
        Adn[q * 4 + 1] = -__expf(al.y);
        Adn[q * 4 + 2] = -__expf(al.z);
        Adn[q * 4 + 3] = -__expf(al.w);
    }
    const float Dd = D_skip[d];

    float h[16];
    size_t o = (((size_t)c * B_ + b) * DI + d) * DS;
    #pragma unroll
    for (int q = 0; q < 4; ++q)
        *(float4*)&h[q * 4] = *(const float4*)&hinit[o + q * 4];

    size_t pd = (size_t)bl0 * DI + d;
    size_t pz = (size_t)bl0 * 4096 + 2048 + d;
    for (int t = 0; t < CL; ++t) {
        float dv = bf2f(Dh[pd]) + bf2f(Dl[pd]);
        float uv = bf2f(uh[pd]) + bf2f(ul[pd]);
        float du = dv * uv;
        float Bv[16], Cv[16];
        *(float4*)&Bv[0]  = *(const float4*)&Bs[t][0];
        *(float4*)&Bv[4]  = *(const float4*)&Bs[t][4];
        *(float4*)&Bv[8]  = *(const float4*)&Bs[t][8];
        *(float4*)&Bv[12] = *(const float4*)&Bs[t][12];
        *(float4*)&Cv[0]  = *(const float4*)&Cs[t][0];
        *(float4*)&Cv[4]  = *(const float4*)&Cs[t][4];
        *(float4*)&Cv[8]  = *(const float4*)&Cs[t][8];
        *(float4*)&Cv[12] = *(const float4*)&Cs[t][12];
        float acc = 0.f;
        #pragma unroll
        for (int n = 0; n < 16; ++n) {
            float dA = __expf(dv * Adn[n]);
            h[n] = fmaf(dA, h[n], du * Bv[n]);
            acc = fmaf(h[n], Cv[n], acc);
        }
        float zv = xz[pz];
        float yv = acc + Dd * uv;
        yv *= zv / (1.f + __expf(-zv));
        yh[pd] = f2bf(yv);
        pd += DI; pz += 4096;
    }
}

// ---------------------------------------------------------------------------
extern "C" void kernel_launch(void* const* d_in, const int* in_sizes, int n_in,
                              void* d_out, int out_size, void* d_ws, size_t ws_size,
                              hipStream_t stream)
{
    const float* x      = (const float*)d_in[0];
    const float* W_in   = (const float*)d_in[1];
    const float* conv_w = (const float*)d_in[2];
    const float* conv_b = (const float*)d_in[3];
    const float* W_xprj = (const float*)d_in[4];
    const float* W_dt   = (const float*)d_in[5];
    const float* b_dt   = (const float*)d_in[6];
    const float* A_log  = (const float*)d_in[7];
    const float* D_skip = (const float*)d_in[8];
    const float* W_out  = (const float*)d_in[9];
    float* out = (float*)d_out;

    char* ws = (char*)d_ws;
    float*  xz    = (float*)(ws + 0);            // 32M
    ushort* Dh    = (ushort*)(ws + 33554432);    // 8M  } softplus'd delta
    ushort* Dl    = (ushort*)(ws + 41943040);    // 8M  }
    float*  xdbl  = (float*)(ws + 50331648);     // 768K
    // rotating region 57.4M..82.6M:
    ushort* Xh    = (ushort*)(ws + 57409536);    // 4M  (prep -> gemm1)
    float*  parts = (float*)(ws + 57409536);     // 6M  (xproj split-K x8)
    ushort* WIh   = (ushort*)(ws + 65798144);    // 8M  (prep -> gemm1)
    ushort* WIl   = (ushort*)(ws + 74186752);    // 8M
    float*  sA    = (float*)(ws + 57409536);     // 8M  (scan)
    float*  sH    = (float*)(ws + 65798144);     // 8M
    float*  hin   = (float*)(ws + 74186752);     // 8M (end 82575360)
    ushort* Yh    = (ushort*)(ws + 57409536);    // 8M  (scan_final out, over sA)
    ushort* Woh   = (ushort*)(ws + 65798144);    // 4M  (after scan, over sH)
    ushort* Wol   = (ushort*)(ws + 69992448);    // 4M
    ushort* Uh    = (ushort*)(ws + 82575360);    // 8M
    ushort* Ul    = (ushort*)(ws + 90963968);    // 8M
    float*  parts2= (float*)(ws + 82575360);     // 16M (gemm_out split-K, over U)
    ushort* WXh   = (ushort*)(ws + 99352576);    // 512K
    ushort* WXl   = (ushort*)(ws + 99876864);    // 512K
    ushort* DTh   = (ushort*)(ws + 100401152);   // 256K
    ushort* WDh   = (ushort*)(ws + 100914176);   // 256K
    ushort* WDl   = (ushort*)(ws + 101170688);   // 256K (end 101427200)

    dim3 blk(256);
    const int M = B_ * L_;   // 2048

    // ---- all input conversions (x hi, W_in^T, W_xproj^T, W_dt^T hi/lo) ----
    prep_all<<<dim3(5504), blk, 0, stream>>>(
        x, W_in, W_xprj, W_dt, Xh, WIh, WIl, WXh, WXl, WDh, WDl);

    // ---- xz = x @ W_in : (2048x1024)@(1024x4096) ----
    gemm_bt<0><<<dim3(32, 16, 1), blk, 0, stream>>>(
        Xh, WIh, WIl, xz, nullptr, nullptr, nullptr,
        M, 4096, DM, DM, 4096, DM);

    // ---- u = silu(conv(x_in)+b) -> bf16 hi/lo ----
    conv_silu<<<dim3((B_ * L_ * DI) / 256), blk, 0, stream>>>(xz, conv_w, conv_b, Uh, Ul);

    // ---- x_dbl = u @ W_xproj : split-K x8 ----
    gemm_bt<0><<<dim3(1, 16, 8), blk, 0, stream>>>(
        Uh, WXh, WXl, parts, nullptr, nullptr, nullptr,
        M, 96, DI, DI, 96, 256);
    reduce_xproj<<<dim3(768), blk, 0, stream>>>(parts, xdbl, DTh);

    // ---- delta = softplus(dt_lr @ W_dt + b_dt) -> bf16 hi/lo (fused epi) ----
    gemm_bt<1><<<dim3(16, 16, 1), blk, 0, stream>>>(
        DTh, WDh, WDl, nullptr, Dh, Dl, b_dt,
        M, DI, DR, DR, DI, DR);

    // ---- chunked selective scan ----
    scan_partial<<<dim3(B_ * NC * 8), blk, 0, stream>>>(
        Dh, Dl, Uh, Ul, xdbl, A_log, sA, sH);
    scan_combine<<<dim3((B_ * DI * DS) / 256), blk, 0, stream>>>(sA, sH, hin);
    scan_final<<<dim3(B_ * NC * 8), blk, 0, stream>>>(
        Dh, Dl, Uh, Ul, xdbl, xz, A_log, D_skip, hin, Yh);

    // ---- out = y @ W_out : split-K x2 ----
    convBT<<<dim3(DM / 32, DI / 32), blk, 0, stream>>>(W_out, Woh, Wol, DI, DM, DM);
    gemm_bt<0><<<dim3(8, 16, 2), blk, 0, stream>>>(
        Yh, Woh, Wol, parts2, nullptr, nullptr, nullptr,
        M, DM, DI, DI, DM, 1024);
    reduceN<<<dim3(2097152 / 256), blk, 0, stream>>>(parts2, out, M * DM, 2);
}

// Round 10
// 204.478 us; speedup vs baseline: 9.4621x; 1.0363x over previous
//
#include <hip/hip_runtime.h>
#include <cmath>

#define B_  2
#define L_  1024
#define DM  1024
#define DI  2048
#define DS  16
#define DR  64
#define NC  32         // scan time-chunks
#define CL  (L_/NC)    // 32 steps per chunk

typedef __attribute__((ext_vector_type(8))) short short8;
typedef __attribute__((ext_vector_type(4))) float f32x4;

static __device__ __forceinline__ ushort f2bf(float f) {
    union { float f; unsigned u; } c; c.f = f;
    unsigned u = c.u;
    return (ushort)((u + 0x7fffu + ((u >> 16) & 1u)) >> 16);   // RNE
}
static __device__ __forceinline__ float bf2f(ushort h) {
    union { unsigned u; float f; } c; c.u = ((unsigned)h) << 16;
    return c.f;
}

static __device__ __forceinline__ float softplus_f(float v) {
    return (v > 20.f) ? v : log1pf(__expf(v));
}

// ---------------------------------------------------------------------------
// bt_body: transpose-convert one 32x32 tile of fp32 [K][N] -> bf16 [N][K]
// (hi, and lo if ol != nullptr). Rows n >= N zero-padded to Npad.
// ---------------------------------------------------------------------------
static __device__ void bt_body(const float* __restrict__ in,
                               ushort* __restrict__ oh, ushort* __restrict__ ol,
                               int K, int N, int Npad, int bx, int by,
                               float (*t)[33])
{
    const int tid = threadIdx.x;
    const int tx = tid & 31, ty = tid >> 5;
    const int n0 = bx * 32, k0 = by * 32;
    #pragma unroll
    for (int i = 0; i < 4; ++i) {
        int k = k0 + ty * 4 + i, n = n0 + tx;
        t[ty * 4 + i][tx] = (n < N) ? in[(size_t)k * N + n] : 0.f;
    }
    __syncthreads();
    #pragma unroll
    for (int i = 0; i < 4; ++i) {
        int r = n0 + ty * 4 + i;
        int c = k0 + tx;
        if (r < Npad) {
            float v = t[tx][ty * 4 + i];
            ushort h = f2bf(v);
            oh[(size_t)r * K + c] = h;
            if (ol) ol[(size_t)r * K + c] = f2bf(v - bf2f(h));
        }
    }
}

// ---------------------------------------------------------------------------
// prep_all: input conversions (x and the three pre-scan weights).
//  [0,4096)     : W_in^T  hi/lo        (K=1024, N=4096)
//  [4096,4352)  : W_xproj^T hi/lo      (K=2048, N=96->128)
//  [4352,4480)  : W_dt^T hi/lo         (K=64,   N=2048)
//  [4480,5504)  : x -> bf16 hi rows
// ---------------------------------------------------------------------------
__global__ __launch_bounds__(256) void prep_all(
    const float* __restrict__ x, const float* __restrict__ W_in,
    const float* __restrict__ W_xprj, const float* __restrict__ W_dt,
    ushort* __restrict__ Xh, ushort* __restrict__ WIh, ushort* __restrict__ WIl,
    ushort* __restrict__ WXh, ushort* __restrict__ WXl,
    ushort* __restrict__ WDh, ushort* __restrict__ WDl)
{
    __shared__ float t[32][33];
    int blk = blockIdx.x;
    if (blk < 4096) {
        bt_body(W_in, WIh, WIl, 1024, 4096, 4096, blk & 127, blk >> 7, t);
    } else if (blk < 4352) {
        int b2 = blk - 4096;
        bt_body(W_xprj, WXh, WXl, 2048, 96, 128, b2 & 3, b2 >> 2, t);
    } else if (blk < 4480) {
        int b2 = blk - 4352;
        bt_body(W_dt, WDh, WDl, 64, 2048, 2048, b2 & 63, b2 >> 6, t);
    } else {
        int v = (blk - 4480) * 256 + threadIdx.x;    // over 262144
        int r  = v >> 7;
        int c8 = v & 127;
        const float* p = x + (size_t)r * DM + c8 * 8;
        float4 v0 = *(const float4*)p;
        float4 v1 = *(const float4*)(p + 4);
        float vv[8] = {v0.x, v0.y, v0.z, v0.w, v1.x, v1.y, v1.z, v1.w};
        unsigned h[4];
        #pragma unroll
        for (int j = 0; j < 4; ++j)
            h[j] = (unsigned)f2bf(vv[2*j]) | ((unsigned)f2bf(vv[2*j+1]) << 16);
        size_t o = (size_t)r * 1024 + c8 * 8;
        *(uint4*)&Xh[o] = make_uint4(h[0], h[1], h[2], h[3]);
    }
}

// ---------------------------------------------------------------------------
// convBT standalone (W_out after scan frees its region). hi only.
// ---------------------------------------------------------------------------
__global__ __launch_bounds__(256) void convBT(
    const float* __restrict__ in, ushort* __restrict__ oh,
    int K, int N, int Npad)
{
    __shared__ float t[32][33];
    bt_body(in, oh, nullptr, K, N, Npad, blockIdx.x, blockIdx.y, t);
}

// ---------------------------------------------------------------------------
// GEMM: C[M][N] = A[M][K] @ B[N][K]^T.
// TERMS=1: acc += Ah*Bh.  TERMS=2: acc += Ah*Bh + Ah*Bl.
// 128x128 tile, BK=32, 4 waves, double-buffered LDS (2-phase, __syncthreads).
// XOR-swizzle involution perm(a)=a^(((a>>7)&7)<<4) on source addr + read.
// EPI=0: fp32 C store (blockIdx.z*M row offset for split-K parts).
// EPI=1: softplus(acc+bvec) -> bf16 hi/lo (delta).
// ---------------------------------------------------------------------------
static __device__ __forceinline__ void stage_tile(
    ushort* lds, const ushort* __restrict__ g, int ld, int row0, int k0,
    int wid, int lane)
{
    #pragma unroll
    for (int it = 0; it < 2; ++it) {
        int o  = wid * 2048 + it * 1024;          // tile-local byte base
        int ob = o + lane * 16;
        int a  = ob ^ (((ob >> 7) & 7) << 4);     // logical byte address
        int row = a >> 6;
        int lc  = (a >> 4) & 3;
        const ushort* gp = g + (size_t)(row0 + row) * ld + k0 + lc * 8;
        __builtin_amdgcn_global_load_lds(
            (const __attribute__((address_space(1))) void*)gp,
            (__attribute__((address_space(3))) void*)((char*)lds + o),
            16, 0, 0);
    }
}

template<int TERMS>
static __device__ __forceinline__ void stage_all(
    ushort* buf, const ushort* Ah, const ushort* Bh, const ushort* Bl,
    int lda, int ldb, int bm, int bn, int k, int wid, int lane)
{
    stage_tile(buf,        Ah, lda, bm, k, wid, lane);
    stage_tile(buf + 4096, Bh, ldb, bn, k, wid, lane);
    if (TERMS == 2) stage_tile(buf + 8192, Bl, ldb, bn, k, wid, lane);
}

static __device__ __forceinline__ short8 frag(const ushort* lds, int row, int fq) {
    int a = row * 64 + fq * 16;
    int b = a ^ (((a >> 7) & 7) << 4);
    return *(const short8*)((const char*)lds + b);
}

template<int TERMS>
static __device__ __forceinline__ void compute_tile(
    const ushort* buf, int wr, int wc, int fr, int fq, f32x4 acc[4][4])
{
    const ushort* sAh = buf;
    const ushort* sBh = buf + 4096;
    const ushort* sBl = buf + 8192;
    short8 a_h[4], b_h[4], b_l[4];
    #pragma unroll
    for (int m = 0; m < 4; ++m)
        a_h[m] = frag(sAh, wr + m * 16 + fr, fq);
    #pragma unroll
    for (int n = 0; n < 4; ++n) {
        b_h[n] = frag(sBh, wc + n * 16 + fr, fq);
        if (TERMS == 2) b_l[n] = frag(sBl, wc + n * 16 + fr, fq);
    }
    #pragma unroll
    for (int m = 0; m < 4; ++m)
        #pragma unroll
        for (int n = 0; n < 4; ++n) {
            acc[m][n] = __builtin_amdgcn_mfma_f32_16x16x32_bf16(a_h[m], b_h[n], acc[m][n], 0, 0, 0);
            if (TERMS == 2)
                acc[m][n] = __builtin_amdgcn_mfma_f32_16x16x32_bf16(a_h[m], b_l[n], acc[m][n], 0, 0, 0);
        }
}

template<int TERMS, int EPI>
__global__ __launch_bounds__(256) void gemm_bt(
    const ushort* __restrict__ Ah,
    const ushort* __restrict__ Bh, const ushort* __restrict__ Bl,
    float* __restrict__ C, ushort* __restrict__ oh, ushort* __restrict__ ol,
    const float* __restrict__ bvec,
    int M, int N, int lda, int ldb, int ldc, int kspl)
{
    constexpr int TILE = TERMS == 1 ? 8192 : 12288;   // ushorts per buffer
    __shared__ ushort sm[2 * TILE];

    const int tid = threadIdx.x, wid = tid >> 6, lane = tid & 63;
    const int bm = blockIdx.y * 128, bn = blockIdx.x * 128;
    const int kb = blockIdx.z * kspl;
    const int wr = (wid >> 1) * 64, wc = (wid & 1) * 64;
    const int fr = lane & 15, fq = lane >> 4;

    f32x4 acc[4][4] = {};

    stage_all<TERMS>(sm, Ah, Bh, Bl, lda, ldb, bm, bn, kb, wid, lane);
    __syncthreads();
    int cur = 0;
    for (int k0 = 32; k0 < kspl; k0 += 32) {
        ushort* nbuf       = cur ? sm : sm + TILE;
        const ushort* cbuf = cur ? sm + TILE : sm;
        stage_all<TERMS>(nbuf, Ah, Bh, Bl, lda, ldb, bm, bn, kb + k0, wid, lane);
        compute_tile<TERMS>(cbuf, wr, wc, fr, fq, acc);
        __syncthreads();
        cur ^= 1;
    }
    compute_tile<TERMS>(cur ? sm + TILE : sm, wr, wc, fr, fq, acc);

    #pragma unroll
    for (int m = 0; m < 4; ++m) {
        int rbase = bm + wr + m * 16 + fq * 4;
        #pragma unroll
        for (int n = 0; n < 4; ++n) {
            int col = bn + wc + n * 16 + fr;
            if (col >= N) continue;
            if (EPI == 0) {
                #pragma unroll
                for (int j = 0; j < 4; ++j)
                    C[((size_t)blockIdx.z * M + rbase + j) * ldc + col] = acc[m][n][j];
            } else {
                float bb = bvec[col];
                #pragma unroll
                for (int j = 0; j < 4; ++j) {
                    float v = softplus_f(acc[m][n][j] + bb);
                    ushort hh = f2bf(v);
                    size_t off = (size_t)(rbase + j) * ldc + col;
                    oh[off] = hh;
                    ol[off] = f2bf(v - bf2f(hh));
                }
            }
        }
    }
}

// ---------------------------------------------------------------------------
// reduce_xproj: sum 8 split-K parts -> xdbl; also emit dt_lr as bf16 hi.
// ---------------------------------------------------------------------------
__global__ __launch_bounds__(256) void reduce_xproj(
    const float* __restrict__ p, float* __restrict__ xdbl,
    ushort* __restrict__ DTh)
{
    int i = blockIdx.x * 256 + threadIdx.x;
    if (i >= 2048 * 96) return;
    float s = 0.f;
    #pragma unroll
    for (int c = 0; c < 8; ++c) s += p[i + (size_t)c * (2048 * 96)];
    xdbl[i] = s;
    int row = i / 96, col = i - row * 96;
    if (col < 64) DTh[row * 64 + col] = f2bf(s);
}

// ---------------------------------------------------------------------------
__global__ __launch_bounds__(256) void reduceN(
    const float* __restrict__ p, float* __restrict__ o, int n, int nch)
{
    int i = blockIdx.x * 256 + threadIdx.x;
    if (i >= n) return;
    float s = 0.f;
    for (int c = 0; c < nch; ++c) s += p[i + (size_t)c * n];
    o[i] = s;
}

// ---------------------------------------------------------------------------
// Depthwise causal conv (k=4) + bias + SiLU -> u as bf16 hi/lo.
// ---------------------------------------------------------------------------
__global__ __launch_bounds__(256) void conv_silu(
    const float* __restrict__ xz, const float* __restrict__ w,
    const float* __restrict__ bias, ushort* __restrict__ uh,
    ushort* __restrict__ ul)
{
    int idx = blockIdx.x * 256 + threadIdx.x;
    if (idx >= B_ * L_ * DI) return;
    int d  = idx & (DI - 1);
    int bl = idx >> 11;
    int l  = bl & (L_ - 1);

    const float w0 = w[d * 4 + 0], w1 = w[d * 4 + 1];
    const float w2 = w[d * 4 + 2], w3 = w[d * 4 + 3];
    float s = bias[d];
    size_t base = (size_t)bl * 4096 + d;
    if (l >= 3) s = fmaf(w0, xz[base - 3 * 4096], s);
    if (l >= 2) s = fmaf(w1, xz[base - 2 * 4096], s);
    if (l >= 1) s = fmaf(w2, xz[base - 1 * 4096], s);
    s = fmaf(w3, xz[base], s);
    float v = s / (1.f + __expf(-s));
    ushort h = f2bf(v);
    uh[idx] = h;
    ul[idx] = f2bf(v - bf2f(h));
}

// ---------------------------------------------------------------------------
// Scan phase A: lane owns channel d for chunk c. h[16], Adn[16] in regs.
// ---------------------------------------------------------------------------
__global__ __launch_bounds__(256) void scan_partial(
    const ushort* __restrict__ Dh, const ushort* __restrict__ Dl,
    const ushort* __restrict__ uh, const ushort* __restrict__ ul,
    const float* __restrict__ xdbl, const float* __restrict__ A_log,
    float* __restrict__ sA, float* __restrict__ sH)
{
    __shared__ float Bs[CL][16];
    const int tid  = threadIdx.x;
    const int dblk = blockIdx.x & 7;
    const int c    = (blockIdx.x >> 3) & (NC - 1);
    const int b    = blockIdx.x >> 8;
    const int d    = dblk * 256 + tid;
    const int bl0  = b * L_ + c * CL;

    for (int i = tid; i < CL * 16; i += 256) {
        int t = i >> 4, n = i & 15;
        Bs[t][n] = xdbl[(size_t)(bl0 + t) * 96 + DR + n];
    }
    __syncthreads();

    float Adn[16];
    #pragma unroll
    for (int q = 0; q < 4; ++q) {
        float4 al = *(const float4*)&A_log[d * DS + q * 4];
        Adn[q * 4 + 0] = -__expf(al.x);
        Adn[q * 4 + 1] = -__expf(al.y);
        Adn[q * 4 + 2] = -__expf(al.z);
        Adn[q * 4 + 3] = -__expf(al.w);
    }
    float h[16];
    #pragma unroll
    for (int n = 0; n < 16; ++n) h[n] = 0.f;
    float S = 0.f;

    size_t pd = (size_t)bl0 * DI + d;
    for (int t = 0; t < CL; ++t) {
        float dv = bf2f(Dh[pd]) + bf2f(Dl[pd]);
        float uv = bf2f(uh[pd]) + bf2f(ul[pd]);
        float du = dv * uv;
        S += dv;
        float Bv[16];
        *(float4*)&Bv[0]  = *(const float4*)&Bs[t][0];
        *(float4*)&Bv[4]  = *(const float4*)&Bs[t][4];
        *(float4*)&Bv[8]  = *(const float4*)&Bs[t][8];
        *(float4*)&Bv[12] = *(const float4*)&Bs[t][12];
        #pragma unroll
        for (int n = 0; n < 16; ++n) {
            float dA = __expf(dv * Adn[n]);
            h[n] = fmaf(dA, h[n], du * Bv[n]);
        }
        pd += DI;
    }

    size_t o = (((size_t)c * B_ + b) * DI + d) * DS;
    float aP[16], hh[16];
    #pragma unroll
    for (int n = 0; n < 16; ++n) { aP[n] = __expf(S * Adn[n]); hh[n] = h[n]; }
    #pragma unroll
    for (int q = 0; q < 4; ++q) {
        *(float4*)&sA[o + q * 4] = *(float4*)&aP[q * 4];
        *(float4*)&sH[o + q * 4] = *(float4*)&hh[q * 4];
    }
}

// ---------------------------------------------------------------------------
__global__ __launch_bounds__(256) void scan_combine(
    const float* __restrict__ sA, const float* __restrict__ sH,
    float* __restrict__ hinit)
{
    int idx = blockIdx.x * 256 + threadIdx.x;   // (b,d,n)
    int n = idx & 15;
    int d = (idx >> 4) & (DI - 1);
    int b = idx >> 15;
    float h = 0.f;
    #pragma unroll
    for (int c = 0; c < NC; ++c) {
        size_t o = (((size_t)c * B_ + b) * DI + d) * DS + n;
        hinit[o] = h;
        h = fmaf(sA[o], h, sH[o]);
    }
}

// ---------------------------------------------------------------------------
// Scan phase C: rescan chunk from h_init; y-dot in regs; skip + z-gate
// fused; writes y as bf16 HI (GEMM_out A-operand).
// ---------------------------------------------------------------------------
__global__ __launch_bounds__(256) void scan_final(
    const ushort* __restrict__ Dh, const ushort* __restrict__ Dl,
    const ushort* __restrict__ uh, const ushort* __restrict__ ul,
    const float* __restrict__ xdbl, const float* __restrict__ xz,
    const float* __restrict__ A_log, const float* __restrict__ D_skip,
    const float* __restrict__ hinit, ushort* __restrict__ yh)
{
    __shared__ float Bs[CL][16];
    __shared__ float Cs[CL][16];
    const int tid  = threadIdx.x;
    const int dblk = blockIdx.x & 7;
    const int c    = (blockIdx.x >> 3) & (NC - 1);
    const int b    = blockIdx.x >> 8;
    const int d    = dblk * 256 + tid;
    const int bl0  = b * L_ + c * CL;

    for (int i = tid; i < CL * 16; i += 256) {
        int t = i >> 4, n = i & 15;
        size_t px = (size_t)(bl0 + t) * 96 + DR + n;
        Bs[t][n] = xdbl[px];
        Cs[t][n] = xdbl[px + DS];
    }
    __syncthreads();

    float Adn[16];
    #pragma unroll
    for (int q = 0; q < 4; ++q) {
        float4 al = *(const float4*)&A_log[d * DS + q * 4];
        Adn[q * 4 + 0] = -__expf(al.x);
        Adn[q * 4 + 1] = -__expf(al.y);
        Adn[q * 4 + 2] = -__expf(al.z);
        Adn[q * 4 + 3] = -__expf(al.w);
    }
    const float Dd = D_skip[d];

    float h[16];
    size_t o = (((size_t)c * B_ + b) * DI + d) * DS;
    #pragma unroll
    for (int q = 0; q < 4; ++q)
        *(float4*)&h[q * 4] = *(const float4*)&hinit[o + q * 4];

    size_t pd = (size_t)bl0 * DI + d;
    size_t pz = (size_t)bl0 * 4096 + 2048 + d;
    for (int t = 0; t < CL; ++t) {
        float dv = bf2f(Dh[pd]) + bf2f(Dl[pd]);
        float uv = bf2f(uh[pd]) + bf2f(ul[pd]);
        float du = dv * uv;
        float Bv[16], Cv[16];
        *(float4*)&Bv[0]  = *(const float4*)&Bs[t][0];
        *(float4*)&Bv[4]  = *(const float4*)&Bs[t][4];
        *(float4*)&Bv[8]  = *(const float4*)&Bs[t][8];
        *(float4*)&Bv[12] = *(const float4*)&Bs[t][12];
        *(float4*)&Cv[0]  = *(const float4*)&Cs[t][0];
        *(float4*)&Cv[4]  = *(const float4*)&Cs[t][4];
        *(float4*)&Cv[8]  = *(const float4*)&Cs[t][8];
        *(float4*)&Cv[12] = *(const float4*)&Cs[t][12];
        float acc = 0.f;
        #pragma unroll
        for (int n = 0; n < 16; ++n) {
            float dA = __expf(dv * Adn[n]);
            h[n] = fmaf(dA, h[n], du * Bv[n]);
            acc = fmaf(h[n], Cv[n], acc);
        }
        float zv = xz[pz];
        float yv = acc + Dd * uv;
        yv *= zv / (1.f + __expf(-zv));
        yh[pd] = f2bf(yv);
        pd += DI; pz += 4096;
    }
}

// ---------------------------------------------------------------------------
extern "C" void kernel_launch(void* const* d_in, const int* in_sizes, int n_in,
                              void* d_out, int out_size, void* d_ws, size_t ws_size,
                              hipStream_t stream)
{
    const float* x      = (const float*)d_in[0];
    const float* W_in   = (const float*)d_in[1];
    const float* conv_w = (const float*)d_in[2];
    const float* conv_b = (const float*)d_in[3];
    const float* W_xprj = (const float*)d_in[4];
    const float* W_dt   = (const float*)d_in[5];
    const float* b_dt   = (const float*)d_in[6];
    const float* A_log  = (const float*)d_in[7];
    const float* D_skip = (const float*)d_in[8];
    const float* W_out  = (const float*)d_in[9];
    float* out = (float*)d_out;

    char* ws = (char*)d_ws;
    float*  xz    = (float*)(ws + 0);            // 32M (live gemm1->scan_final)
    ushort* Dh    = (ushort*)(ws + 33554432);    // 8M  } softplus'd delta
    ushort* Dl    = (ushort*)(ws + 41943040);    // 8M  }
    float*  xdbl  = (float*)(ws + 50331648);     // 768K
    // rotating region 57.4M..82.6M:
    ushort* Xh    = (ushort*)(ws + 57409536);    // 4M  (prep -> gemm1)
    float*  parts = (float*)(ws + 57409536);     // 6M  (xproj split-K x8)
    ushort* WIh   = (ushort*)(ws + 65798144);    // 8M  (prep -> gemm1)
    ushort* WIl   = (ushort*)(ws + 74186752);    // 8M  (end 82575360)
    float*  sA    = (float*)(ws + 57409536);     // 8M  (scan)
    float*  sH    = (float*)(ws + 65798144);     // 8M
    float*  hin   = (float*)(ws + 74186752);     // 8M (end 82575360)
    ushort* Yh    = (ushort*)(ws + 57409536);    // 8M  (scan_final out, over sA)
    float*  parts2= (float*)(ws + 65798144);     // 16M (gemm_out split-K x2,
                                                 //      over sH+hin, post-scan)
    ushort* Uh    = (ushort*)(ws + 82575360);    // 8M
    ushort* Ul    = (ushort*)(ws + 90963968);    // 8M
    ushort* Woh   = (ushort*)(ws + 82575360);    // 4M  (over Uh, post-scan)
    ushort* WXh   = (ushort*)(ws + 99352576);    // 512K
    ushort* WXl   = (ushort*)(ws + 99876864);    // 512K
    ushort* DTh   = (ushort*)(ws + 100401152);   // 256K
    ushort* WDh   = (ushort*)(ws + 100914176);   // 256K
    ushort* WDl   = (ushort*)(ws + 101170688);   // 256K (end 101427200 = proven cap)

    dim3 blk(256);
    const int M = B_ * L_;   // 2048

    // ---- input conversions (x hi; W_in/W_xproj/W_dt hi/lo) ----
    prep_all<<<dim3(5504), blk, 0, stream>>>(
        x, W_in, W_xprj, W_dt, Xh, WIh, WIl, WXh, WXl, WDh, WDl);

    // ---- xz = x @ W_in : 2-term (scan-path precision) ----
    gemm_bt<2, 0><<<dim3(32, 16, 1), blk, 0, stream>>>(
        Xh, WIh, WIl, xz, nullptr, nullptr, nullptr,
        M, 4096, DM, DM, 4096, DM);

    // ---- u = silu(conv(x_in)+b) -> bf16 hi/lo ----
    conv_silu<<<dim3((B_ * L_ * DI) / 256), blk, 0, stream>>>(xz, conv_w, conv_b, Uh, Ul);

    // ---- x_dbl = u @ W_xproj : 2-term, split-K x8 ----
    gemm_bt<2, 0><<<dim3(1, 16, 8), blk, 0, stream>>>(
        Uh, WXh, WXl, parts, nullptr, nullptr, nullptr,
        M, 96, DI, DI, 96, 256);
    reduce_xproj<<<dim3(768), blk, 0, stream>>>(parts, xdbl, DTh);

    // ---- delta = softplus(dt_lr @ W_dt + b_dt) : 2-term, fused epi ----
    gemm_bt<2, 1><<<dim3(16, 16, 1), blk, 0, stream>>>(
        DTh, WDh, WDl, nullptr, Dh, Dl, b_dt,
        M, DI, DR, DR, DI, DR);

    // ---- chunked selective scan ----
    scan_partial<<<dim3(B_ * NC * 8), blk, 0, stream>>>(
        Dh, Dl, Uh, Ul, xdbl, A_log, sA, sH);
    scan_combine<<<dim3((B_ * DI * DS) / 256), blk, 0, stream>>>(sA, sH, hin);
    scan_final<<<dim3(B_ * NC * 8), blk, 0, stream>>>(
        Dh, Dl, Uh, Ul, xdbl, xz, A_log, D_skip, hin, Yh);

    // ---- out = y @ W_out : 1-term, split-K x2 -> parts2 -> reduce ----
    convBT<<<dim3(DM / 32, DI / 32), blk, 0, stream>>>(W_out, Woh, DI, DM, DM);
    gemm_bt<1, 0><<<dim3(8, 16, 2), blk, 0, stream>>>(
        Yh, Woh, nullptr, parts2, nullptr, nullptr, nullptr,
        M, DM, DI, DI, DM, 1024);
    reduceN<<<dim3(2097152 / 256), blk, 0, stream>>>(parts2, out, M * DM, 2);
}

// Round 11
// 181.905 us; speedup vs baseline: 10.6363x; 1.1241x over previous
//
#include <hip/hip_runtime.h>
#include <cmath>

#define B_  2
#define L_  1024
#define DM  1024
#define DI  2048
#define DS  16
#define DR  64
#define NC  32         // scan time-chunks
#define CL  (L_/NC)    // 32 steps per chunk

typedef __attribute__((ext_vector_type(8))) short short8;
typedef __attribute__((ext_vector_type(4))) float f32x4;

static __device__ __forceinline__ ushort f2bf(float f) {
    union { float f; unsigned u; } c; c.f = f;
    unsigned u = c.u;
    return (ushort)((u + 0x7fffu + ((u >> 16) & 1u)) >> 16);   // RNE
}
static __device__ __forceinline__ float bf2f(ushort h) {
    union { unsigned u; float f; } c; c.u = ((unsigned)h) << 16;
    return c.f;
}

static __device__ __forceinline__ float softplus_f(float v) {
    return (v > 20.f) ? v : log1pf(__expf(v));
}

// ---------------------------------------------------------------------------
// bt_body: transpose-convert one 32x32 tile of fp32 [K][N] -> bf16 [N][K]
// (hi, and lo if ol != nullptr). Rows n >= N zero-padded to Npad.
// ---------------------------------------------------------------------------
static __device__ void bt_body(const float* __restrict__ in,
                               ushort* __restrict__ oh, ushort* __restrict__ ol,
                               int K, int N, int Npad, int bx, int by,
                               float (*t)[33])
{
    const int tid = threadIdx.x;
    const int tx = tid & 31, ty = tid >> 5;
    const int n0 = bx * 32, k0 = by * 32;
    #pragma unroll
    for (int i = 0; i < 4; ++i) {
        int k = k0 + ty * 4 + i, n = n0 + tx;
        t[ty * 4 + i][tx] = (n < N) ? in[(size_t)k * N + n] : 0.f;
    }
    __syncthreads();
    #pragma unroll
    for (int i = 0; i < 4; ++i) {
        int r = n0 + ty * 4 + i;
        int c = k0 + tx;
        if (r < Npad) {
            float v = t[tx][ty * 4 + i];
            ushort h = f2bf(v);
            oh[(size_t)r * K + c] = h;
            if (ol) ol[(size_t)r * K + c] = f2bf(v - bf2f(h));
        }
    }
}

// ---------------------------------------------------------------------------
// prep_all: input conversions (x and the three pre-scan weights).
//  [0,4096)     : W_in^T  hi ONLY      (K=1024, N=4096)  <- tested this round
//  [4096,4352)  : W_xproj^T hi/lo      (K=2048, N=96->128)
//  [4352,4480)  : W_dt^T hi/lo         (K=64,   N=2048)
//  [4480,5504)  : x -> bf16 hi rows
// ---------------------------------------------------------------------------
__global__ __launch_bounds__(256) void prep_all(
    const float* __restrict__ x, const float* __restrict__ W_in,
    const float* __restrict__ W_xprj, const float* __restrict__ W_dt,
    ushort* __restrict__ Xh, ushort* __restrict__ WIh,
    ushort* __restrict__ WXh, ushort* __restrict__ WXl,
    ushort* __restrict__ WDh, ushort* __restrict__ WDl)
{
    __shared__ float t[32][33];
    int blk = blockIdx.x;
    if (blk < 4096) {
        bt_body(W_in, WIh, nullptr, 1024, 4096, 4096, blk & 127, blk >> 7, t);
    } else if (blk < 4352) {
        int b2 = blk - 4096;
        bt_body(W_xprj, WXh, WXl, 2048, 96, 128, b2 & 3, b2 >> 2, t);
    } else if (blk < 4480) {
        int b2 = blk - 4352;
        bt_body(W_dt, WDh, WDl, 64, 2048, 2048, b2 & 63, b2 >> 6, t);
    } else {
        int v = (blk - 4480) * 256 + threadIdx.x;    // over 262144
        int r  = v >> 7;
        int c8 = v & 127;
        const float* p = x + (size_t)r * DM + c8 * 8;
        float4 v0 = *(const float4*)p;
        float4 v1 = *(const float4*)(p + 4);
        float vv[8] = {v0.x, v0.y, v0.z, v0.w, v1.x, v1.y, v1.z, v1.w};
        unsigned h[4];
        #pragma unroll
        for (int j = 0; j < 4; ++j)
            h[j] = (unsigned)f2bf(vv[2*j]) | ((unsigned)f2bf(vv[2*j+1]) << 16);
        size_t o = (size_t)r * 1024 + c8 * 8;
        *(uint4*)&Xh[o] = make_uint4(h[0], h[1], h[2], h[3]);
    }
}

// ---------------------------------------------------------------------------
// convBT standalone (W_out after scan frees its region). hi only.
// ---------------------------------------------------------------------------
__global__ __launch_bounds__(256) void convBT(
    const float* __restrict__ in, ushort* __restrict__ oh,
    int K, int N, int Npad)
{
    __shared__ float t[32][33];
    bt_body(in, oh, nullptr, K, N, Npad, blockIdx.x, blockIdx.y, t);
}

// ---------------------------------------------------------------------------
// Shared GEMM building blocks. XOR-swizzle involution
// perm(a)=a^(((a>>7)&7)<<4): bits 4-6 ^= bits 7-9 (preserved) — involution
// within any aligned 1KB region; applied to BOTH gload source addr and
// frag read addr (both-sides-or-neither).
// ---------------------------------------------------------------------------
static __device__ __forceinline__ void stage_tile(
    ushort* lds, const ushort* __restrict__ g, int ld, int row0, int k0,
    int wid, int lane)
{
    #pragma unroll
    for (int it = 0; it < 2; ++it) {
        int o  = wid * 2048 + it * 1024;          // tile-local byte base
        int ob = o + lane * 16;
        int a  = ob ^ (((ob >> 7) & 7) << 4);     // logical byte address
        int row = a >> 6;
        int lc  = (a >> 4) & 3;
        const ushort* gp = g + (size_t)(row0 + row) * ld + k0 + lc * 8;
        __builtin_amdgcn_global_load_lds(
            (const __attribute__((address_space(1))) void*)gp,
            (__attribute__((address_space(3))) void*)((char*)lds + o),
            16, 0, 0);
    }
}

// 64-row tile (4KB): one 1KB gload per wave
static __device__ __forceinline__ void stage_tile64(
    ushort* lds, const ushort* __restrict__ g, int ld, int row0, int k0,
    int wid, int lane)
{
    int o  = wid * 1024;
    int ob = o + lane * 16;
    int a  = ob ^ (((ob >> 7) & 7) << 4);
    int row = a >> 6;
    int lc  = (a >> 4) & 3;
    const ushort* gp = g + (size_t)(row0 + row) * ld + k0 + lc * 8;
    __builtin_amdgcn_global_load_lds(
        (const __attribute__((address_space(1))) void*)gp,
        (__attribute__((address_space(3))) void*)((char*)lds + o),
        16, 0, 0);
}

static __device__ __forceinline__ short8 frag(const ushort* lds, int row, int fq) {
    int a = row * 64 + fq * 16;
    int b = a ^ (((a >> 7) & 7) << 4);
    return *(const short8*)((const char*)lds + b);
}

// ---------------------------------------------------------------------------
// gemm_bt: C[M][N] = A[M][K] @ B[N][K]^T, 128x128 tile, BK=32, 4 waves,
// double-buffered LDS. TERMS=1: Ah*Bh. TERMS=2: Ah*(Bh+Bl).
// EPI=0: fp32 store (+blockIdx.z*M row offset). EPI=1: softplus->bf16 hi/lo.
// ---------------------------------------------------------------------------
template<int TERMS>
static __device__ __forceinline__ void stage_all(
    ushort* buf, const ushort* Ah, const ushort* Bh, const ushort* Bl,
    int lda, int ldb, int bm, int bn, int k, int wid, int lane)
{
    stage_tile(buf,        Ah, lda, bm, k, wid, lane);
    stage_tile(buf + 4096, Bh, ldb, bn, k, wid, lane);
    if (TERMS == 2) stage_tile(buf + 8192, Bl, ldb, bn, k, wid, lane);
}

template<int TERMS>
static __device__ __forceinline__ void compute_tile(
    const ushort* buf, int wr, int wc, int fr, int fq, f32x4 acc[4][4])
{
    const ushort* sAh = buf;
    const ushort* sBh = buf + 4096;
    const ushort* sBl = buf + 8192;
    short8 a_h[4], b_h[4], b_l[4];
    #pragma unroll
    for (int m = 0; m < 4; ++m)
        a_h[m] = frag(sAh, wr + m * 16 + fr, fq);
    #pragma unroll
    for (int n = 0; n < 4; ++n) {
        b_h[n] = frag(sBh, wc + n * 16 + fr, fq);
        if (TERMS == 2) b_l[n] = frag(sBl, wc + n * 16 + fr, fq);
    }
    #pragma unroll
    for (int m = 0; m < 4; ++m)
        #pragma unroll
        for (int n = 0; n < 4; ++n) {
            acc[m][n] = __builtin_amdgcn_mfma_f32_16x16x32_bf16(a_h[m], b_h[n], acc[m][n], 0, 0, 0);
            if (TERMS == 2)
                acc[m][n] = __builtin_amdgcn_mfma_f32_16x16x32_bf16(a_h[m], b_l[n], acc[m][n], 0, 0, 0);
        }
}

template<int TERMS, int EPI>
__global__ __launch_bounds__(256) void gemm_bt(
    const ushort* __restrict__ Ah,
    const ushort* __restrict__ Bh, const ushort* __restrict__ Bl,
    float* __restrict__ C, ushort* __restrict__ oh, ushort* __restrict__ ol,
    const float* __restrict__ bvec,
    int M, int N, int lda, int ldb, int ldc, int kspl)
{
    constexpr int TILE = TERMS == 1 ? 8192 : 12288;   // ushorts per buffer
    __shared__ ushort sm[2 * TILE];

    const int tid = threadIdx.x, wid = tid >> 6, lane = tid & 63;
    const int bm = blockIdx.y * 128, bn = blockIdx.x * 128;
    const int kb = blockIdx.z * kspl;
    const int wr = (wid >> 1) * 64, wc = (wid & 1) * 64;
    const int fr = lane & 15, fq = lane >> 4;

    f32x4 acc[4][4] = {};

    stage_all<TERMS>(sm, Ah, Bh, Bl, lda, ldb, bm, bn, kb, wid, lane);
    __syncthreads();
    int cur = 0;
    for (int k0 = 32; k0 < kspl; k0 += 32) {
        ushort* nbuf       = cur ? sm : sm + TILE;
        const ushort* cbuf = cur ? sm + TILE : sm;
        stage_all<TERMS>(nbuf, Ah, Bh, Bl, lda, ldb, bm, bn, kb + k0, wid, lane);
        compute_tile<TERMS>(cbuf, wr, wc, fr, fq, acc);
        __syncthreads();
        cur ^= 1;
    }
    compute_tile<TERMS>(cur ? sm + TILE : sm, wr, wc, fr, fq, acc);

    #pragma unroll
    for (int m = 0; m < 4; ++m) {
        int rbase = bm + wr + m * 16 + fq * 4;
        #pragma unroll
        for (int n = 0; n < 4; ++n) {
            int col = bn + wc + n * 16 + fr;
            if (col >= N) continue;
            if (EPI == 0) {
                #pragma unroll
                for (int j = 0; j < 4; ++j)
                    C[((size_t)blockIdx.z * M + rbase + j) * ldc + col] = acc[m][n][j];
            } else {
                float bb = bvec[col];
                #pragma unroll
                for (int j = 0; j < 4; ++j) {
                    float v = softplus_f(acc[m][n][j] + bb);
                    ushort hh = f2bf(v);
                    size_t off = (size_t)(rbase + j) * ldc + col;
                    oh[off] = hh;
                    ol[off] = f2bf(v - bf2f(hh));
                }
            }
        }
    }
}

// ---------------------------------------------------------------------------
// gemm_out64: C[M][N] = A[M][K] @ B[N][K]^T, 128x64 tile, full-K (no split),
// 1-term bf16, direct fp32 store. 4 waves as 2(M)x2(N); per wave 64x32.
// Grid (N/64, M/128) = 256 blocks -> full CU coverage without split-K.
// ---------------------------------------------------------------------------
__global__ __launch_bounds__(256) void gemm_out64(
    const ushort* __restrict__ Ah, const ushort* __restrict__ Bh,
    float* __restrict__ C, int K, int lda, int ldb, int ldc)
{
    __shared__ ushort sm[12288];                  // 24 KB: two 12 KB buffers
    const int tid = threadIdx.x, wid = tid >> 6, lane = tid & 63;
    const int bm = blockIdx.y * 128, bn = blockIdx.x * 64;
    const int wr = (wid >> 1) * 64, wc = (wid & 1) * 32;
    const int fr = lane & 15, fq = lane >> 4;

    f32x4 acc[4][2] = {};

    stage_tile  (sm,        Ah, lda, bm, 0, wid, lane);
    stage_tile64(sm + 4096, Bh, ldb, bn, 0, wid, lane);
    __syncthreads();
    int cur = 0;
    for (int k0 = 32; k0 < K; k0 += 32) {
        ushort* nbuf       = cur ? sm : sm + 6144;
        const ushort* cbuf = cur ? sm + 6144 : sm;
        stage_tile  (nbuf,        Ah, lda, bm, k0, wid, lane);
        stage_tile64(nbuf + 4096, Bh, ldb, bn, k0, wid, lane);
        // compute current
        {
            short8 a_h[4], b_h[2];
            #pragma unroll
            for (int m = 0; m < 4; ++m)
                a_h[m] = frag(cbuf, wr + m * 16 + fr, fq);
            #pragma unroll
            for (int n = 0; n < 2; ++n)
                b_h[n] = frag(cbuf + 4096, wc + n * 16 + fr, fq);
            #pragma unroll
            for (int m = 0; m < 4; ++m)
                #pragma unroll
                for (int n = 0; n < 2; ++n)
                    acc[m][n] = __builtin_amdgcn_mfma_f32_16x16x32_bf16(a_h[m], b_h[n], acc[m][n], 0, 0, 0);
        }
        __syncthreads();
        cur ^= 1;
    }
    {
        const ushort* cbuf = cur ? sm + 6144 : sm;
        short8 a_h[4], b_h[2];
        #pragma unroll
        for (int m = 0; m < 4; ++m)
            a_h[m] = frag(cbuf, wr + m * 16 + fr, fq);
        #pragma unroll
        for (int n = 0; n < 2; ++n)
            b_h[n] = frag(cbuf + 4096, wc + n * 16 + fr, fq);
        #pragma unroll
        for (int m = 0; m < 4; ++m)
            #pragma unroll
            for (int n = 0; n < 2; ++n)
                acc[m][n] = __builtin_amdgcn_mfma_f32_16x16x32_bf16(a_h[m], b_h[n], acc[m][n], 0, 0, 0);
    }

    #pragma unroll
    for (int m = 0; m < 4; ++m) {
        int rbase = bm + wr + m * 16 + fq * 4;
        #pragma unroll
        for (int n = 0; n < 2; ++n) {
            int col = bn + wc + n * 16 + fr;
            #pragma unroll
            for (int j = 0; j < 4; ++j)
                C[(size_t)(rbase + j) * ldc + col] = acc[m][n][j];
        }
    }
}

// ---------------------------------------------------------------------------
// reduce_xproj: sum 8 split-K parts -> xdbl; also emit dt_lr as bf16 hi.
// ---------------------------------------------------------------------------
__global__ __launch_bounds__(256) void reduce_xproj(
    const float* __restrict__ p, float* __restrict__ xdbl,
    ushort* __restrict__ DTh)
{
    int i = blockIdx.x * 256 + threadIdx.x;
    if (i >= 2048 * 96) return;
    float s = 0.f;
    #pragma unroll
    for (int c = 0; c < 8; ++c) s += p[i + (size_t)c * (2048 * 96)];
    xdbl[i] = s;
    int row = i / 96, col = i - row * 96;
    if (col < 64) DTh[row * 64 + col] = f2bf(s);
}

// ---------------------------------------------------------------------------
// Depthwise causal conv (k=4) + bias + SiLU -> u as bf16 hi/lo.
// ---------------------------------------------------------------------------
__global__ __launch_bounds__(256) void conv_silu(
    const float* __restrict__ xz, const float* __restrict__ w,
    const float* __restrict__ bias, ushort* __restrict__ uh,
    ushort* __restrict__ ul)
{
    int idx = blockIdx.x * 256 + threadIdx.x;
    if (idx >= B_ * L_ * DI) return;
    int d  = idx & (DI - 1);
    int bl = idx >> 11;
    int l  = bl & (L_ - 1);

    const float w0 = w[d * 4 + 0], w1 = w[d * 4 + 1];
    const float w2 = w[d * 4 + 2], w3 = w[d * 4 + 3];
    float s = bias[d];
    size_t base = (size_t)bl * 4096 + d;
    if (l >= 3) s = fmaf(w0, xz[base - 3 * 4096], s);
    if (l >= 2) s = fmaf(w1, xz[base - 2 * 4096], s);
    if (l >= 1) s = fmaf(w2, xz[base - 1 * 4096], s);
    s = fmaf(w3, xz[base], s);
    float v = s / (1.f + __expf(-s));
    ushort h = f2bf(v);
    uh[idx] = h;
    ul[idx] = f2bf(v - bf2f(h));
}

// ---------------------------------------------------------------------------
// Scan phase A: lane owns channel d for chunk c. h[16], Adn[16] in regs.
// ---------------------------------------------------------------------------
__global__ __launch_bounds__(256) void scan_partial(
    const ushort* __restrict__ Dh, const ushort* __restrict__ Dl,
    const ushort* __restrict__ uh, const ushort* __restrict__ ul,
    const float* __restrict__ xdbl, const float* __restrict__ A_log,
    float* __restrict__ sA, float* __restrict__ sH)
{
    __shared__ float Bs[CL][16];
    const int tid  = threadIdx.x;
    const int dblk = blockIdx.x & 7;
    const int c    = (blockIdx.x >> 3) & (NC - 1);
    const int b    = blockIdx.x >> 8;
    const int d    = dblk * 256 + tid;
    const int bl0  = b * L_ + c * CL;

    for (int i = tid; i < CL * 16; i += 256) {
        int t = i >> 4, n = i & 15;
        Bs[t][n] = xdbl[(size_t)(bl0 + t) * 96 + DR + n];
    }
    __syncthreads();

    float Adn[16];
    #pragma unroll
    for (int q = 0; q < 4; ++q) {
        float4 al = *(const float4*)&A_log[d * DS + q * 4];
        Adn[q * 4 + 0] = -__expf(al.x);
        Adn[q * 4 + 1] = -__expf(al.y);
        Adn[q * 4 + 2] = -__expf(al.z);
        Adn[q * 4 + 3] = -__expf(al.w);
    }
    float h[16];
    #pragma unroll
    for (int n = 0; n < 16; ++n) h[n] = 0.f;
    float S = 0.f;

    size_t pd = (size_t)bl0 * DI + d;
    for (int t = 0; t < CL; ++t) {
        float dv = bf2f(Dh[pd]) + bf2f(Dl[pd]);
        float uv = bf2f(uh[pd]) + bf2f(ul[pd]);
        float du = dv * uv;
        S += dv;
        float Bv[16];
        *(float4*)&Bv[0]  = *(const float4*)&Bs[t][0];
        *(float4*)&Bv[4]  = *(const float4*)&Bs[t][4];
        *(float4*)&Bv[8]  = *(const float4*)&Bs[t][8];
        *(float4*)&Bv[12] = *(const float4*)&Bs[t][12];
        #pragma unroll
        for (int n = 0; n < 16; ++n) {
            float dA = __expf(dv * Adn[n]);
            h[n] = fmaf(dA, h[n], du * Bv[n]);
        }
        pd += DI;
    }

    size_t o = (((size_t)c * B_ + b) * DI + d) * DS;
    float aP[16], hh[16];
    #pragma unroll
    for (int n = 0; n < 16; ++n) { aP[n] = __expf(S * Adn[n]); hh[n] = h[n]; }
    #pragma unroll
    for (int q = 0; q < 4; ++q) {
        *(float4*)&sA[o + q * 4] = *(float4*)&aP[q * 4];
        *(float4*)&sH[o + q * 4] = *(float4*)&hh[q * 4];
    }
}

// ---------------------------------------------------------------------------
__global__ __launch_bounds__(256) void scan_combine(
    const float* __restrict__ sA, const float* __restrict__ sH,
    float* __restrict__ hinit)
{
    int idx = blockIdx.x * 256 + threadIdx.x;   // (b,d,n)
    int n = idx & 15;
    int d = (idx >> 4) & (DI - 1);
    int b = idx >> 15;
    float h = 0.f;
    #pragma unroll
    for (int c = 0; c < NC; ++c) {
        size_t o = (((size_t)c * B_ + b) * DI + d) * DS + n;
        hinit[o] = h;
        h = fmaf(sA[o], h, sH[o]);
    }
}

// ---------------------------------------------------------------------------
// Scan phase C: rescan chunk from h_init; y-dot in regs; skip + z-gate
// fused; writes y as bf16 HI (GEMM_out A-operand).
// ---------------------------------------------------------------------------
__global__ __launch_bounds__(256) void scan_final(
    const ushort* __restrict__ Dh, const ushort* __restrict__ Dl,
    const ushort* __restrict__ uh, const ushort* __restrict__ ul,
    const float* __restrict__ xdbl, const float* __restrict__ xz,
    const float* __restrict__ A_log, const float* __restrict__ D_skip,
    const float* __restrict__ hinit, ushort* __restrict__ yh)
{
    __shared__ float Bs[CL][16];
    __shared__ float Cs[CL][16];
    const int tid  = threadIdx.x;
    const int dblk = blockIdx.x & 7;
    const int c    = (blockIdx.x >> 3) & (NC - 1);
    const int b    = blockIdx.x >> 8;
    const int d    = dblk * 256 + tid;
    const int bl0  = b * L_ + c * CL;

    for (int i = tid; i < CL * 16; i += 256) {
        int t = i >> 4, n = i & 15;
        size_t px = (size_t)(bl0 + t) * 96 + DR + n;
        Bs[t][n] = xdbl[px];
        Cs[t][n] = xdbl[px + DS];
    }
    __syncthreads();

    float Adn[16];
    #pragma unroll
    for (int q = 0; q < 4; ++q) {
        float4 al = *(const float4*)&A_log[d * DS + q * 4];
        Adn[q * 4 + 0] = -__expf(al.x);
        Adn[q * 4 + 1] = -__expf(al.y);
        Adn[q * 4 + 2] = -__expf(al.z);
        Adn[q * 4 + 3] = -__expf(al.w);
    }
    const float Dd = D_skip[d];

    float h[16];
    size_t o = (((size_t)c * B_ + b) * DI + d) * DS;
    #pragma unroll
    for (int q = 0; q < 4; ++q)
        *(float4*)&h[q * 4] = *(const float4*)&hinit[o + q * 4];

    size_t pd = (size_t)bl0 * DI + d;
    size_t pz = (size_t)bl0 * 4096 + 2048 + d;
    for (int t = 0; t < CL; ++t) {
        float dv = bf2f(Dh[pd]) + bf2f(Dl[pd]);
        float uv = bf2f(uh[pd]) + bf2f(ul[pd]);
        float du = dv * uv;
        float Bv[16], Cv[16];
        *(float4*)&Bv[0]  = *(const float4*)&Bs[t][0];
        *(float4*)&Bv[4]  = *(const float4*)&Bs[t][4];
        *(float4*)&Bv[8]  = *(const float4*)&Bs[t][8];
        *(float4*)&Bv[12] = *(const float4*)&Bs[t][12];
        *(float4*)&Cv[0]  = *(const float4*)&Cs[t][0];
        *(float4*)&Cv[4]  = *(const float4*)&Cs[t][4];
        *(float4*)&Cv[8]  = *(const float4*)&Cs[t][8];
        *(float4*)&Cv[12] = *(const float4*)&Cs[t][12];
        float acc = 0.f;
        #pragma unroll
        for (int n = 0; n < 16; ++n) {
            float dA = __expf(dv * Adn[n]);
            h[n] = fmaf(dA, h[n], du * Bv[n]);
            acc = fmaf(h[n], Cv[n], acc);
        }
        float zv = xz[pz];
        float yv = acc + Dd * uv;
        yv *= zv / (1.f + __expf(-zv));
        yh[pd] = f2bf(yv);
        pd += DI; pz += 4096;
    }
}

// ---------------------------------------------------------------------------
extern "C" void kernel_launch(void* const* d_in, const int* in_sizes, int n_in,
                              void* d_out, int out_size, void* d_ws, size_t ws_size,
                              hipStream_t stream)
{
    const float* x      = (const float*)d_in[0];
    const float* W_in   = (const float*)d_in[1];
    const float* conv_w = (const float*)d_in[2];
    const float* conv_b = (const float*)d_in[3];
    const float* W_xprj = (const float*)d_in[4];
    const float* W_dt   = (const float*)d_in[5];
    const float* b_dt   = (const float*)d_in[6];
    const float* A_log  = (const float*)d_in[7];
    const float* D_skip = (const float*)d_in[8];
    const float* W_out  = (const float*)d_in[9];
    float* out = (float*)d_out;

    char* ws = (char*)d_ws;
    float*  xz    = (float*)(ws + 0);            // 32M (live gemm1->scan_final)
    ushort* Dh    = (ushort*)(ws + 33554432);    // 8M  } softplus'd delta
    ushort* Dl    = (ushort*)(ws + 41943040);    // 8M  }
    float*  xdbl  = (float*)(ws + 50331648);     // 768K
    // rotating region 57.4M..82.6M:
    ushort* Xh    = (ushort*)(ws + 57409536);    // 4M  (prep -> gemm1)
    float*  parts = (float*)(ws + 57409536);     // 6M  (xproj split-K x8)
    ushort* WIh   = (ushort*)(ws + 65798144);    // 8M  (prep -> gemm1)
    float*  sA    = (float*)(ws + 57409536);     // 8M  (scan)
    float*  sH    = (float*)(ws + 65798144);     // 8M
    float*  hin   = (float*)(ws + 74186752);     // 8M (end 82575360)
    ushort* Yh    = (ushort*)(ws + 57409536);    // 8M  (scan_final out, over sA)
    ushort* Uh    = (ushort*)(ws + 82575360);    // 8M
    ushort* Ul    = (ushort*)(ws + 90963968);    // 8M
    ushort* Woh   = (ushort*)(ws + 82575360);    // 4M  (over Uh, post-scan)
    ushort* WXh   = (ushort*)(ws + 99352576);    // 512K
    ushort* WXl   = (ushort*)(ws + 99876864);    // 512K
    ushort* DTh   = (ushort*)(ws + 100401152);   // 256K
    ushort* WDh   = (ushort*)(ws + 100914176);   // 256K
    ushort* WDl   = (ushort*)(ws + 101170688);   // 256K (end 101427200 = proven cap)

    dim3 blk(256);
    const int M = B_ * L_;   // 2048

    // ---- input conversions (x, W_in hi; W_xproj/W_dt hi/lo) ----
    prep_all<<<dim3(5504), blk, 0, stream>>>(
        x, W_in, W_xprj, W_dt, Xh, WIh, WXh, WXl, WDh, WDl);

    // ---- xz = x @ W_in : 1-term bf16 (precision test of record) ----
    gemm_bt<1, 0><<<dim3(32, 16, 1), blk, 0, stream>>>(
        Xh, WIh, nullptr, xz, nullptr, nullptr, nullptr,
        M, 4096, DM, DM, 4096, DM);

    // ---- u = silu(conv(x_in)+b) -> bf16 hi/lo ----
    conv_silu<<<dim3((B_ * L_ * DI) / 256), blk, 0, stream>>>(xz, conv_w, conv_b, Uh, Ul);

    // ---- x_dbl = u @ W_xproj : 2-term, split-K x8 ----
    gemm_bt<2, 0><<<dim3(1, 16, 8), blk, 0, stream>>>(
        Uh, WXh, WXl, parts, nullptr, nullptr, nullptr,
        M, 96, DI, DI, 96, 256);
    reduce_xproj<<<dim3(768), blk, 0, stream>>>(parts, xdbl, DTh);

    // ---- delta = softplus(dt_lr @ W_dt + b_dt) : 2-term, fused epi ----
    gemm_bt<2, 1><<<dim3(16, 16, 1), blk, 0, stream>>>(
        DTh, WDh, WDl, nullptr, Dh, Dl, b_dt,
        M, DI, DR, DR, DI, DR);

    // ---- chunked selective scan ----
    scan_partial<<<dim3(B_ * NC * 8), blk, 0, stream>>>(
        Dh, Dl, Uh, Ul, xdbl, A_log, sA, sH);
    scan_combine<<<dim3((B_ * DI * DS) / 256), blk, 0, stream>>>(sA, sH, hin);
    scan_final<<<dim3(B_ * NC * 8), blk, 0, stream>>>(
        Dh, Dl, Uh, Ul, xdbl, xz, A_log, D_skip, hin, Yh);

    // ---- out = y @ W_out : 128x64 tile, full-K, direct store ----
    convBT<<<dim3(DM / 32, DI / 32), blk, 0, stream>>>(W_out, Woh, DI, DM, DM);
    gemm_out64<<<dim3(DM / 64, M / 128), blk, 0, stream>>>(
        Yh, Woh, out, DI, DI, DI, DM);
}

// Round 12
// 175.432 us; speedup vs baseline: 11.0287x; 1.0369x over previous
//
#include <hip/hip_runtime.h>
#include <cmath>

#define B_  2
#define L_  1024
#define DM  1024
#define DI  2048
#define DS  16
#define DR  64
#define NC  32         // scan time-chunks
#define CL  (L_/NC)    // 32 steps per chunk

typedef __attribute__((ext_vector_type(8))) short short8;
typedef __attribute__((ext_vector_type(4))) float f32x4;

static __device__ __forceinline__ ushort f2bf(float f) {
    union { float f; unsigned u; } c; c.f = f;
    unsigned u = c.u;
    return (ushort)((u + 0x7fffu + ((u >> 16) & 1u)) >> 16);   // RNE
}
static __device__ __forceinline__ float bf2f(ushort h) {
    union { unsigned u; float f; } c; c.u = ((unsigned)h) << 16;
    return c.f;
}

static __device__ __forceinline__ float softplus_f(float v) {
    return (v > 20.f) ? v : log1pf(__expf(v));
}

// ---------------------------------------------------------------------------
// bt_body: transpose-convert one 32x32 tile of fp32 [K][N] -> bf16 [N][K]
// (hi, and lo if ol != nullptr). Rows n >= N zero-padded to Npad.
// ---------------------------------------------------------------------------
static __device__ void bt_body(const float* __restrict__ in,
                               ushort* __restrict__ oh, ushort* __restrict__ ol,
                               int K, int N, int Npad, int bx, int by,
                               float (*t)[33])
{
    const int tid = threadIdx.x;
    const int tx = tid & 31, ty = tid >> 5;
    const int n0 = bx * 32, k0 = by * 32;
    #pragma unroll
    for (int i = 0; i < 4; ++i) {
        int k = k0 + ty * 4 + i, n = n0 + tx;
        t[ty * 4 + i][tx] = (n < N) ? in[(size_t)k * N + n] : 0.f;
    }
    __syncthreads();
    #pragma unroll
    for (int i = 0; i < 4; ++i) {
        int r = n0 + ty * 4 + i;
        int c = k0 + tx;
        if (r < Npad) {
            float v = t[tx][ty * 4 + i];
            ushort h = f2bf(v);
            oh[(size_t)r * K + c] = h;
            if (ol) ol[(size_t)r * K + c] = f2bf(v - bf2f(h));
        }
    }
}

// ---------------------------------------------------------------------------
// prep_all: ALL input conversions in one kernel.
//  [0,4096)     : W_in^T  hi only      (K=1024, N=4096)
//  [4096,4352)  : W_xproj^T hi/lo      (K=2048, N=96->128)
//  [4352,4480)  : W_dt^T hi/lo         (K=64,   N=2048)
//  [4480,5504)  : x -> bf16 hi rows
//  [5504,7552)  : W_out^T hi only      (K=2048, N=1024)
// ---------------------------------------------------------------------------
__global__ __launch_bounds__(256) void prep_all(
    const float* __restrict__ x, const float* __restrict__ W_in,
    const float* __restrict__ W_xprj, const float* __restrict__ W_dt,
    const float* __restrict__ W_out,
    ushort* __restrict__ Xh, ushort* __restrict__ WIh,
    ushort* __restrict__ WXh, ushort* __restrict__ WXl,
    ushort* __restrict__ WDh, ushort* __restrict__ WDl,
    ushort* __restrict__ Woh)
{
    __shared__ float t[32][33];
    int blk = blockIdx.x;
    if (blk < 4096) {
        bt_body(W_in, WIh, nullptr, 1024, 4096, 4096, blk & 127, blk >> 7, t);
    } else if (blk < 4352) {
        int b2 = blk - 4096;
        bt_body(W_xprj, WXh, WXl, 2048, 96, 128, b2 & 3, b2 >> 2, t);
    } else if (blk < 4480) {
        int b2 = blk - 4352;
        bt_body(W_dt, WDh, WDl, 64, 2048, 2048, b2 & 63, b2 >> 6, t);
    } else if (blk < 5504) {
        int v = (blk - 4480) * 256 + threadIdx.x;    // over 262144
        int r  = v >> 7;
        int c8 = v & 127;
        const float* p = x + (size_t)r * DM + c8 * 8;
        float4 v0 = *(const float4*)p;
        float4 v1 = *(const float4*)(p + 4);
        float vv[8] = {v0.x, v0.y, v0.z, v0.w, v1.x, v1.y, v1.z, v1.w};
        unsigned h[4];
        #pragma unroll
        for (int j = 0; j < 4; ++j)
            h[j] = (unsigned)f2bf(vv[2*j]) | ((unsigned)f2bf(vv[2*j+1]) << 16);
        size_t o = (size_t)r * 1024 + c8 * 8;
        *(uint4*)&Xh[o] = make_uint4(h[0], h[1], h[2], h[3]);
    } else {
        int b2 = blk - 5504;
        bt_body(W_out, Woh, nullptr, 2048, 1024, 1024, b2 & 31, b2 >> 5, t);
    }
}

// ---------------------------------------------------------------------------
// Shared GEMM building blocks. XOR-swizzle involution
// perm(a)=a^(((a>>7)&7)<<4) applied to BOTH gload source addr and frag read.
// ---------------------------------------------------------------------------
static __device__ __forceinline__ void stage_tile(
    ushort* lds, const ushort* __restrict__ g, int ld, int row0, int k0,
    int wid, int lane)
{
    #pragma unroll
    for (int it = 0; it < 2; ++it) {
        int o  = wid * 2048 + it * 1024;          // tile-local byte base
        int ob = o + lane * 16;
        int a  = ob ^ (((ob >> 7) & 7) << 4);     // logical byte address
        int row = a >> 6;
        int lc  = (a >> 4) & 3;
        const ushort* gp = g + (size_t)(row0 + row) * ld + k0 + lc * 8;
        __builtin_amdgcn_global_load_lds(
            (const __attribute__((address_space(1))) void*)gp,
            (__attribute__((address_space(3))) void*)((char*)lds + o),
            16, 0, 0);
    }
}

// 64-row tile (4KB): one 1KB gload per wave
static __device__ __forceinline__ void stage_tile64(
    ushort* lds, const ushort* __restrict__ g, int ld, int row0, int k0,
    int wid, int lane)
{
    int o  = wid * 1024;
    int ob = o + lane * 16;
    int a  = ob ^ (((ob >> 7) & 7) << 4);
    int row = a >> 6;
    int lc  = (a >> 4) & 3;
    const ushort* gp = g + (size_t)(row0 + row) * ld + k0 + lc * 8;
    __builtin_amdgcn_global_load_lds(
        (const __attribute__((address_space(1))) void*)gp,
        (__attribute__((address_space(3))) void*)((char*)lds + o),
        16, 0, 0);
}

static __device__ __forceinline__ short8 frag(const ushort* lds, int row, int fq) {
    int a = row * 64 + fq * 16;
    int b = a ^ (((a >> 7) & 7) << 4);
    return *(const short8*)((const char*)lds + b);
}

// ---------------------------------------------------------------------------
// gemm_bt: C[M][N] = A[M][K] @ B[N][K]^T, 128x128 tile, BK=32, 4 waves,
// double-buffered LDS. TERMS=1: Ah*Bh. TERMS=2: Ah*(Bh+Bl).
// EPI=0: fp32 store (+blockIdx.z*M row offset). EPI=1: softplus->bf16 hi/lo.
// ---------------------------------------------------------------------------
template<int TERMS>
static __device__ __forceinline__ void stage_all(
    ushort* buf, const ushort* Ah, const ushort* Bh, const ushort* Bl,
    int lda, int ldb, int bm, int bn, int k, int wid, int lane)
{
    stage_tile(buf,        Ah, lda, bm, k, wid, lane);
    stage_tile(buf + 4096, Bh, ldb, bn, k, wid, lane);
    if (TERMS == 2) stage_tile(buf + 8192, Bl, ldb, bn, k, wid, lane);
}

template<int TERMS>
static __device__ __forceinline__ void compute_tile(
    const ushort* buf, int wr, int wc, int fr, int fq, f32x4 acc[4][4])
{
    const ushort* sAh = buf;
    const ushort* sBh = buf + 4096;
    const ushort* sBl = buf + 8192;
    short8 a_h[4], b_h[4], b_l[4];
    #pragma unroll
    for (int m = 0; m < 4; ++m)
        a_h[m] = frag(sAh, wr + m * 16 + fr, fq);
    #pragma unroll
    for (int n = 0; n < 4; ++n) {
        b_h[n] = frag(sBh, wc + n * 16 + fr, fq);
        if (TERMS == 2) b_l[n] = frag(sBl, wc + n * 16 + fr, fq);
    }
    #pragma unroll
    for (int m = 0; m < 4; ++m)
        #pragma unroll
        for (int n = 0; n < 4; ++n) {
            acc[m][n] = __builtin_amdgcn_mfma_f32_16x16x32_bf16(a_h[m], b_h[n], acc[m][n], 0, 0, 0);
            if (TERMS == 2)
                acc[m][n] = __builtin_amdgcn_mfma_f32_16x16x32_bf16(a_h[m], b_l[n], acc[m][n], 0, 0, 0);
        }
}

template<int TERMS, int EPI>
__global__ __launch_bounds__(256) void gemm_bt(
    const ushort* __restrict__ Ah,
    const ushort* __restrict__ Bh, const ushort* __restrict__ Bl,
    float* __restrict__ C, ushort* __restrict__ oh, ushort* __restrict__ ol,
    const float* __restrict__ bvec,
    int M, int N, int lda, int ldb, int ldc, int kspl)
{
    constexpr int TILE = TERMS == 1 ? 8192 : 12288;   // ushorts per buffer
    __shared__ ushort sm[2 * TILE];

    const int tid = threadIdx.x, wid = tid >> 6, lane = tid & 63;
    const int bm = blockIdx.y * 128, bn = blockIdx.x * 128;
    const int kb = blockIdx.z * kspl;
    const int wr = (wid >> 1) * 64, wc = (wid & 1) * 64;
    const int fr = lane & 15, fq = lane >> 4;

    f32x4 acc[4][4] = {};

    stage_all<TERMS>(sm, Ah, Bh, Bl, lda, ldb, bm, bn, kb, wid, lane);
    __syncthreads();
    int cur = 0;
    for (int k0 = 32; k0 < kspl; k0 += 32) {
        ushort* nbuf       = cur ? sm : sm + TILE;
        const ushort* cbuf = cur ? sm + TILE : sm;
        stage_all<TERMS>(nbuf, Ah, Bh, Bl, lda, ldb, bm, bn, kb + k0, wid, lane);
        compute_tile<TERMS>(cbuf, wr, wc, fr, fq, acc);
        __syncthreads();
        cur ^= 1;
    }
    compute_tile<TERMS>(cur ? sm + TILE : sm, wr, wc, fr, fq, acc);

    #pragma unroll
    for (int m = 0; m < 4; ++m) {
        int rbase = bm + wr + m * 16 + fq * 4;
        #pragma unroll
        for (int n = 0; n < 4; ++n) {
            int col = bn + wc + n * 16 + fr;
            if (col >= N) continue;
            if (EPI == 0) {
                #pragma unroll
                for (int j = 0; j < 4; ++j)
                    C[((size_t)blockIdx.z * M + rbase + j) * ldc + col] = acc[m][n][j];
            } else {
                float bb = bvec[col];
                #pragma unroll
                for (int j = 0; j < 4; ++j) {
                    float v = softplus_f(acc[m][n][j] + bb);
                    ushort hh = f2bf(v);
                    size_t off = (size_t)(rbase + j) * ldc + col;
                    oh[off] = hh;
                    ol[off] = f2bf(v - bf2f(hh));
                }
            }
        }
    }
}

// ---------------------------------------------------------------------------
// gemm_out64: C[M][N] = A[M][K] @ B[N][K]^T, 128x64 tile, full-K, 1-term,
// direct fp32 store. Grid (N/64, M/128) = 256 blocks.
// ---------------------------------------------------------------------------
__global__ __launch_bounds__(256) void gemm_out64(
    const ushort* __restrict__ Ah, const ushort* __restrict__ Bh,
    float* __restrict__ C, int K, int lda, int ldb, int ldc)
{
    __shared__ ushort sm[12288];                  // 24 KB: two 12 KB buffers
    const int tid = threadIdx.x, wid = tid >> 6, lane = tid & 63;
    const int bm = blockIdx.y * 128, bn = blockIdx.x * 64;
    const int wr = (wid >> 1) * 64, wc = (wid & 1) * 32;
    const int fr = lane & 15, fq = lane >> 4;

    f32x4 acc[4][2] = {};

    stage_tile  (sm,        Ah, lda, bm, 0, wid, lane);
    stage_tile64(sm + 4096, Bh, ldb, bn, 0, wid, lane);
    __syncthreads();
    int cur = 0;
    for (int k0 = 32; k0 < K; k0 += 32) {
        ushort* nbuf       = cur ? sm : sm + 6144;
        const ushort* cbuf = cur ? sm + 6144 : sm;
        stage_tile  (nbuf,        Ah, lda, bm, k0, wid, lane);
        stage_tile64(nbuf + 4096, Bh, ldb, bn, k0, wid, lane);
        {
            short8 a_h[4], b_h[2];
            #pragma unroll
            for (int m = 0; m < 4; ++m)
                a_h[m] = frag(cbuf, wr + m * 16 + fr, fq);
            #pragma unroll
            for (int n = 0; n < 2; ++n)
                b_h[n] = frag(cbuf + 4096, wc + n * 16 + fr, fq);
            #pragma unroll
            for (int m = 0; m < 4; ++m)
                #pragma unroll
                for (int n = 0; n < 2; ++n)
                    acc[m][n] = __builtin_amdgcn_mfma_f32_16x16x32_bf16(a_h[m], b_h[n], acc[m][n], 0, 0, 0);
        }
        __syncthreads();
        cur ^= 1;
    }
    {
        const ushort* cbuf = cur ? sm + 6144 : sm;
        short8 a_h[4], b_h[2];
        #pragma unroll
        for (int m = 0; m < 4; ++m)
            a_h[m] = frag(cbuf, wr + m * 16 + fr, fq);
        #pragma unroll
        for (int n = 0; n < 2; ++n)
            b_h[n] = frag(cbuf + 4096, wc + n * 16 + fr, fq);
        #pragma unroll
        for (int m = 0; m < 4; ++m)
            #pragma unroll
            for (int n = 0; n < 2; ++n)
                acc[m][n] = __builtin_amdgcn_mfma_f32_16x16x32_bf16(a_h[m], b_h[n], acc[m][n], 0, 0, 0);
    }

    #pragma unroll
    for (int m = 0; m < 4; ++m) {
        int rbase = bm + wr + m * 16 + fq * 4;
        #pragma unroll
        for (int n = 0; n < 2; ++n) {
            int col = bn + wc + n * 16 + fr;
            #pragma unroll
            for (int j = 0; j < 4; ++j)
                C[(size_t)(rbase + j) * ldc + col] = acc[m][n][j];
        }
    }
}

// ---------------------------------------------------------------------------
// reduce_xproj: sum 16 split-K parts -> xdbl; also emit dt_lr as bf16 hi.
// ---------------------------------------------------------------------------
__global__ __launch_bounds__(256) void reduce_xproj(
    const float* __restrict__ p, float* __restrict__ xdbl,
    ushort* __restrict__ DTh)
{
    int i = blockIdx.x * 256 + threadIdx.x;
    if (i >= 2048 * 96) return;
    float s = 0.f;
    #pragma unroll
    for (int c = 0; c < 16; ++c) s += p[i + (size_t)c * (2048 * 96)];
    xdbl[i] = s;
    int row = i / 96, col = i - row * 96;
    if (col < 64) DTh[row * 64 + col] = f2bf(s);
}

// ---------------------------------------------------------------------------
// Depthwise causal conv (k=4) + bias + SiLU -> u as bf16 hi only.
// ---------------------------------------------------------------------------
__global__ __launch_bounds__(256) void conv_silu(
    const float* __restrict__ xz, const float* __restrict__ w,
    const float* __restrict__ bias, ushort* __restrict__ uh)
{
    int idx = blockIdx.x * 256 + threadIdx.x;
    if (idx >= B_ * L_ * DI) return;
    int d  = idx & (DI - 1);
    int bl = idx >> 11;
    int l  = bl & (L_ - 1);

    const float w0 = w[d * 4 + 0], w1 = w[d * 4 + 1];
    const float w2 = w[d * 4 + 2], w3 = w[d * 4 + 3];
    float s = bias[d];
    size_t base = (size_t)bl * 4096 + d;
    if (l >= 3) s = fmaf(w0, xz[base - 3 * 4096], s);
    if (l >= 2) s = fmaf(w1, xz[base - 2 * 4096], s);
    if (l >= 1) s = fmaf(w2, xz[base - 1 * 4096], s);
    s = fmaf(w3, xz[base], s);
    float v = s / (1.f + __expf(-s));
    uh[idx] = f2bf(v);
}

// ---------------------------------------------------------------------------
// Scan phase A: lane owns channel d for chunk c. h[16], Adn[16] in regs.
// ---------------------------------------------------------------------------
__global__ __launch_bounds__(256) void scan_partial(
    const ushort* __restrict__ Dh, const ushort* __restrict__ Dl,
    const ushort* __restrict__ uh,
    const float* __restrict__ xdbl, const float* __restrict__ A_log,
    float* __restrict__ sA, float* __restrict__ sH)
{
    __shared__ float Bs[CL][16];
    const int tid  = threadIdx.x;
    const int dblk = blockIdx.x & 7;
    const int c    = (blockIdx.x >> 3) & (NC - 1);
    const int b    = blockIdx.x >> 8;
    const int d    = dblk * 256 + tid;
    const int bl0  = b * L_ + c * CL;

    for (int i = tid; i < CL * 16; i += 256) {
        int t = i >> 4, n = i & 15;
        Bs[t][n] = xdbl[(size_t)(bl0 + t) * 96 + DR + n];
    }
    __syncthreads();

    float Adn[16];
    #pragma unroll
    for (int q = 0; q < 4; ++q) {
        float4 al = *(const float4*)&A_log[d * DS + q * 4];
        Adn[q * 4 + 0] = -__expf(al.x);
        Adn[q * 4 + 1] = -__expf(al.y);
        Adn[q * 4 + 2] = -__expf(al.z);
        Adn[q * 4 + 3] = -__expf(al.w);
    }
    float h[16];
    #pragma unroll
    for (int n = 0; n < 16; ++n) h[n] = 0.f;
    float S = 0.f;

    size_t pd = (size_t)bl0 * DI + d;
    for (int t = 0; t < CL; ++t) {
        float dv = bf2f(Dh[pd]) + bf2f(Dl[pd]);
        float uv = bf2f(uh[pd]);
        float du = dv * uv;
        S += dv;
        float Bv[16];
        *(float4*)&Bv[0]  = *(const float4*)&Bs[t][0];
        *(float4*)&Bv[4]  = *(const float4*)&Bs[t][4];
        *(float4*)&Bv[8]  = *(const float4*)&Bs[t][8];
        *(float4*)&Bv[12] = *(const float4*)&Bs[t][12];
        #pragma unroll
        for (int n = 0; n < 16; ++n) {
            float dA = __expf(dv * Adn[n]);
            h[n] = fmaf(dA, h[n], du * Bv[n]);
        }
        pd += DI;
    }

    size_t o = (((size_t)c * B_ + b) * DI + d) * DS;
    float aP[16], hh[16];
    #pragma unroll
    for (int n = 0; n < 16; ++n) { aP[n] = __expf(S * Adn[n]); hh[n] = h[n]; }
    #pragma unroll
    for (int q = 0; q < 4; ++q) {
        *(float4*)&sA[o + q * 4] = *(float4*)&aP[q * 4];
        *(float4*)&sH[o + q * 4] = *(float4*)&hh[q * 4];
    }
}

// ---------------------------------------------------------------------------
__global__ __launch_bounds__(256) void scan_combine(
    const float* __restrict__ sA, const float* __restrict__ sH,
    float* __restrict__ hinit)
{
    int idx = blockIdx.x * 256 + threadIdx.x;   // (b,d,n)
    int n = idx & 15;
    int d = (idx >> 4) & (DI - 1);
    int b = idx >> 15;
    float h = 0.f;
    #pragma unroll
    for (int c = 0; c < NC; ++c) {
        size_t o = (((size_t)c * B_ + b) * DI + d) * DS + n;
        hinit[o] = h;
        h = fmaf(sA[o], h, sH[o]);
    }
}

// ---------------------------------------------------------------------------
// Scan phase C: rescan chunk from h_init; y-dot in regs; skip + z-gate
// fused; writes y as bf16 HI (GEMM_out A-operand).
// ---------------------------------------------------------------------------
__global__ __launch_bounds__(256) void scan_final(
    const ushort* __restrict__ Dh, const ushort* __restrict__ Dl,
    const ushort* __restrict__ uh,
    const float* __restrict__ xdbl, const float* __restrict__ xz,
    const float* __restrict__ A_log, const float* __restrict__ D_skip,
    const float* __restrict__ hinit, ushort* __restrict__ yh)
{
    __shared__ float Bs[CL][16];
    __shared__ float Cs[CL][16];
    const int tid  = threadIdx.x;
    const int dblk = blockIdx.x & 7;
    const int c    = (blockIdx.x >> 3) & (NC - 1);
    const int b    = blockIdx.x >> 8;
    const int d    = dblk * 256 + tid;
    const int bl0  = b * L_ + c * CL;

    for (int i = tid; i < CL * 16; i += 256) {
        int t = i >> 4, n = i & 15;
        size_t px = (size_t)(bl0 + t) * 96 + DR + n;
        Bs[t][n] = xdbl[px];
        Cs[t][n] = xdbl[px + DS];
    }
    __syncthreads();

    float Adn[16];
    #pragma unroll
    for (int q = 0; q < 4; ++q) {
        float4 al = *(const float4*)&A_log[d * DS + q * 4];
        Adn[q * 4 + 0] = -__expf(al.x);
        Adn[q * 4 + 1] = -__expf(al.y);
        Adn[q * 4 + 2] = -__expf(al.z);
        Adn[q * 4 + 3] = -__expf(al.w);
    }
    const float Dd = D_skip[d];

    float h[16];
    size_t o = (((size_t)c * B_ + b) * DI + d) * DS;
    #pragma unroll
    for (int q = 0; q < 4; ++q)
        *(float4*)&h[q * 4] = *(const float4*)&hinit[o + q * 4];

    size_t pd = (size_t)bl0 * DI + d;
    size_t pz = (size_t)bl0 * 4096 + 2048 + d;
    for (int t = 0; t < CL; ++t) {
        float dv = bf2f(Dh[pd]) + bf2f(Dl[pd]);
        float uv = bf2f(uh[pd]);
        float du = dv * uv;
        float Bv[16], Cv[16];
        *(float4*)&Bv[0]  = *(const float4*)&Bs[t][0];
        *(float4*)&Bv[4]  = *(const float4*)&Bs[t][4];
        *(float4*)&Bv[8]  = *(const float4*)&Bs[t][8];
        *(float4*)&Bv[12] = *(const float4*)&Bs[t][12];
        *(float4*)&Cv[0]  = *(const float4*)&Cs[t][0];
        *(float4*)&Cv[4]  = *(const float4*)&Cs[t][4];
        *(float4*)&Cv[8]  = *(const float4*)&Cs[t][8];
        *(float4*)&Cv[12] = *(const float4*)&Cs[t][12];
        float acc = 0.f;
        #pragma unroll
        for (int n = 0; n < 16; ++n) {
            float dA = __expf(dv * Adn[n]);
            h[n] = fmaf(dA, h[n], du * Bv[n]);
            acc = fmaf(h[n], Cv[n], acc);
        }
        float zv = xz[pz];
        float yv = acc + Dd * uv;
        yv *= zv / (1.f + __expf(-zv));
        yh[pd] = f2bf(yv);
        pd += DI; pz += 4096;
    }
}

// ---------------------------------------------------------------------------
extern "C" void kernel_launch(void* const* d_in, const int* in_sizes, int n_in,
                              void* d_out, int out_size, void* d_ws, size_t ws_size,
                              hipStream_t stream)
{
    const float* x      = (const float*)d_in[0];
    const float* W_in   = (const float*)d_in[1];
    const float* conv_w = (const float*)d_in[2];
    const float* conv_b = (const float*)d_in[3];
    const float* W_xprj = (const float*)d_in[4];
    const float* W_dt   = (const float*)d_in[5];
    const float* b_dt   = (const float*)d_in[6];
    const float* A_log  = (const float*)d_in[7];
    const float* D_skip = (const float*)d_in[8];
    const float* W_out  = (const float*)d_in[9];
    float* out = (float*)d_out;

    char* ws = (char*)d_ws;
    float*  xz    = (float*)(ws + 0);            // 32M (live gemm1->scan_final)
    ushort* Dh    = (ushort*)(ws + 33554432);    // 8M  } softplus'd delta
    ushort* Dl    = (ushort*)(ws + 41943040);    // 8M  }
    float*  xdbl  = (float*)(ws + 50331648);     // 768K (ends 51118080)
    ushort* Woh   = (ushort*)(ws + 51118080);    // 4M  (prep -> gemm_out; the
                                                 //      51.1M..57.4M gap, no
                                                 //      intermediate writer)
    // rotating region 57.4M..82.6M:
    ushort* Xh    = (ushort*)(ws + 57409536);    // 4M  (prep -> gemm1)
    float*  parts = (float*)(ws + 57409536);     // 12.6M (xproj split-K x16,
                                                 //      over Xh+WIh, both dead)
    ushort* WIh   = (ushort*)(ws + 65798144);    // 8M  (prep -> gemm1)
    float*  sA    = (float*)(ws + 57409536);     // 8M  (scan)
    float*  sH    = (float*)(ws + 65798144);     // 8M
    float*  hin   = (float*)(ws + 74186752);     // 8M (end 82575360)
    ushort* Yh    = (ushort*)(ws + 57409536);    // 8M  (scan_final out, over sA)
    ushort* Uh    = (ushort*)(ws + 82575360);    // 8M
    ushort* WXh   = (ushort*)(ws + 99352576);    // 512K
    ushort* WXl   = (ushort*)(ws + 99876864);    // 512K
    ushort* DTh   = (ushort*)(ws + 100401152);   // 256K
    ushort* WDh   = (ushort*)(ws + 100914176);   // 256K
    ushort* WDl   = (ushort*)(ws + 101170688);   // 256K (end 101427200 = proven cap)

    dim3 blk(256);
    const int M = B_ * L_;   // 2048

    // ---- ALL input conversions (incl. W_out^T) ----
    prep_all<<<dim3(7552), blk, 0, stream>>>(
        x, W_in, W_xprj, W_dt, W_out, Xh, WIh, WXh, WXl, WDh, WDl, Woh);

    // ---- xz = x @ W_in : 1-term bf16 ----
    gemm_bt<1, 0><<<dim3(32, 16, 1), blk, 0, stream>>>(
        Xh, WIh, nullptr, xz, nullptr, nullptr, nullptr,
        M, 4096, DM, DM, 4096, DM);

    // ---- u = silu(conv(x_in)+b) -> bf16 hi ----
    conv_silu<<<dim3((B_ * L_ * DI) / 256), blk, 0, stream>>>(xz, conv_w, conv_b, Uh);

    // ---- x_dbl = u @ W_xproj : 2-term, split-K x16 (full occupancy) ----
    gemm_bt<2, 0><<<dim3(1, 16, 16), blk, 0, stream>>>(
        Uh, WXh, WXl, parts, nullptr, nullptr, nullptr,
        M, 96, DI, DI, 96, 128);
    reduce_xproj<<<dim3(768), blk, 0, stream>>>(parts, xdbl, DTh);

    // ---- delta = softplus(dt_lr @ W_dt + b_dt) : 2-term, fused epi ----
    gemm_bt<2, 1><<<dim3(16, 16, 1), blk, 0, stream>>>(
        DTh, WDh, WDl, nullptr, Dh, Dl, b_dt,
        M, DI, DR, DR, DI, DR);

    // ---- chunked selective scan ----
    scan_partial<<<dim3(B_ * NC * 8), blk, 0, stream>>>(
        Dh, Dl, Uh, xdbl, A_log, sA, sH);
    scan_combine<<<dim3((B_ * DI * DS) / 256), blk, 0, stream>>>(sA, sH, hin);
    scan_final<<<dim3(B_ * NC * 8), blk, 0, stream>>>(
        Dh, Dl, Uh, xdbl, xz, A_log, D_skip, hin, Yh);

    // ---- out = y @ W_out : 128x64 tile, full-K, direct store ----
    gemm_out64<<<dim3(DM / 64, M / 128), blk, 0, stream>>>(
        Yh, Woh, out, DI, DI, DI, DM);
}